// Round 4
// baseline (553.481 us; speedup 1.0000x reference)
//
#include <hip/hip_runtime.h>
#include <hip/hip_bf16.h>

typedef unsigned int u32;
typedef unsigned short ushortt;

#define B_  8
#define C_  64
#define N_  1000
#define T_  24
#define R_  10
#define NT_ 24000   // N*T
#define CT_ 1536    // C*T
#define NC_ 64000   // N*Co

typedef __attribute__((ext_vector_type(8))) short bf8v;
typedef __attribute__((ext_vector_type(4))) float f4v;

__device__ __forceinline__ ushortt f2b_bits(float f) {
  u32 x = __float_as_uint(f);
  u32 r = (x + 0x7fffu + ((x >> 16) & 1u)) >> 16;   // round-to-nearest-even
  return (ushortt)r;
}

__device__ __forceinline__ u32 f2b_pair(float a, float b) {
  return (u32)f2b_bits(a) | ((u32)f2b_bits(b) << 16);
}

__device__ __forceinline__ float blockSum256(float v, float* red) {
  red[threadIdx.x] = v; __syncthreads();
  #pragma unroll
  for (int s = 128; s > 0; s >>= 1) {
    if (threadIdx.x < s) red[threadIdx.x] += red[threadIdx.x + s];
    __syncthreads();
  }
  float r = red[0]; __syncthreads();
  return r;
}
__device__ __forceinline__ float blockMax256(float v, float* red) {
  red[threadIdx.x] = v; __syncthreads();
  #pragma unroll
  for (int s = 128; s > 0; s >>= 1) {
    if (threadIdx.x < s) red[threadIdx.x] = fmaxf(red[threadIdx.x], red[threadIdx.x + s]);
    __syncthreads();
  }
  float r = red[0]; __syncthreads();
  return r;
}

__device__ __forceinline__ void ld24f32(const float* p, float* v) {
  #pragma unroll
  for (int t = 0; t < 24; t += 4) {
    float4 f = *(const float4*)&p[t];
    v[t] = f.x; v[t+1] = f.y; v[t+2] = f.z; v[t+3] = f.w;
  }
}

// ---------- utility ----------
__global__ __launch_bounds__(256) void zerok(float* p, int n) {
  int i = blockIdx.x * 256 + threadIdx.x;
  if (i < n) p[i] = 0.f;
}

// pack W1[K][10] and W2[10][K] -> Wp[K][20]
__global__ __launch_bounds__(256) void pack_w(
    const float* __restrict__ W1, const float* __restrict__ W2,
    float* __restrict__ Wp, int K) {
  int i = blockIdx.x * 256 + threadIdx.x;
  if (i >= K * 20) return;
  int k = i / 20, r = i - k * 20;
  Wp[i] = (r < 10) ? W1[(size_t)k * 10 + r] : W2[(size_t)(r - 10) * K + k];
}

// pack tail weights to bf16 A-matrices:
// [0:8192)  Wc1b[2][64][64]  tap0 = c1w[...,1] (current), tap1 = c1w[...,0] (t-1)
// [8192:16384) Wc2b[2][64][64]
// [16384:20480) Wrb[64][64]
__global__ __launch_bounds__(256) void pack_tailw(
    const float* __restrict__ c1w, const float* __restrict__ c2w,
    const float* __restrict__ rw, ushortt* __restrict__ Wt) {
  int i = blockIdx.x * 256 + threadIdx.x;
  if (i >= 20480) return;
  float v;
  if (i < 8192) {
    int tap = i >> 12, o = (i >> 6) & 63, c = i & 63;
    v = c1w[(size_t)(o * 64 + c) * 2 + (tap ? 0 : 1)];
  } else if (i < 16384) {
    int j = i - 8192;
    int tap = j >> 12, o = (j >> 6) & 63, c = j & 63;
    v = c2w[(size_t)(o * 64 + c) * 2 + (tap ? 0 : 1)];
  } else {
    int j = i - 16384;
    v = rw[j];
  }
  Wt[i] = f2b_bits(v);
}

// ---------- stage 1: channel attention scores ----------
// Split-K tall-skinny GEMM: [512 x 24000] @ Wp[24000 x 20] -> s1/s2 (atomics).
__global__ __launch_bounds__(256) void att0_s12(
    const float* __restrict__ x, const float* __restrict__ Wp,
    float* __restrict__ s1, float* __restrict__ s2) {
  __shared__ float red[40 * 257];
  const int row0 = blockIdx.x * 4;
  const int kbase = blockIdx.y * 6000;
  const int tid = threadIdx.x;
  float acc[4][20];
  #pragma unroll
  for (int r = 0; r < 4; ++r)
    #pragma unroll
    for (int j = 0; j < 20; ++j) acc[r][j] = 0.f;
  const float* xb = x + (size_t)row0 * NT_ + kbase;
  const float4* wb4 = (const float4*)Wp + (size_t)kbase * 5;  // Wp[kbase*20]
  #pragma unroll 1
  for (int it = 0; it < 6; ++it) {
    int slot = tid + 256 * it;                 // float4-slot in chunk, < 1500
    if (slot < 1500) {
      int k = slot * 4;
      float4 xv0 = *(const float4*)&xb[k];
      float4 xv1 = *(const float4*)&xb[NT_ + k];
      float4 xv2 = *(const float4*)&xb[2 * NT_ + k];
      float4 xv3 = *(const float4*)&xb[3 * NT_ + k];
      const float4* w4 = wb4 + (size_t)slot * 20;   // 4 k's x 5 float4
      #pragma unroll
      for (int kk = 0; kk < 4; ++kk) {
        float4 wa = w4[kk * 5 + 0], wbv = w4[kk * 5 + 1], wc = w4[kk * 5 + 2],
               wd = w4[kk * 5 + 3], we = w4[kk * 5 + 4];
        float w[20] = {wa.x,wa.y,wa.z,wa.w, wbv.x,wbv.y,wbv.z,wbv.w,
                       wc.x,wc.y,wc.z,wc.w, wd.x,wd.y,wd.z,wd.w,
                       we.x,we.y,we.z,we.w};
        float xs0 = ((const float*)&xv0)[kk];
        float xs1 = ((const float*)&xv1)[kk];
        float xs2 = ((const float*)&xv2)[kk];
        float xs3 = ((const float*)&xv3)[kk];
        #pragma unroll
        for (int j = 0; j < 20; ++j) {
          acc[0][j] += xs0 * w[j];
          acc[1][j] += xs1 * w[j];
          acc[2][j] += xs2 * w[j];
          acc[3][j] += xs3 * w[j];
        }
      }
    }
  }
  // block reduce: 80 values x 256 threads, in 2 halves of 40
  #pragma unroll
  for (int half = 0; half < 2; ++half) {
    __syncthreads();
    #pragma unroll
    for (int mm = 0; mm < 40; ++mm) {
      int m = half * 40 + mm;
      red[mm * 257 + tid] = acc[m / 20][m % 20];
    }
    __syncthreads();
    #pragma unroll
    for (int s = 128; s >= 8; s >>= 1) {
      for (int i = tid; i < 40 * s; i += 256) {
        int rr = i / s, col = i - rr * s;
        red[rr * 257 + col] += red[rr * 257 + col + s];
      }
      __syncthreads();
    }
    if (tid < 40) {
      float v = 0.f;
      #pragma unroll
      for (int c = 0; c < 8; ++c) v += red[tid * 257 + c];
      int m = half * 40 + tid;
      int row = row0 + m / 20, j = m % 20;
      if (j < 10) atomicAdd(&s1[row * 10 + j], v);
      else        atomicAdd(&s2[row * 10 + (j - 10)], v);
    }
  }
}

__global__ __launch_bounds__(64) void att0_softmax(
    const float* __restrict__ s1, const float* __restrict__ s2, float* __restrict__ P) {
  int b = blockIdx.x, i = threadIdx.x;
  float r1[R_];
  #pragma unroll
  for (int r = 0; r < R_; ++r) r1[r] = s1[(b * 64 + i) * R_ + r];
  const float scale = rsqrtf(24000.f);
  float row[64]; float m = -1e30f;
  for (int j = 0; j < 64; ++j) {
    const float* s2r = s2 + (size_t)(b * 64 + j) * R_;
    float d = 0.f;
    #pragma unroll
    for (int r = 0; r < R_; ++r) d += r1[r] * s2r[r];
    d *= scale; row[j] = d; m = fmaxf(m, d);
  }
  float s = 0.f;
  for (int j = 0; j < 64; ++j) { float e = __expf(row[j] - m); row[j] = e; s += e; }
  float inv = 1.f / s;
  for (int j = 0; j < 64; ++j) P[((size_t)b * 64 + i) * 64 + j] = row[j] * inv;
}

__global__ __launch_bounds__(256) void att0_apply(
    const float* __restrict__ x, const float* __restrict__ P, float* __restrict__ x1tr) {
  __shared__ float Pss[4160];
  __shared__ float xt[6144];
  int b = blockIdx.y, n0 = blockIdx.x * 4;
  int tid = threadIdx.x;
  for (int i = tid; i < 4096; i += 256)
    Pss[(i >> 6) * 65 + (i & 63)] = P[(size_t)b * 4096 + i];
  {
    const float4* src4 = (const float4*)x;
    float4* dst4 = (float4*)xt;
    for (int i = tid; i < 1536; i += 256) {
      int j = i / 24, q = i - j * 24;
      dst4[i] = src4[(size_t)(b * 64 + j) * 6000 + n0 * 6 + q];
    }
  }
  __syncthreads();
  int ig = tid >> 4, ln = (tid >> 2) & 3, ts = tid & 3;
  float acc[4][6];
  #pragma unroll
  for (int ii = 0; ii < 4; ++ii)
    #pragma unroll
    for (int m = 0; m < 6; ++m) acc[ii][m] = 0.f;
  const float* base = &xt[ln * 24 + ts * 6];
  #pragma unroll 4
  for (int j = 0; j < 64; ++j) {
    float vj[6];
    #pragma unroll
    for (int m = 0; m < 6; ++m) vj[m] = base[j * 96 + m];
    #pragma unroll
    for (int ii = 0; ii < 4; ++ii) {
      float p = Pss[(ig * 4 + ii) * 65 + j];
      #pragma unroll
      for (int m = 0; m < 6; ++m) acc[ii][m] += p * vj[m];
    }
  }
  float* drow = x1tr + ((size_t)b * N_ + n0 + ln) * CT_ + ts * 6;
  #pragma unroll
  for (int ii = 0; ii < 4; ++ii) {
    float* d = drow + (ii * 4 + ig) * 0 + (ig * 4 + ii) * 24;
    *(float2*)&d[0] = make_float2(acc[ii][0], acc[ii][1]);
    *(float2*)&d[2] = make_float2(acc[ii][2], acc[ii][3]);
    *(float2*)&d[4] = make_float2(acc[ii][4], acc[ii][5]);
  }
}

// ---------- transpose x1tr -> Xbt bf16 ----------
__global__ __launch_bounds__(256) void transpose_x1(
    const float* __restrict__ x1tr, ushortt* __restrict__ Xbt) {
  __shared__ float s[64][65];
  int b = blockIdx.z, n0 = blockIdx.y * 64, c0 = blockIdx.x * 64;
  int tid = threadIdx.x;
  int r = tid >> 2, cc = (tid & 3) * 16;
  if (n0 + r < N_) {
    const float* src = x1tr + ((size_t)b * N_ + n0 + r) * CT_ + c0 + cc;
    #pragma unroll
    for (int i = 0; i < 16; i += 4) {
      float4 v = *(const float4*)&src[i];
      s[r][cc + i] = v.x; s[r][cc + i + 1] = v.y;
      s[r][cc + i + 2] = v.z; s[r][cc + i + 3] = v.w;
    }
  } else {
    #pragma unroll
    for (int i = 0; i < 16; ++i) s[r][cc + i] = 0.f;
  }
  __syncthreads();
  ushortt* dst = Xbt + ((size_t)b * CT_ + c0 + r) * 1024 + n0 + cc;
  #pragma unroll
  for (int i = 0; i < 16; ++i) dst[i] = f2b_bits(s[cc + i][r]);
}

// ---------- stage 2: gate scores ----------
__global__ __launch_bounds__(256) void gatt_s12(
    const float* __restrict__ xg, const float* __restrict__ Wp,
    float* __restrict__ s1, float* __restrict__ s2T) {
  __shared__ float xs[6144];
  __shared__ float red[5120];
  int bn0 = blockIdx.x * 4;
  int tid = threadIdx.x;
  {
    const float4* src4 = (const float4*)(xg + (size_t)bn0 * CT_);
    float4* dst4 = (float4*)xs;
    for (int i = tid; i < 1536; i += 256) dst4[i] = src4[i];
  }
  __syncthreads();
  int rid = tid >> 6, ks = tid & 63;
  float a[20];
  #pragma unroll
  for (int r = 0; r < 20; ++r) a[r] = 0.f;
  for (int k = ks; k < CT_; k += 64) {
    float xv = xs[rid * CT_ + k];
    const float4* wp4 = (const float4*)&Wp[(size_t)k * 20];
    float4 wa = wp4[0], wb = wp4[1], wc = wp4[2], wd = wp4[3], we = wp4[4];
    float wv[20] = {wa.x,wa.y,wa.z,wa.w, wb.x,wb.y,wb.z,wb.w, wc.x,wc.y,wc.z,wc.w,
                    wd.x,wd.y,wd.z,wd.w, we.x,we.y,we.z,we.w};
    #pragma unroll
    for (int r = 0; r < 20; ++r) a[r] += xv * wv[r];
  }
  #pragma unroll
  for (int r = 0; r < 20; ++r) red[tid * 20 + r] = a[r];
  __syncthreads();
  if (tid < 80) {
    int rid2 = tid / 20, r = tid % 20;
    float s = 0.f;
    for (int l = 0; l < 64; ++l) s += red[(rid2 * 64 + l) * 20 + r];
    int row = bn0 + rid2;
    int b = row / N_, n = row - b * N_;
    if (r < 10) s1[row * 10 + r] = s;
    else        s2T[((size_t)b * 10 + (r - 10)) * N_ + n] = s;
  }
}

__global__ __launch_bounds__(256) void gatt_scores(
    const float* __restrict__ s1, const float* __restrict__ s2T,
    const float* __restrict__ Aadj, ushortt* __restrict__ Agb) {
  __shared__ float p[N_];
  __shared__ float r1[R_];
  __shared__ float red[256];
  int b = blockIdx.x / N_, n = blockIdx.x % N_;
  if (threadIdx.x < R_) r1[threadIdx.x] = s1[((size_t)b * N_ + n) * R_ + threadIdx.x];
  __syncthreads();
  const float scale = rsqrtf(1536.f);
  const float* s2b = s2T + (size_t)b * 10 * N_;
  float lmax = -1e30f;
  for (int m = threadIdx.x; m < N_; m += 256) {
    float d = 0.f;
    #pragma unroll
    for (int r = 0; r < R_; ++r) d += r1[r] * s2b[r * N_ + m];
    d *= scale; p[m] = d; lmax = fmaxf(lmax, d);
  }
  float gmax = blockMax256(lmax, red);
  float lsum = 0.f;
  for (int m = threadIdx.x; m < N_; m += 256) {
    float e = __expf(p[m] - gmax); p[m] = e; lsum += e;
  }
  float gsum = blockSum256(lsum, red);
  float inv = 1.f / gsum;
  ushortt* agr = Agb + ((size_t)b * 1024 + n) * 1024;
  const float* ar = Aadj + (size_t)n * N_;
  for (int m = threadIdx.x; m < 1024; m += 256) {
    float v = (m < N_) ? p[m] * inv * ar[m] : 0.f;
    agr[m] = f2b_bits(v);
  }
}

// ---------- batched MFMA GEMM ----------
__global__ __launch_bounds__(256) void gemm_mfma(
    const ushortt* __restrict__ Agb, const ushortt* __restrict__ Xbt,
    float* __restrict__ g1) {
  __shared__ ushortt As[4096];
  __shared__ ushortt Bs[4096];
  const int b = blockIdx.z;
  const int n0 = blockIdx.x * 128;
  const int m0 = blockIdx.y * 128;
  const ushortt* Ab = Agb + (size_t)b * 1024 * 1024;
  const ushortt* Bb = Xbt + (size_t)b * 1536 * 1024;
  const int tid = threadIdx.x;
  const int wave = tid >> 6, lane = tid & 63;
  const int wr = (wave >> 1) * 64, wc = (wave & 1) * 64;
  const int lrow = lane >> 2;
  const int lcol = (lane & 3) * 8;
  const int q = lane >> 4, l15 = lane & 15;

  f4v acc[4][4];
  #pragma unroll
  for (int i = 0; i < 4; ++i)
    #pragma unroll
    for (int j = 0; j < 4; ++j) acc[i][j] = (f4v){0.f, 0.f, 0.f, 0.f};

  const ushortt* gA = Ab + (size_t)(m0 + wave * 16 + lrow) * 1024 + lcol;
  const ushortt* gB = Bb + (size_t)(n0 + wave * 16 + lrow) * 1024 + lcol;
  ushortt* lA = &As[wave * 16 * 32];
  ushortt* lB = &Bs[wave * 16 * 32];

  for (int k0 = 0; k0 < 1024; k0 += 32) {
    __syncthreads();
    __builtin_amdgcn_global_load_lds(
      (const __attribute__((address_space(1))) void*)(gA + k0),
      (__attribute__((address_space(3))) void*)lA, 16, 0, 0);
    __builtin_amdgcn_global_load_lds(
      (const __attribute__((address_space(1))) void*)(gA + (size_t)64 * 1024 + k0),
      (__attribute__((address_space(3))) void*)(lA + 64 * 32), 16, 0, 0);
    __builtin_amdgcn_global_load_lds(
      (const __attribute__((address_space(1))) void*)(gB + k0),
      (__attribute__((address_space(3))) void*)lB, 16, 0, 0);
    __builtin_amdgcn_global_load_lds(
      (const __attribute__((address_space(1))) void*)(gB + (size_t)64 * 1024 + k0),
      (__attribute__((address_space(3))) void*)(lB + 64 * 32), 16, 0, 0);
    __syncthreads();
    bf8v af[4], bfr[4];
    #pragma unroll
    for (int i = 0; i < 4; ++i)
      af[i] = *(const bf8v*)&As[(wr + i * 16 + l15) * 32 + q * 8];
    #pragma unroll
    for (int j = 0; j < 4; ++j)
      bfr[j] = *(const bf8v*)&Bs[(wc + j * 16 + l15) * 32 + q * 8];
    #pragma unroll
    for (int i = 0; i < 4; ++i)
      #pragma unroll
      for (int j = 0; j < 4; ++j)
        acc[i][j] = __builtin_amdgcn_mfma_f32_16x16x32_bf16(af[i], bfr[j], acc[i][j], 0, 0, 0);
  }
  #pragma unroll
  for (int i = 0; i < 4; ++i) {
    int rbase = m0 + wr + i * 16 + q * 4;
    #pragma unroll
    for (int r = 0; r < 4; ++r) {
      int gm = rbase + r;
      if (gm < N_) {
        float* dst = g1 + ((size_t)b * N_ + gm) * CT_ + n0 + wc + l15;
        #pragma unroll
        for (int j = 0; j < 4; ++j) dst[j * 16] = acc[i][j][r];
      }
    }
  }
}

// ---------- gcn_out ----------
__global__ __launch_bounds__(256) void gcn_out(
    const float* __restrict__ g1, const float* __restrict__ W, float* __restrict__ g) {
  __shared__ float gs[6160];
  __shared__ float Ws[4096];
  int b = blockIdx.y, n0 = blockIdx.x * 4;
  int tid = threadIdx.x;
  {
    const float4* src4 = (const float4*)g1;
    float4* dst4 = (float4*)gs;
    for (int i = tid; i < 1536; i += 256) {
      int ln = i / 384, q = i - ln * 384;
      dst4[ln * 385 + q] = src4[(size_t)(b * N_ + n0 + ln) * 384 + q];
    }
  }
  for (int i = tid; i < 4096; i += 256) Ws[i] = W[i];
  __syncthreads();
  int og = tid >> 4, ln = (tid >> 2) & 3, ts = tid & 3;
  float acc[4][6];
  #pragma unroll
  for (int oo = 0; oo < 4; ++oo)
    #pragma unroll
    for (int m = 0; m < 6; ++m) acc[oo][m] = 0.f;
  const float* base = &gs[ln * 1540 + ts * 6];
  #pragma unroll 4
  for (int c = 0; c < 64; ++c) {
    float v[6];
    #pragma unroll
    for (int m = 0; m < 6; ++m) v[m] = base[c * 24 + m];
    float4 w4 = *(const float4*)&Ws[c * 64 + og * 4];
    float wv[4] = {w4.x, w4.y, w4.z, w4.w};
    #pragma unroll
    for (int oo = 0; oo < 4; ++oo)
      #pragma unroll
      for (int m = 0; m < 6; ++m) acc[oo][m] += wv[oo] * v[m];
  }
  #pragma unroll
  for (int oo = 0; oo < 4; ++oo) {
    int o = og * 4 + oo;
    float* d = g + (((size_t)(b * C_ + o)) * N_ + n0 + ln) * T_ + ts * 6;
    *(float2*)&d[0] = make_float2(acc[oo][0], acc[oo][1]);
    *(float2*)&d[2] = make_float2(acc[oo][2], acc[oo][3]);
    *(float2*)&d[4] = make_float2(acc[oo][4], acc[oo][5]);
  }
}

// ---------- stage 3: temporal attention scores ----------
__global__ __launch_bounds__(256) void tatt_s12(
    const float* __restrict__ g, const float* __restrict__ Wp,
    float* __restrict__ s1, float* __restrict__ s2) {
  __shared__ float red[40 * 257];
  const int b = blockIdx.z, t0 = blockIdx.y * 4, n0 = blockIdx.x * 20;
  const int tid = threadIdx.x;
  const int o = tid & 63, nl = tid >> 6;
  float acc[4][20];
  #pragma unroll
  for (int tt = 0; tt < 4; ++tt)
    #pragma unroll
    for (int j = 0; j < 20; ++j) acc[tt][j] = 0.f;
  const float* gb = g + (size_t)(b * 64 + o) * NT_ + t0;
  #pragma unroll 1
  for (int it = 0; it < 5; ++it) {
    int n = n0 + it * 4 + nl;
    float4 gv = *(const float4*)&gb[n * 24];
    const float4* w4 = (const float4*)&Wp[(size_t)(n * 64 + o) * 20];
    float4 wa = w4[0], wbv = w4[1], wc = w4[2], wd = w4[3], we = w4[4];
    float w[20] = {wa.x,wa.y,wa.z,wa.w, wbv.x,wbv.y,wbv.z,wbv.w,
                   wc.x,wc.y,wc.z,wc.w, wd.x,wd.y,wd.z,wd.w,
                   we.x,we.y,we.z,we.w};
    float gs[4] = {gv.x, gv.y, gv.z, gv.w};
    #pragma unroll
    for (int tt = 0; tt < 4; ++tt)
      #pragma unroll
      for (int j = 0; j < 20; ++j) acc[tt][j] += gs[tt] * w[j];
  }
  // block reduce: 80 values x 256 threads, in 2 halves of 40
  #pragma unroll
  for (int half = 0; half < 2; ++half) {
    __syncthreads();
    #pragma unroll
    for (int mm = 0; mm < 40; ++mm) {
      int m = half * 40 + mm;
      red[mm * 257 + tid] = acc[m / 20][m % 20];
    }
    __syncthreads();
    #pragma unroll
    for (int s = 128; s >= 8; s >>= 1) {
      for (int i = tid; i < 40 * s; i += 256) {
        int rr = i / s, col = i - rr * s;
        red[rr * 257 + col] += red[rr * 257 + col + s];
      }
      __syncthreads();
    }
    if (tid < 40) {
      float v = 0.f;
      #pragma unroll
      for (int c = 0; c < 8; ++c) v += red[tid * 257 + c];
      int m = half * 40 + tid;
      int t = t0 + m / 20, j = m % 20;
      if (j < 10) atomicAdd(&s1[(b * T_ + t) * R_ + j], v);
      else        atomicAdd(&s2[(b * T_ + t) * R_ + (j - 10)], v);
    }
  }
}

__global__ __launch_bounds__(64) void tatt_softmax(
    const float* __restrict__ s1, const float* __restrict__ s2, float* __restrict__ Pt) {
  int b = blockIdx.x, t = threadIdx.x;
  if (t >= T_) return;
  float r1[R_];
  #pragma unroll
  for (int r = 0; r < R_; ++r) r1[r] = s1[(b * T_ + t) * R_ + r];
  const float scale = rsqrtf(64000.f);
  float row[T_]; float m = -1e30f;
  for (int j = 0; j < T_; ++j) {
    const float* s2r = s2 + (b * T_ + j) * R_;
    float d = 0.f;
    #pragma unroll
    for (int r = 0; r < R_; ++r) d += r1[r] * s2r[r];
    d *= scale; row[j] = d; m = fmaxf(m, d);
  }
  float s = 0.f;
  for (int j = 0; j < T_; ++j) { float e = __expf(row[j] - m); row[j] = e; s += e; }
  float inv = 1.f / s;
  for (int j = 0; j < T_; ++j) Pt[(b * T_ + t) * T_ + j] = row[j] * inv;
}

// writes x2 as packed bf16 (same f2b rounding tail_k used to apply on read)
__global__ __launch_bounds__(256) void tatt_apply(
    const float* __restrict__ g, const float* __restrict__ Pt, ushortt* __restrict__ x2b) {
  __shared__ float P[576];
  int b = blockIdx.y;
  for (int i = threadIdx.x; i < 576; i += 256) P[i] = Pt[b * 576 + i];
  __syncthreads();
  int row = blockIdx.x * 256 + threadIdx.x;
  const float* gp = g + ((size_t)b * 64000 + row) * T_;
  float gr[T_];
  ld24f32(gp, gr);
  float out[T_];
  #pragma unroll
  for (int t = 0; t < T_; ++t) {
    float a = 0.f;
    const float* Pr = &P[t * T_];
    #pragma unroll
    for (int j = 0; j < T_; ++j) a += Pr[j] * gr[j];
    out[t] = a;
  }
  u32 w[12];
  #pragma unroll
  for (int t = 0; t < 24; t += 2) w[t >> 1] = f2b_pair(out[t], out[t + 1]);
  ushortt* xp = x2b + ((size_t)b * 64000 + row) * 24;
  *(uint4*)&xp[0]  = make_uint4(w[0], w[1], w[2], w[3]);
  *(uint4*)&xp[8]  = make_uint4(w[4], w[5], w[6], w[7]);
  *(uint4*)&xp[16] = make_uint4(w[8], w[9], w[10], w[11]);
}

// ---------- stage 4 (MFMA tail): conv1 -> conv2 + res -> LN ----------
// grid (250, 8), 256 threads = 4 waves; wave w owns node nl=w (cols 32w..32w+31).
// Column layout per node: s=0,1 zero guards; s=2..25 <-> t=0..23; s=26..31 zero pad.
// TWO 16KB LDS arrays, timeline-overlaid:
//   L0: x2 row-staging -> X2c (MFMA tile) -> Y1c (conv1 out) -> preS (LN)
//   L1: x  row-staging -> Xrc (MFMA tile)
// Residual-x fragments (kb) and conv1 outputs (ypack) ride in registers across
// the overlap points. Stage-A loads are block-strided channel-major: per channel
// the block's 4 nodes x 24 t are contiguous (384B f32 / 192B bf16), so each load
// instruction touches ~17 lines instead of 64.
#define CSB 1024
#define RSB 104
__global__ __launch_bounds__(256, 4) void tail_k(
    const ushortt* __restrict__ x2b, const float* __restrict__ x,
    const ushortt* __restrict__ Wt,
    const float* __restrict__ c1b, const float* __restrict__ c2b,
    const float* __restrict__ rb,
    const float* __restrict__ lg, const float* __restrict__ lb,
    float* __restrict__ outp) {
  __shared__ ushortt L0[8192];
  __shared__ ushortt L1[8192];
  __shared__ float mu[96], rs[96];
  int b = blockIdx.y, n0 = blockIdx.x * 4;
  int tid = threadIdx.x;
  int wave = tid >> 6, lane = tid & 63;
  int q = lane >> 4, l15 = lane & 15;

  // ---- stage A: coalesced block-strided loads into row-staging [64][RSB] ----
  #pragma unroll
  for (int rep = 0; rep < 3; ++rep) {
    int i = tid + rep * 256;                 // < 768 : x2b uint4 slots
    int c = i / 12, u = i - c * 12;
    const uint4* src = (const uint4*)(x2b + ((size_t)(b * 64 + c) * 1000 + n0) * 24);
    uint4 v = src[u];
    *(uint4*)&L0[c * RSB + u * 8] = v;
  }
  #pragma unroll
  for (int rep = 0; rep < 6; ++rep) {
    int i = tid + rep * 256;                 // < 1536 : x float4 slots
    int c = i / 24, qq = i - c * 24;
    const float4* src = (const float4*)(x + ((size_t)(b * 64 + c) * 1000 + n0) * 24);
    float4 v = src[qq];
    *(uint2*)&L1[c * RSB + qq * 4] = make_uint2(f2b_pair(v.x, v.y), f2b_pair(v.z, v.w));
  }
  __syncthreads();

  // ---- stage B: read x2 fragments (pa) from L0 row-staging ----
  u32 pa[4][4];
  int sKblk[4], sCol[4];
  #pragma unroll
  for (int rep = 0; rep < 4; ++rep) {
    int slot = tid + rep * 256;
    int kblk = slot >> 7, col = slot & 127;
    sKblk[rep] = kblk; sCol[rep] = col;
    int nl2 = col >> 5, s = col & 31;
    if (s >= 2 && s <= 25) {
      int boff = (kblk * 8) * RSB + nl2 * 24 + (s - 2);
      #pragma unroll
      for (int h = 0; h < 4; ++h) {
        u32 a0 = L0[boff + (2 * h) * RSB], a1 = L0[boff + (2 * h + 1) * RSB];
        pa[rep][h] = a0 | (a1 << 16);
      }
    } else {
      #pragma unroll
      for (int h = 0; h < 4; ++h) pa[rep][h] = 0u;
    }
  }
  __syncthreads();
  // write X2c tile into L0 (row-staging dead)
  #pragma unroll
  for (int rep = 0; rep < 4; ++rep)
    *(uint4*)&L0[sKblk[rep] * CSB + sCol[rep] * 8] =
        make_uint4(pa[rep][0], pa[rep][1], pa[rep][2], pa[rep][3]);
  __syncthreads();

  // ---- conv1 (X2c in L0) + read residual fragments (kb) from L1 ----
  f4v acc1[2][4];
  #pragma unroll
  for (int ct = 0; ct < 2; ++ct)
    #pragma unroll
    for (int mt = 0; mt < 4; ++mt) acc1[ct][mt] = (f4v){0.f, 0.f, 0.f, 0.f};
  #pragma unroll
  for (int ki = 0; ki < 2; ++ki) {
    bf8v a0[4], a1[4];
    #pragma unroll
    for (int mt = 0; mt < 4; ++mt) {
      a0[mt] = *(const bf8v*)&Wt[(mt * 16 + l15) * 64 + ki * 32 + q * 8];
      a1[mt] = *(const bf8v*)&Wt[4096 + (mt * 16 + l15) * 64 + ki * 32 + q * 8];
    }
    #pragma unroll
    for (int ct = 0; ct < 2; ++ct) {
      int col = wave * 32 + ct * 16 + l15;
      int colp = (col == 0) ? 0 : col - 1;
      bf8v bc = *(const bf8v*)&L0[(ki * 4 + q) * CSB + col * 8];
      bf8v bp = *(const bf8v*)&L0[(ki * 4 + q) * CSB + colp * 8];
      #pragma unroll
      for (int mt = 0; mt < 4; ++mt) {
        acc1[ct][mt] = __builtin_amdgcn_mfma_f32_16x16x32_bf16(a0[mt], bc, acc1[ct][mt], 0, 0, 0);
        acc1[ct][mt] = __builtin_amdgcn_mfma_f32_16x16x32_bf16(a1[mt], bp, acc1[ct][mt], 0, 0, 0);
      }
    }
  }
  u32 kb[4][4];
  #pragma unroll
  for (int rep = 0; rep < 4; ++rep) {
    int col = sCol[rep];
    int nl2 = col >> 5, s = col & 31;
    if (s >= 2 && s <= 25) {
      int boff = (sKblk[rep] * 8) * RSB + nl2 * 24 + (s - 2);
      #pragma unroll
      for (int h = 0; h < 4; ++h) {
        u32 b0 = L1[boff + (2 * h) * RSB], b1 = L1[boff + (2 * h + 1) * RSB];
        kb[rep][h] = b0 | (b1 << 16);
      }
    } else {
      #pragma unroll
      for (int h = 0; h < 4; ++h) kb[rep][h] = 0u;
    }
  }
  // epilogue 1 in regs: bias + relu (zeros in guard/pad cols)
  u32 ypack[2][4][2];
  #pragma unroll
  for (int ct = 0; ct < 2; ++ct) {
    int s = ct * 16 + l15;
    bool v = (s >= 2 && s <= 25);
    #pragma unroll
    for (int mt = 0; mt < 4; ++mt) {
      int o0 = mt * 16 + q * 4;
      float4 bb = *(const float4*)&c1b[o0];
      float y0 = v ? fmaxf(acc1[ct][mt][0] + bb.x, 0.f) : 0.f;
      float y1 = v ? fmaxf(acc1[ct][mt][1] + bb.y, 0.f) : 0.f;
      float y2 = v ? fmaxf(acc1[ct][mt][2] + bb.z, 0.f) : 0.f;
      float y3 = v ? fmaxf(acc1[ct][mt][3] + bb.w, 0.f) : 0.f;
      ypack[ct][mt][0] = f2b_pair(y0, y1);
      ypack[ct][mt][1] = f2b_pair(y2, y3);
    }
  }
  __syncthreads();   // all conv1 X2c reads + kb L1 reads done

  // ---- write Y1c -> L0 (over X2c), Xrc -> L1 (over x staging) ----
  #pragma unroll
  for (int ct = 0; ct < 2; ++ct) {
    int col = wave * 32 + ct * 16 + l15;
    #pragma unroll
    for (int mt = 0; mt < 4; ++mt) {
      int o0 = mt * 16 + q * 4;
      *(uint2*)&L0[(o0 >> 3) * CSB + col * 8 + (o0 & 7)] =
          make_uint2(ypack[ct][mt][0], ypack[ct][mt][1]);
    }
  }
  #pragma unroll
  for (int rep = 0; rep < 4; ++rep)
    *(uint4*)&L1[sKblk[rep] * CSB + sCol[rep] * 8] =
        make_uint4(kb[rep][0], kb[rep][1], kb[rep][2], kb[rep][3]);
  __syncthreads();

  // ---- conv2 (taps col, col-2 from Y1c=L0) + residual (Xrc=L1) ----
  f4v accA[2][4], accR[2][4];
  #pragma unroll
  for (int ct = 0; ct < 2; ++ct)
    #pragma unroll
    for (int mt = 0; mt < 4; ++mt) {
      accA[ct][mt] = (f4v){0.f, 0.f, 0.f, 0.f};
      accR[ct][mt] = (f4v){0.f, 0.f, 0.f, 0.f};
    }
  #pragma unroll
  for (int ki = 0; ki < 2; ++ki) {
    bf8v c0[4], c1t[4], rrf[4];
    #pragma unroll
    for (int mt = 0; mt < 4; ++mt) {
      c0[mt]  = *(const bf8v*)&Wt[8192 + (mt * 16 + l15) * 64 + ki * 32 + q * 8];
      c1t[mt] = *(const bf8v*)&Wt[12288 + (mt * 16 + l15) * 64 + ki * 32 + q * 8];
      rrf[mt] = *(const bf8v*)&Wt[16384 + (mt * 16 + l15) * 64 + ki * 32 + q * 8];
    }
    #pragma unroll
    for (int ct = 0; ct < 2; ++ct) {
      int col = wave * 32 + ct * 16 + l15;
      int colp2 = (col < 2) ? col : col - 2;
      bf8v bc = *(const bf8v*)&L0[(ki * 4 + q) * CSB + col * 8];
      bf8v bp = *(const bf8v*)&L0[(ki * 4 + q) * CSB + colp2 * 8];
      bf8v bx = *(const bf8v*)&L1[(ki * 4 + q) * CSB + col * 8];
      #pragma unroll
      for (int mt = 0; mt < 4; ++mt) {
        accA[ct][mt] = __builtin_amdgcn_mfma_f32_16x16x32_bf16(c0[mt], bc, accA[ct][mt], 0, 0, 0);
        accA[ct][mt] = __builtin_amdgcn_mfma_f32_16x16x32_bf16(c1t[mt], bp, accA[ct][mt], 0, 0, 0);
        accR[ct][mt] = __builtin_amdgcn_mfma_f32_16x16x32_bf16(rrf[mt], bx, accR[ct][mt], 0, 0, 0);
      }
    }
  }
  // epilogue 2: relu(conv2+b2) + (res+rb), relu -> pre (regs)
  float pre[2][4][4];
  #pragma unroll
  for (int ct = 0; ct < 2; ++ct) {
    #pragma unroll
    for (int mt = 0; mt < 4; ++mt) {
      int o0 = mt * 16 + q * 4;
      float4 b2 = *(const float4*)&c2b[o0];
      float4 rbv = *(const float4*)&rb[o0];
      float bb2[4] = {b2.x, b2.y, b2.z, b2.w};
      float brv[4] = {rbv.x, rbv.y, rbv.z, rbv.w};
      #pragma unroll
      for (int r = 0; r < 4; ++r) {
        float a = fmaxf(accA[ct][mt][r] + bb2[r], 0.f) + accR[ct][mt][r] + brv[r];
        pre[ct][mt][r] = fmaxf(a, 0.f);
      }
    }
  }
  __syncthreads();   // all conv2 L0/L1 reads done before preS overwrite

  // preS (bf16) -> L0
  ushortt* preS = L0;
  #pragma unroll
  for (int ct = 0; ct < 2; ++ct) {
    int s = ct * 16 + l15;
    bool v = (s >= 2 && s <= 25);
    if (v) {
      int p = wave * 24 + s - 2;
      #pragma unroll
      for (int mt = 0; mt < 4; ++mt) {
        int o0 = mt * 16 + q * 4;
        *(uint2*)&preS[p * 68 + o0] =
            make_uint2(f2b_pair(pre[ct][mt][0], pre[ct][mt][1]),
                       f2b_pair(pre[ct][mt][2], pre[ct][mt][3]));
      }
    }
  }
  __syncthreads();
  // LN stats over o for each of 96 (node,t) pairs
  if (tid < 96) {
    const ushortt* pr = &preS[tid * 68];
    float sm = 0.f, qq = 0.f;
    #pragma unroll 8
    for (int c = 0; c < 64; c += 2) {
      u32 u = *(const u32*)&pr[c];
      float v0 = __uint_as_float(u << 16);
      float v1 = __uint_as_float(u & 0xffff0000u);
      sm += v0 + v1; qq += v0 * v0 + v1 * v1;
    }
    float m = sm * (1.f / 64.f);
    mu[tid] = m;
    rs[tid] = rsqrtf(qq * (1.f / 64.f) - m * m + 1e-5f);
  }
  __syncthreads();
  // normalize + affine + store
  #pragma unroll
  for (int ct = 0; ct < 2; ++ct) {
    int s = ct * 16 + l15;
    bool v = (s >= 2 && s <= 25);
    if (!v) continue;
    int p = wave * 24 + s - 2;
    int t = s - 2;
    float m = mu[p], rr = rs[p];
    #pragma unroll
    for (int mt = 0; mt < 4; ++mt) {
      int o0 = mt * 16 + q * 4;
      float4 g4 = *(const float4*)&lg[o0];
      float4 b4 = *(const float4*)&lb[o0];
      float gg[4] = {g4.x, g4.y, g4.z, g4.w};
      float bb[4] = {b4.x, b4.y, b4.z, b4.w};
      #pragma unroll
      for (int r = 0; r < 4; ++r) {
        int o = o0 + r;
        float val = (pre[ct][mt][r] - m) * rr * gg[r] + bb[r];
        outp[((size_t)(b * 64 + o) * 1000 + n0 + wave) * 24 + t] = val;
      }
    }
  }
}

extern "C" void kernel_launch(void* const* d_in, const int* in_sizes, int n_in,
                              void* d_out, int out_size, void* d_ws, size_t ws_size,
                              hipStream_t stream) {
  const float* x     = (const float*)d_in[0];
  const float* Aadj  = (const float*)d_in[1];
  const float* a0W1  = (const float*)d_in[2];
  const float* a0W2  = (const float*)d_in[3];
  const float* gW1   = (const float*)d_in[4];
  const float* gW2   = (const float*)d_in[5];
  const float* gcnW  = (const float*)d_in[6];
  const float* tW1   = (const float*)d_in[7];
  const float* tW2   = (const float*)d_in[8];
  const float* c1w   = (const float*)d_in[9];
  const float* c1b   = (const float*)d_in[10];
  const float* c2w   = (const float*)d_in[11];
  const float* c2b   = (const float*)d_in[12];
  const float* rw    = (const float*)d_in[13];
  const float* rb    = (const float*)d_in[14];
  const float* lng   = (const float*)d_in[15];
  const float* lnb   = (const float*)d_in[16];
  float* out = (float*)d_out;

  float* ws = (float*)d_ws;
  float* R1   = ws;                    // 12,288,000: x1tr -> x2 (bf16 after tatt)
  float* U    = R1 + 12288000;         // 12,288,000: Xbt+Agb (bf16), later g (f32)
  float* D    = U + 12288000;          // 12,288,000: g1
  float* s1_0 = D + 12288000;          // 5120
  float* s2_0 = s1_0 + 5120;           // 5120
  float* P0   = s2_0 + 5120;           // 32768
  float* s1g  = P0 + 32768;            // 80000
  float* s2gT = s1g + 80000;           // 80000
  float* s1t  = s2gT + 80000;          // 1920
  float* s2t  = s1t + 1920;            // 1920
  float* Ptb  = s2t + 1920;            // 4608
  float* Wp0  = Ptb + 4608;            // 480000
  float* Wgp  = Wp0 + 480000;          // 30720
  float* Wtp  = Wgp + 30720;           // 1280000
  float* Wtl  = Wtp + 1280000;         // 10240 (20480 bf16 packed tail weights)
  ushortt* Xbt = (ushortt*)U;
  ushortt* Agb = (ushortt*)(U + 6291456);
  ushortt* Wtail = (ushortt*)Wtl;
  float* g = U;
  if (ws_size < (size_t)38876416 * 4) return;

  // weight packing
  pack_w<<<1875, 256, 0, stream>>>(a0W1, a0W2, Wp0, 24000);
  pack_w<<<120, 256, 0, stream>>>(gW1, gW2, Wgp, 1536);
  pack_w<<<5000, 256, 0, stream>>>(tW1, tW2, Wtp, 64000);
  pack_tailw<<<80, 256, 0, stream>>>(c1w, c2w, rw, Wtail);
  // stage 1: channel attention (split-K accumulate -> zero first)
  zerok<<<40, 256, 0, stream>>>(s1_0, 10240);
  att0_s12<<<dim3(128, 4), 256, 0, stream>>>(x, Wp0, s1_0, s2_0);
  att0_softmax<<<8, 64, 0, stream>>>(s1_0, s2_0, P0);
  att0_apply<<<dim3(250, 8), 256, 0, stream>>>(x, P0, R1);
  // stage 2: gated GCN
  gatt_s12<<<2000, 256, 0, stream>>>(R1, Wgp, s1g, s2gT);
  transpose_x1<<<dim3(24, 16, 8), 256, 0, stream>>>(R1, Xbt);
  gatt_scores<<<8000, 256, 0, stream>>>(s1g, s2gT, Aadj, Agb);
  gemm_mfma<<<dim3(12, 8, 8), 256, 0, stream>>>(Agb, Xbt, D);
  gcn_out<<<dim3(250, 8), 256, 0, stream>>>(D, gcnW, g);
  // stage 3: temporal attention (split-K accumulate -> zero first)
  zerok<<<15, 256, 0, stream>>>(s1t, 3840);
  tatt_s12<<<dim3(50, 6, 8), 256, 0, stream>>>(g, Wtp, s1t, s2t);
  tatt_softmax<<<8, 32, 0, stream>>>(s1t, s2t, Ptb);
  tatt_apply<<<dim3(250, 8), 256, 0, stream>>>(g, Ptb, (ushortt*)R1);
  // stage 4: MFMA tail + residual + LN
  tail_k<<<dim3(250, 8), 256, 0, stream>>>((const ushortt*)R1, x, Wtail,
                                           c1b, c2b, rb, lng, lnb, out);
}

// Round 5
// 552.195 us; speedup vs baseline: 1.0023x; 1.0023x over previous
//
#include <hip/hip_runtime.h>
#include <hip/hip_bf16.h>

typedef unsigned int u32;
typedef unsigned short ushortt;

#define B_  8
#define C_  64
#define N_  1000
#define T_  24
#define R_  10
#define NT_ 24000   // N*T
#define CT_ 1536    // C*T
#define NC_ 64000   // N*Co

typedef __attribute__((ext_vector_type(8))) short bf8v;
typedef __attribute__((ext_vector_type(4))) float f4v;

__device__ __forceinline__ ushortt f2b_bits(float f) {
  u32 x = __float_as_uint(f);
  u32 r = (x + 0x7fffu + ((x >> 16) & 1u)) >> 16;   // round-to-nearest-even
  return (ushortt)r;
}

__device__ __forceinline__ u32 f2b_pair(float a, float b) {
  return (u32)f2b_bits(a) | ((u32)f2b_bits(b) << 16);
}

__device__ __forceinline__ float blockSum256(float v, float* red) {
  red[threadIdx.x] = v; __syncthreads();
  #pragma unroll
  for (int s = 128; s > 0; s >>= 1) {
    if (threadIdx.x < s) red[threadIdx.x] += red[threadIdx.x + s];
    __syncthreads();
  }
  float r = red[0]; __syncthreads();
  return r;
}
__device__ __forceinline__ float blockMax256(float v, float* red) {
  red[threadIdx.x] = v; __syncthreads();
  #pragma unroll
  for (int s = 128; s > 0; s >>= 1) {
    if (threadIdx.x < s) red[threadIdx.x] = fmaxf(red[threadIdx.x], red[threadIdx.x + s]);
    __syncthreads();
  }
  float r = red[0]; __syncthreads();
  return r;
}

__device__ __forceinline__ void ld24f32(const float* p, float* v) {
  #pragma unroll
  for (int t = 0; t < 24; t += 4) {
    float4 f = *(const float4*)&p[t];
    v[t] = f.x; v[t+1] = f.y; v[t+2] = f.z; v[t+3] = f.w;
  }
}

// ---------- utility ----------
__global__ __launch_bounds__(256) void zerok(float* p, int n) {
  int i = blockIdx.x * 256 + threadIdx.x;
  if (i < n) p[i] = 0.f;
}

// pack W1[K][10] and W2[10][K] -> Wp[K][20]
__global__ __launch_bounds__(256) void pack_w(
    const float* __restrict__ W1, const float* __restrict__ W2,
    float* __restrict__ Wp, int K) {
  int i = blockIdx.x * 256 + threadIdx.x;
  if (i >= K * 20) return;
  int k = i / 20, r = i - k * 20;
  Wp[i] = (r < 10) ? W1[(size_t)k * 10 + r] : W2[(size_t)(r - 10) * K + k];
}

// pack tail weights to bf16 A-matrices:
// [0:8192)  Wc1b[2][64][64]  tap0 = c1w[...,1] (current), tap1 = c1w[...,0] (t-1)
// [8192:16384) Wc2b[2][64][64]
// [16384:20480) Wrb[64][64]
__global__ __launch_bounds__(256) void pack_tailw(
    const float* __restrict__ c1w, const float* __restrict__ c2w,
    const float* __restrict__ rw, ushortt* __restrict__ Wt) {
  int i = blockIdx.x * 256 + threadIdx.x;
  if (i >= 20480) return;
  float v;
  if (i < 8192) {
    int tap = i >> 12, o = (i >> 6) & 63, c = i & 63;
    v = c1w[(size_t)(o * 64 + c) * 2 + (tap ? 0 : 1)];
  } else if (i < 16384) {
    int j = i - 8192;
    int tap = j >> 12, o = (j >> 6) & 63, c = j & 63;
    v = c2w[(size_t)(o * 64 + c) * 2 + (tap ? 0 : 1)];
  } else {
    int j = i - 16384;
    v = rw[j];
  }
  Wt[i] = f2b_bits(v);
}

// ---------- stage 1: channel attention scores ----------
// Split-K tall-skinny GEMM: [512 x 24000] @ Wp[24000 x 20] -> s1/s2 (atomics).
__global__ __launch_bounds__(256) void att0_s12(
    const float* __restrict__ x, const float* __restrict__ Wp,
    float* __restrict__ s1, float* __restrict__ s2) {
  __shared__ float red[40 * 257];
  const int row0 = blockIdx.x * 4;
  const int kbase = blockIdx.y * 6000;
  const int tid = threadIdx.x;
  float acc[4][20];
  #pragma unroll
  for (int r = 0; r < 4; ++r)
    #pragma unroll
    for (int j = 0; j < 20; ++j) acc[r][j] = 0.f;
  const float* xb = x + (size_t)row0 * NT_ + kbase;
  const float4* wb4 = (const float4*)Wp + (size_t)kbase * 5;  // Wp[kbase*20]
  #pragma unroll 1
  for (int it = 0; it < 6; ++it) {
    int slot = tid + 256 * it;                 // float4-slot in chunk, < 1500
    if (slot < 1500) {
      int k = slot * 4;
      float4 xv0 = *(const float4*)&xb[k];
      float4 xv1 = *(const float4*)&xb[NT_ + k];
      float4 xv2 = *(const float4*)&xb[2 * NT_ + k];
      float4 xv3 = *(const float4*)&xb[3 * NT_ + k];
      const float4* w4 = wb4 + (size_t)slot * 20;   // 4 k's x 5 float4
      #pragma unroll
      for (int kk = 0; kk < 4; ++kk) {
        float4 wa = w4[kk * 5 + 0], wbv = w4[kk * 5 + 1], wc = w4[kk * 5 + 2],
               wd = w4[kk * 5 + 3], we = w4[kk * 5 + 4];
        float w[20] = {wa.x,wa.y,wa.z,wa.w, wbv.x,wbv.y,wbv.z,wbv.w,
                       wc.x,wc.y,wc.z,wc.w, wd.x,wd.y,wd.z,wd.w,
                       we.x,we.y,we.z,we.w};
        float xs0 = ((const float*)&xv0)[kk];
        float xs1 = ((const float*)&xv1)[kk];
        float xs2 = ((const float*)&xv2)[kk];
        float xs3 = ((const float*)&xv3)[kk];
        #pragma unroll
        for (int j = 0; j < 20; ++j) {
          acc[0][j] += xs0 * w[j];
          acc[1][j] += xs1 * w[j];
          acc[2][j] += xs2 * w[j];
          acc[3][j] += xs3 * w[j];
        }
      }
    }
  }
  // block reduce: 80 values x 256 threads, in 2 halves of 40
  #pragma unroll
  for (int half = 0; half < 2; ++half) {
    __syncthreads();
    #pragma unroll
    for (int mm = 0; mm < 40; ++mm) {
      int m = half * 40 + mm;
      red[mm * 257 + tid] = acc[m / 20][m % 20];
    }
    __syncthreads();
    #pragma unroll
    for (int s = 128; s >= 8; s >>= 1) {
      for (int i = tid; i < 40 * s; i += 256) {
        int rr = i / s, col = i - rr * s;
        red[rr * 257 + col] += red[rr * 257 + col + s];
      }
      __syncthreads();
    }
    if (tid < 40) {
      float v = 0.f;
      #pragma unroll
      for (int c = 0; c < 8; ++c) v += red[tid * 257 + c];
      int m = half * 40 + tid;
      int row = row0 + m / 20, j = m % 20;
      if (j < 10) atomicAdd(&s1[row * 10 + j], v);
      else        atomicAdd(&s2[row * 10 + (j - 10)], v);
    }
  }
}

__global__ __launch_bounds__(64) void att0_softmax(
    const float* __restrict__ s1, const float* __restrict__ s2, float* __restrict__ P) {
  int b = blockIdx.x, i = threadIdx.x;
  float r1[R_];
  #pragma unroll
  for (int r = 0; r < R_; ++r) r1[r] = s1[(b * 64 + i) * R_ + r];
  const float scale = rsqrtf(24000.f);
  float row[64]; float m = -1e30f;
  for (int j = 0; j < 64; ++j) {
    const float* s2r = s2 + (size_t)(b * 64 + j) * R_;
    float d = 0.f;
    #pragma unroll
    for (int r = 0; r < R_; ++r) d += r1[r] * s2r[r];
    d *= scale; row[j] = d; m = fmaxf(m, d);
  }
  float s = 0.f;
  for (int j = 0; j < 64; ++j) { float e = __expf(row[j] - m); row[j] = e; s += e; }
  float inv = 1.f / s;
  for (int j = 0; j < 64; ++j) P[((size_t)b * 64 + i) * 64 + j] = row[j] * inv;
}

__global__ __launch_bounds__(256) void att0_apply(
    const float* __restrict__ x, const float* __restrict__ P, float* __restrict__ x1tr) {
  __shared__ float Pss[4160];
  __shared__ float xt[6144];
  int b = blockIdx.y, n0 = blockIdx.x * 4;
  int tid = threadIdx.x;
  for (int i = tid; i < 4096; i += 256)
    Pss[(i >> 6) * 65 + (i & 63)] = P[(size_t)b * 4096 + i];
  {
    const float4* src4 = (const float4*)x;
    float4* dst4 = (float4*)xt;
    for (int i = tid; i < 1536; i += 256) {
      int j = i / 24, q = i - j * 24;
      dst4[i] = src4[(size_t)(b * 64 + j) * 6000 + n0 * 6 + q];
    }
  }
  __syncthreads();
  int ig = tid >> 4, ln = (tid >> 2) & 3, ts = tid & 3;
  float acc[4][6];
  #pragma unroll
  for (int ii = 0; ii < 4; ++ii)
    #pragma unroll
    for (int m = 0; m < 6; ++m) acc[ii][m] = 0.f;
  const float* base = &xt[ln * 24 + ts * 6];
  #pragma unroll 4
  for (int j = 0; j < 64; ++j) {
    float vj[6];
    #pragma unroll
    for (int m = 0; m < 6; ++m) vj[m] = base[j * 96 + m];
    #pragma unroll
    for (int ii = 0; ii < 4; ++ii) {
      float p = Pss[(ig * 4 + ii) * 65 + j];
      #pragma unroll
      for (int m = 0; m < 6; ++m) acc[ii][m] += p * vj[m];
    }
  }
  float* drow = x1tr + ((size_t)b * N_ + n0 + ln) * CT_ + ts * 6;
  #pragma unroll
  for (int ii = 0; ii < 4; ++ii) {
    float* d = drow + (ig * 4 + ii) * 24;
    *(float2*)&d[0] = make_float2(acc[ii][0], acc[ii][1]);
    *(float2*)&d[2] = make_float2(acc[ii][2], acc[ii][3]);
    *(float2*)&d[4] = make_float2(acc[ii][4], acc[ii][5]);
  }
}

// ---------- transpose x1tr -> Xbt bf16 ----------
__global__ __launch_bounds__(256) void transpose_x1(
    const float* __restrict__ x1tr, ushortt* __restrict__ Xbt) {
  __shared__ float s[64][65];
  int b = blockIdx.z, n0 = blockIdx.y * 64, c0 = blockIdx.x * 64;
  int tid = threadIdx.x;
  int r = tid >> 2, cc = (tid & 3) * 16;
  if (n0 + r < N_) {
    const float* src = x1tr + ((size_t)b * N_ + n0 + r) * CT_ + c0 + cc;
    #pragma unroll
    for (int i = 0; i < 16; i += 4) {
      float4 v = *(const float4*)&src[i];
      s[r][cc + i] = v.x; s[r][cc + i + 1] = v.y;
      s[r][cc + i + 2] = v.z; s[r][cc + i + 3] = v.w;
    }
  } else {
    #pragma unroll
    for (int i = 0; i < 16; ++i) s[r][cc + i] = 0.f;
  }
  __syncthreads();
  ushortt* dst = Xbt + ((size_t)b * CT_ + c0 + r) * 1024 + n0 + cc;
  #pragma unroll
  for (int i = 0; i < 16; ++i) dst[i] = f2b_bits(s[cc + i][r]);
}

// ---------- stage 2: gate scores ----------
__global__ __launch_bounds__(256) void gatt_s12(
    const float* __restrict__ xg, const float* __restrict__ Wp,
    float* __restrict__ s1, float* __restrict__ s2T) {
  __shared__ float xs[6144];
  __shared__ float red[5120];
  int bn0 = blockIdx.x * 4;
  int tid = threadIdx.x;
  {
    const float4* src4 = (const float4*)(xg + (size_t)bn0 * CT_);
    float4* dst4 = (float4*)xs;
    for (int i = tid; i < 1536; i += 256) dst4[i] = src4[i];
  }
  __syncthreads();
  int rid = tid >> 6, ks = tid & 63;
  float a[20];
  #pragma unroll
  for (int r = 0; r < 20; ++r) a[r] = 0.f;
  for (int k = ks; k < CT_; k += 64) {
    float xv = xs[rid * CT_ + k];
    const float4* wp4 = (const float4*)&Wp[(size_t)k * 20];
    float4 wa = wp4[0], wb = wp4[1], wc = wp4[2], wd = wp4[3], we = wp4[4];
    float wv[20] = {wa.x,wa.y,wa.z,wa.w, wb.x,wb.y,wb.z,wb.w, wc.x,wc.y,wc.z,wc.w,
                    wd.x,wd.y,wd.z,wd.w, we.x,we.y,we.z,we.w};
    #pragma unroll
    for (int r = 0; r < 20; ++r) a[r] += xv * wv[r];
  }
  #pragma unroll
  for (int r = 0; r < 20; ++r) red[tid * 20 + r] = a[r];
  __syncthreads();
  if (tid < 80) {
    int rid2 = tid / 20, r = tid % 20;
    float s = 0.f;
    for (int l = 0; l < 64; ++l) s += red[(rid2 * 64 + l) * 20 + r];
    int row = bn0 + rid2;
    int b = row / N_, n = row - b * N_;
    if (r < 10) s1[row * 10 + r] = s;
    else        s2T[((size_t)b * 10 + (r - 10)) * N_ + n] = s;
  }
}

__global__ __launch_bounds__(256) void gatt_scores(
    const float* __restrict__ s1, const float* __restrict__ s2T,
    const float* __restrict__ Aadj, ushortt* __restrict__ Agb) {
  __shared__ float p[N_];
  __shared__ float r1[R_];
  __shared__ float red[256];
  int b = blockIdx.x / N_, n = blockIdx.x % N_;
  if (threadIdx.x < R_) r1[threadIdx.x] = s1[((size_t)b * N_ + n) * R_ + threadIdx.x];
  __syncthreads();
  const float scale = rsqrtf(1536.f);
  const float* s2b = s2T + (size_t)b * 10 * N_;
  float lmax = -1e30f;
  for (int m = threadIdx.x; m < N_; m += 256) {
    float d = 0.f;
    #pragma unroll
    for (int r = 0; r < R_; ++r) d += r1[r] * s2b[r * N_ + m];
    d *= scale; p[m] = d; lmax = fmaxf(lmax, d);
  }
  float gmax = blockMax256(lmax, red);
  float lsum = 0.f;
  for (int m = threadIdx.x; m < N_; m += 256) {
    float e = __expf(p[m] - gmax); p[m] = e; lsum += e;
  }
  float gsum = blockSum256(lsum, red);
  float inv = 1.f / gsum;
  ushortt* agr = Agb + ((size_t)b * 1024 + n) * 1024;
  const float* ar = Aadj + (size_t)n * N_;
  for (int m = threadIdx.x; m < 1024; m += 256) {
    float v = (m < N_) ? p[m] * inv * ar[m] : 0.f;
    agr[m] = f2b_bits(v);
  }
}

// ---------- batched MFMA GEMM ----------
__global__ __launch_bounds__(256) void gemm_mfma(
    const ushortt* __restrict__ Agb, const ushortt* __restrict__ Xbt,
    float* __restrict__ g1) {
  __shared__ ushortt As[4096];
  __shared__ ushortt Bs[4096];
  const int b = blockIdx.z;
  const int n0 = blockIdx.x * 128;
  const int m0 = blockIdx.y * 128;
  const ushortt* Ab = Agb + (size_t)b * 1024 * 1024;
  const ushortt* Bb = Xbt + (size_t)b * 1536 * 1024;
  const int tid = threadIdx.x;
  const int wave = tid >> 6, lane = tid & 63;
  const int wr = (wave >> 1) * 64, wc = (wave & 1) * 64;
  const int lrow = lane >> 2;
  const int lcol = (lane & 3) * 8;
  const int q = lane >> 4, l15 = lane & 15;

  f4v acc[4][4];
  #pragma unroll
  for (int i = 0; i < 4; ++i)
    #pragma unroll
    for (int j = 0; j < 4; ++j) acc[i][j] = (f4v){0.f, 0.f, 0.f, 0.f};

  const ushortt* gA = Ab + (size_t)(m0 + wave * 16 + lrow) * 1024 + lcol;
  const ushortt* gB = Bb + (size_t)(n0 + wave * 16 + lrow) * 1024 + lcol;
  ushortt* lA = &As[wave * 16 * 32];
  ushortt* lB = &Bs[wave * 16 * 32];

  for (int k0 = 0; k0 < 1024; k0 += 32) {
    __syncthreads();
    __builtin_amdgcn_global_load_lds(
      (const __attribute__((address_space(1))) void*)(gA + k0),
      (__attribute__((address_space(3))) void*)lA, 16, 0, 0);
    __builtin_amdgcn_global_load_lds(
      (const __attribute__((address_space(1))) void*)(gA + (size_t)64 * 1024 + k0),
      (__attribute__((address_space(3))) void*)(lA + 64 * 32), 16, 0, 0);
    __builtin_amdgcn_global_load_lds(
      (const __attribute__((address_space(1))) void*)(gB + k0),
      (__attribute__((address_space(3))) void*)lB, 16, 0, 0);
    __builtin_amdgcn_global_load_lds(
      (const __attribute__((address_space(1))) void*)(gB + (size_t)64 * 1024 + k0),
      (__attribute__((address_space(3))) void*)(lB + 64 * 32), 16, 0, 0);
    __syncthreads();
    bf8v af[4], bfr[4];
    #pragma unroll
    for (int i = 0; i < 4; ++i)
      af[i] = *(const bf8v*)&As[(wr + i * 16 + l15) * 32 + q * 8];
    #pragma unroll
    for (int j = 0; j < 4; ++j)
      bfr[j] = *(const bf8v*)&Bs[(wc + j * 16 + l15) * 32 + q * 8];
    #pragma unroll
    for (int i = 0; i < 4; ++i)
      #pragma unroll
      for (int j = 0; j < 4; ++j)
        acc[i][j] = __builtin_amdgcn_mfma_f32_16x16x32_bf16(af[i], bfr[j], acc[i][j], 0, 0, 0);
  }
  #pragma unroll
  for (int i = 0; i < 4; ++i) {
    int rbase = m0 + wr + i * 16 + q * 4;
    #pragma unroll
    for (int r = 0; r < 4; ++r) {
      int gm = rbase + r;
      if (gm < N_) {
        float* dst = g1 + ((size_t)b * N_ + gm) * CT_ + n0 + wc + l15;
        #pragma unroll
        for (int j = 0; j < 4; ++j) dst[j * 16] = acc[i][j][r];
      }
    }
  }
}

// ---------- gcn_out ----------
__global__ __launch_bounds__(256) void gcn_out(
    const float* __restrict__ g1, const float* __restrict__ W, float* __restrict__ g) {
  __shared__ float gs[6160];
  __shared__ float Ws[4096];
  int b = blockIdx.y, n0 = blockIdx.x * 4;
  int tid = threadIdx.x;
  {
    const float4* src4 = (const float4*)g1;
    float4* dst4 = (float4*)gs;
    for (int i = tid; i < 1536; i += 256) {
      int ln = i / 384, q = i - ln * 384;
      dst4[ln * 385 + q] = src4[(size_t)(b * N_ + n0 + ln) * 384 + q];
    }
  }
  for (int i = tid; i < 4096; i += 256) Ws[i] = W[i];
  __syncthreads();
  int og = tid >> 4, ln = (tid >> 2) & 3, ts = tid & 3;
  float acc[4][6];
  #pragma unroll
  for (int oo = 0; oo < 4; ++oo)
    #pragma unroll
    for (int m = 0; m < 6; ++m) acc[oo][m] = 0.f;
  const float* base = &gs[ln * 1540 + ts * 6];
  #pragma unroll 4
  for (int c = 0; c < 64; ++c) {
    float v[6];
    #pragma unroll
    for (int m = 0; m < 6; ++m) v[m] = base[c * 24 + m];
    float4 w4 = *(const float4*)&Ws[c * 64 + og * 4];
    float wv[4] = {w4.x, w4.y, w4.z, w4.w};
    #pragma unroll
    for (int oo = 0; oo < 4; ++oo)
      #pragma unroll
      for (int m = 0; m < 6; ++m) acc[oo][m] += wv[oo] * v[m];
  }
  #pragma unroll
  for (int oo = 0; oo < 4; ++oo) {
    int o = og * 4 + oo;
    float* d = g + (((size_t)(b * C_ + o)) * N_ + n0 + ln) * T_ + ts * 6;
    *(float2*)&d[0] = make_float2(acc[oo][0], acc[oo][1]);
    *(float2*)&d[2] = make_float2(acc[oo][2], acc[oo][3]);
    *(float2*)&d[4] = make_float2(acc[oo][4], acc[oo][5]);
  }
}

// ---------- stage 3: temporal attention scores ----------
__global__ __launch_bounds__(256) void tatt_s12(
    const float* __restrict__ g, const float* __restrict__ Wp,
    float* __restrict__ s1, float* __restrict__ s2) {
  __shared__ float red[40 * 257];
  const int b = blockIdx.z, t0 = blockIdx.y * 4, n0 = blockIdx.x * 20;
  const int tid = threadIdx.x;
  const int o = tid & 63, nl = tid >> 6;
  float acc[4][20];
  #pragma unroll
  for (int tt = 0; tt < 4; ++tt)
    #pragma unroll
    for (int j = 0; j < 20; ++j) acc[tt][j] = 0.f;
  const float* gb = g + (size_t)(b * 64 + o) * NT_ + t0;
  #pragma unroll 1
  for (int it = 0; it < 5; ++it) {
    int n = n0 + it * 4 + nl;
    float4 gv = *(const float4*)&gb[n * 24];
    const float4* w4 = (const float4*)&Wp[(size_t)(n * 64 + o) * 20];
    float4 wa = w4[0], wbv = w4[1], wc = w4[2], wd = w4[3], we = w4[4];
    float w[20] = {wa.x,wa.y,wa.z,wa.w, wbv.x,wbv.y,wbv.z,wbv.w,
                   wc.x,wc.y,wc.z,wc.w, wd.x,wd.y,wd.z,wd.w,
                   we.x,we.y,we.z,we.w};
    float gs[4] = {gv.x, gv.y, gv.z, gv.w};
    #pragma unroll
    for (int tt = 0; tt < 4; ++tt)
      #pragma unroll
      for (int j = 0; j < 20; ++j) acc[tt][j] += gs[tt] * w[j];
  }
  // block reduce: 80 values x 256 threads, in 2 halves of 40
  #pragma unroll
  for (int half = 0; half < 2; ++half) {
    __syncthreads();
    #pragma unroll
    for (int mm = 0; mm < 40; ++mm) {
      int m = half * 40 + mm;
      red[mm * 257 + tid] = acc[m / 20][m % 20];
    }
    __syncthreads();
    #pragma unroll
    for (int s = 128; s >= 8; s >>= 1) {
      for (int i = tid; i < 40 * s; i += 256) {
        int rr = i / s, col = i - rr * s;
        red[rr * 257 + col] += red[rr * 257 + col + s];
      }
      __syncthreads();
    }
    if (tid < 40) {
      float v = 0.f;
      #pragma unroll
      for (int c = 0; c < 8; ++c) v += red[tid * 257 + c];
      int m = half * 40 + tid;
      int t = t0 + m / 20, j = m % 20;
      if (j < 10) atomicAdd(&s1[(b * T_ + t) * R_ + j], v);
      else        atomicAdd(&s2[(b * T_ + t) * R_ + (j - 10)], v);
    }
  }
}

__global__ __launch_bounds__(64) void tatt_softmax(
    const float* __restrict__ s1, const float* __restrict__ s2, float* __restrict__ Pt) {
  int b = blockIdx.x, t = threadIdx.x;
  if (t >= T_) return;
  float r1[R_];
  #pragma unroll
  for (int r = 0; r < R_; ++r) r1[r] = s1[(b * T_ + t) * R_ + r];
  const float scale = rsqrtf(64000.f);
  float row[T_]; float m = -1e30f;
  for (int j = 0; j < T_; ++j) {
    const float* s2r = s2 + (b * T_ + j) * R_;
    float d = 0.f;
    #pragma unroll
    for (int r = 0; r < R_; ++r) d += r1[r] * s2r[r];
    d *= scale; row[j] = d; m = fmaxf(m, d);
  }
  float s = 0.f;
  for (int j = 0; j < T_; ++j) { float e = __expf(row[j] - m); row[j] = e; s += e; }
  float inv = 1.f / s;
  for (int j = 0; j < T_; ++j) Pt[(b * T_ + t) * T_ + j] = row[j] * inv;
}

// writes x2 as packed bf16 (same f2b rounding tail_k used to apply on read)
__global__ __launch_bounds__(256) void tatt_apply(
    const float* __restrict__ g, const float* __restrict__ Pt, ushortt* __restrict__ x2b) {
  __shared__ float P[576];
  int b = blockIdx.y;
  for (int i = threadIdx.x; i < 576; i += 256) P[i] = Pt[b * 576 + i];
  __syncthreads();
  int row = blockIdx.x * 256 + threadIdx.x;
  const float* gp = g + ((size_t)b * 64000 + row) * T_;
  float gr[T_];
  ld24f32(gp, gr);
  float out[T_];
  #pragma unroll
  for (int t = 0; t < T_; ++t) {
    float a = 0.f;
    const float* Pr = &P[t * T_];
    #pragma unroll
    for (int j = 0; j < T_; ++j) a += Pr[j] * gr[j];
    out[t] = a;
  }
  u32 w[12];
  #pragma unroll
  for (int t = 0; t < 24; t += 2) w[t >> 1] = f2b_pair(out[t], out[t + 1]);
  ushortt* xp = x2b + ((size_t)b * 64000 + row) * 24;
  *(uint4*)&xp[0]  = make_uint4(w[0], w[1], w[2], w[3]);
  *(uint4*)&xp[8]  = make_uint4(w[4], w[5], w[6], w[7]);
  *(uint4*)&xp[16] = make_uint4(w[8], w[9], w[10], w[11]);
}

// ---------- stage 4 (MFMA tail): conv1 -> conv2 + res -> LN ----------
// grid (250, 8), 256 threads = 4 waves; wave w owns node nl=w (cols 32w..32w+31).
// Column layout per node: s=0,1 zero guards; s=2..25 <-> t=0..23; s=26..31 zero pad.
// ONE 32KB LDS union, timeline-overlaid:
//   phase 1: L0 = x2 row-staging, L1 = x row-staging
//   phase 2: L0 = X2c tile -> Y1c tile, L1 = Xrc tile
//   phase 3: preF = f32 [96][66] LN buffer (spans both halves)
// Final store is fully coalesced: one thread owns one 96B output row.
#define CSB 1024
#define RSB 104
#define PFS 66
__global__ __launch_bounds__(256, 4) void tail_k(
    const ushortt* __restrict__ x2b, const float* __restrict__ x,
    const ushortt* __restrict__ Wt,
    const float* __restrict__ c1b, const float* __restrict__ c2b,
    const float* __restrict__ rb,
    const float* __restrict__ lg, const float* __restrict__ lb,
    float* __restrict__ outp) {
  __shared__ __align__(16) ushortt LSH[16384];   // 32 KB union
  __shared__ float mu[96], rs[96];
  ushortt* L0 = LSH;
  ushortt* L1 = LSH + 8192;
  float* preF = (float*)LSH;                     // 96*66*4 = 25344 B
  int b = blockIdx.y, n0 = blockIdx.x * 4;
  int tid = threadIdx.x;
  int wave = tid >> 6, lane = tid & 63;
  int q = lane >> 4, l15 = lane & 15;

  // ---- stage A: coalesced block-strided loads into row-staging [64][RSB] ----
  #pragma unroll
  for (int rep = 0; rep < 3; ++rep) {
    int i = tid + rep * 256;                 // < 768 : x2b uint4 slots
    int c = i / 12, u = i - c * 12;
    const uint4* src = (const uint4*)(x2b + ((size_t)(b * 64 + c) * 1000 + n0) * 24);
    uint4 v = src[u];
    *(uint4*)&L0[c * RSB + u * 8] = v;
  }
  #pragma unroll
  for (int rep = 0; rep < 6; ++rep) {
    int i = tid + rep * 256;                 // < 1536 : x float4 slots
    int c = i / 24, qq = i - c * 24;
    const float4* src = (const float4*)(x + ((size_t)(b * 64 + c) * 1000 + n0) * 24);
    float4 v = src[qq];
    *(uint2*)&L1[c * RSB + qq * 4] = make_uint2(f2b_pair(v.x, v.y), f2b_pair(v.z, v.w));
  }
  __syncthreads();

  // ---- stage B: read x2 fragments (pa) from L0 row-staging ----
  u32 pa[4][4];
  int sKblk[4], sCol[4];
  #pragma unroll
  for (int rep = 0; rep < 4; ++rep) {
    int slot = tid + rep * 256;
    int kblk = slot >> 7, col = slot & 127;
    sKblk[rep] = kblk; sCol[rep] = col;
    int nl2 = col >> 5, s = col & 31;
    if (s >= 2 && s <= 25) {
      int boff = (kblk * 8) * RSB + nl2 * 24 + (s - 2);
      #pragma unroll
      for (int h = 0; h < 4; ++h) {
        u32 a0 = L0[boff + (2 * h) * RSB], a1 = L0[boff + (2 * h + 1) * RSB];
        pa[rep][h] = a0 | (a1 << 16);
      }
    } else {
      #pragma unroll
      for (int h = 0; h < 4; ++h) pa[rep][h] = 0u;
    }
  }
  __syncthreads();
  // write X2c tile into L0 (row-staging dead)
  #pragma unroll
  for (int rep = 0; rep < 4; ++rep)
    *(uint4*)&L0[sKblk[rep] * CSB + sCol[rep] * 8] =
        make_uint4(pa[rep][0], pa[rep][1], pa[rep][2], pa[rep][3]);
  __syncthreads();

  // ---- conv1 (X2c in L0) + read residual fragments (kb) from L1 ----
  f4v acc1[2][4];
  #pragma unroll
  for (int ct = 0; ct < 2; ++ct)
    #pragma unroll
    for (int mt = 0; mt < 4; ++mt) acc1[ct][mt] = (f4v){0.f, 0.f, 0.f, 0.f};
  #pragma unroll
  for (int ki = 0; ki < 2; ++ki) {
    bf8v a0[4], a1[4];
    #pragma unroll
    for (int mt = 0; mt < 4; ++mt) {
      a0[mt] = *(const bf8v*)&Wt[(mt * 16 + l15) * 64 + ki * 32 + q * 8];
      a1[mt] = *(const bf8v*)&Wt[4096 + (mt * 16 + l15) * 64 + ki * 32 + q * 8];
    }
    #pragma unroll
    for (int ct = 0; ct < 2; ++ct) {
      int col = wave * 32 + ct * 16 + l15;
      int colp = (col == 0) ? 0 : col - 1;
      bf8v bc = *(const bf8v*)&L0[(ki * 4 + q) * CSB + col * 8];
      bf8v bp = *(const bf8v*)&L0[(ki * 4 + q) * CSB + colp * 8];
      #pragma unroll
      for (int mt = 0; mt < 4; ++mt) {
        acc1[ct][mt] = __builtin_amdgcn_mfma_f32_16x16x32_bf16(a0[mt], bc, acc1[ct][mt], 0, 0, 0);
        acc1[ct][mt] = __builtin_amdgcn_mfma_f32_16x16x32_bf16(a1[mt], bp, acc1[ct][mt], 0, 0, 0);
      }
    }
  }
  u32 kb[4][4];
  #pragma unroll
  for (int rep = 0; rep < 4; ++rep) {
    int col = sCol[rep];
    int nl2 = col >> 5, s = col & 31;
    if (s >= 2 && s <= 25) {
      int boff = (sKblk[rep] * 8) * RSB + nl2 * 24 + (s - 2);
      #pragma unroll
      for (int h = 0; h < 4; ++h) {
        u32 b0 = L1[boff + (2 * h) * RSB], b1 = L1[boff + (2 * h + 1) * RSB];
        kb[rep][h] = b0 | (b1 << 16);
      }
    } else {
      #pragma unroll
      for (int h = 0; h < 4; ++h) kb[rep][h] = 0u;
    }
  }
  // epilogue 1 in regs: bias + relu (zeros in guard/pad cols)
  u32 ypack[2][4][2];
  #pragma unroll
  for (int ct = 0; ct < 2; ++ct) {
    int s = ct * 16 + l15;
    bool v = (s >= 2 && s <= 25);
    #pragma unroll
    for (int mt = 0; mt < 4; ++mt) {
      int o0 = mt * 16 + q * 4;
      float4 bb = *(const float4*)&c1b[o0];
      float y0 = v ? fmaxf(acc1[ct][mt][0] + bb.x, 0.f) : 0.f;
      float y1 = v ? fmaxf(acc1[ct][mt][1] + bb.y, 0.f) : 0.f;
      float y2 = v ? fmaxf(acc1[ct][mt][2] + bb.z, 0.f) : 0.f;
      float y3 = v ? fmaxf(acc1[ct][mt][3] + bb.w, 0.f) : 0.f;
      ypack[ct][mt][0] = f2b_pair(y0, y1);
      ypack[ct][mt][1] = f2b_pair(y2, y3);
    }
  }
  __syncthreads();   // all conv1 X2c reads + kb L1 reads done

  // ---- write Y1c -> L0 (over X2c), Xrc -> L1 (over x staging) ----
  #pragma unroll
  for (int ct = 0; ct < 2; ++ct) {
    int col = wave * 32 + ct * 16 + l15;
    #pragma unroll
    for (int mt = 0; mt < 4; ++mt) {
      int o0 = mt * 16 + q * 4;
      *(uint2*)&L0[(o0 >> 3) * CSB + col * 8 + (o0 & 7)] =
          make_uint2(ypack[ct][mt][0], ypack[ct][mt][1]);
    }
  }
  #pragma unroll
  for (int rep = 0; rep < 4; ++rep)
    *(uint4*)&L1[sKblk[rep] * CSB + sCol[rep] * 8] =
        make_uint4(kb[rep][0], kb[rep][1], kb[rep][2], kb[rep][3]);
  __syncthreads();

  // ---- conv2 (taps col, col-2 from Y1c=L0) + residual (Xrc=L1) ----
  f4v accA[2][4], accR[2][4];
  #pragma unroll
  for (int ct = 0; ct < 2; ++ct)
    #pragma unroll
    for (int mt = 0; mt < 4; ++mt) {
      accA[ct][mt] = (f4v){0.f, 0.f, 0.f, 0.f};
      accR[ct][mt] = (f4v){0.f, 0.f, 0.f, 0.f};
    }
  #pragma unroll
  for (int ki = 0; ki < 2; ++ki) {
    bf8v c0[4], c1t[4], rrf[4];
    #pragma unroll
    for (int mt = 0; mt < 4; ++mt) {
      c0[mt]  = *(const bf8v*)&Wt[8192 + (mt * 16 + l15) * 64 + ki * 32 + q * 8];
      c1t[mt] = *(const bf8v*)&Wt[12288 + (mt * 16 + l15) * 64 + ki * 32 + q * 8];
      rrf[mt] = *(const bf8v*)&Wt[16384 + (mt * 16 + l15) * 64 + ki * 32 + q * 8];
    }
    #pragma unroll
    for (int ct = 0; ct < 2; ++ct) {
      int col = wave * 32 + ct * 16 + l15;
      int colp2 = (col < 2) ? col : col - 2;
      bf8v bc = *(const bf8v*)&L0[(ki * 4 + q) * CSB + col * 8];
      bf8v bp = *(const bf8v*)&L0[(ki * 4 + q) * CSB + colp2 * 8];
      bf8v bx = *(const bf8v*)&L1[(ki * 4 + q) * CSB + col * 8];
      #pragma unroll
      for (int mt = 0; mt < 4; ++mt) {
        accA[ct][mt] = __builtin_amdgcn_mfma_f32_16x16x32_bf16(c0[mt], bc, accA[ct][mt], 0, 0, 0);
        accA[ct][mt] = __builtin_amdgcn_mfma_f32_16x16x32_bf16(c1t[mt], bp, accA[ct][mt], 0, 0, 0);
        accR[ct][mt] = __builtin_amdgcn_mfma_f32_16x16x32_bf16(rrf[mt], bx, accR[ct][mt], 0, 0, 0);
      }
    }
  }
  // epilogue 2: relu(conv2+b2) + (res+rb), relu -> pre (regs)
  float pre[2][4][4];
  #pragma unroll
  for (int ct = 0; ct < 2; ++ct) {
    #pragma unroll
    for (int mt = 0; mt < 4; ++mt) {
      int o0 = mt * 16 + q * 4;
      float4 b2 = *(const float4*)&c2b[o0];
      float4 rbv = *(const float4*)&rb[o0];
      float bb2[4] = {b2.x, b2.y, b2.z, b2.w};
      float brv[4] = {rbv.x, rbv.y, rbv.z, rbv.w};
      #pragma unroll
      for (int r = 0; r < 4; ++r) {
        float a = fmaxf(accA[ct][mt][r] + bb2[r], 0.f) + accR[ct][mt][r] + brv[r];
        pre[ct][mt][r] = fmaxf(a, 0.f);
      }
    }
  }
  __syncthreads();   // all conv2 L0/L1 reads done before preF overwrite

  // ---- preF (f32 [96][PFS]) spans the whole union ----
  #pragma unroll
  for (int ct = 0; ct < 2; ++ct) {
    int s = ct * 16 + l15;
    if (s >= 2 && s <= 25) {
      int p = wave * 24 + s - 2;
      #pragma unroll
      for (int mt = 0; mt < 4; ++mt) {
        int o0 = mt * 16 + q * 4;
        *(float2*)&preF[p * PFS + o0]     = make_float2(pre[ct][mt][0], pre[ct][mt][1]);
        *(float2*)&preF[p * PFS + o0 + 2] = make_float2(pre[ct][mt][2], pre[ct][mt][3]);
      }
    }
  }
  __syncthreads();
  // LN stats over o for each of 96 (node,t) pairs (f32)
  if (tid < 96) {
    const float* pr = &preF[tid * PFS];
    float sm = 0.f, qq = 0.f;
    #pragma unroll 16
    for (int c = 0; c < 64; ++c) {
      float v = pr[c];
      sm += v; qq += v * v;
    }
    float m = sm * (1.f / 64.f);
    mu[tid] = m;
    rs[tid] = rsqrtf(qq * (1.f / 64.f) - m * m + 1e-5f);
  }
  __syncthreads();
  // ---- coalesced store: thread owns one 96B output row (o, nl) ----
  {
    int o = tid >> 2, nl = tid & 3;
    float gam = lg[o], bet = lb[o];
    float vals[24];
    #pragma unroll
    for (int t = 0; t < 24; ++t) {
      int p = nl * 24 + t;
      vals[t] = (preF[p * PFS + o] - mu[p]) * rs[p] * gam + bet;
    }
    float* dst = outp + ((size_t)(b * 64 + o) * 1000 + n0 + nl) * 24;
    #pragma unroll
    for (int t = 0; t < 24; t += 4)
      *(float4*)&dst[t] = make_float4(vals[t], vals[t+1], vals[t+2], vals[t+3]);
  }
}

extern "C" void kernel_launch(void* const* d_in, const int* in_sizes, int n_in,
                              void* d_out, int out_size, void* d_ws, size_t ws_size,
                              hipStream_t stream) {
  const float* x     = (const float*)d_in[0];
  const float* Aadj  = (const float*)d_in[1];
  const float* a0W1  = (const float*)d_in[2];
  const float* a0W2  = (const float*)d_in[3];
  const float* gW1   = (const float*)d_in[4];
  const float* gW2   = (const float*)d_in[5];
  const float* gcnW  = (const float*)d_in[6];
  const float* tW1   = (const float*)d_in[7];
  const float* tW2   = (const float*)d_in[8];
  const float* c1w   = (const float*)d_in[9];
  const float* c1b   = (const float*)d_in[10];
  const float* c2w   = (const float*)d_in[11];
  const float* c2b   = (const float*)d_in[12];
  const float* rw    = (const float*)d_in[13];
  const float* rb    = (const float*)d_in[14];
  const float* lng   = (const float*)d_in[15];
  const float* lnb   = (const float*)d_in[16];
  float* out = (float*)d_out;

  float* ws = (float*)d_ws;
  float* R1   = ws;                    // 12,288,000: x1tr -> x2 (bf16 after tatt)
  float* U    = R1 + 12288000;         // 12,288,000: Xbt+Agb (bf16), later g (f32)
  float* D    = U + 12288000;          // 12,288,000: g1
  float* s1_0 = D + 12288000;          // 5120
  float* s2_0 = s1_0 + 5120;           // 5120
  float* P0   = s2_0 + 5120;           // 32768
  float* s1g  = P0 + 32768;            // 80000
  float* s2gT = s1g + 80000;           // 80000
  float* s1t  = s2gT + 80000;          // 1920
  float* s2t  = s1t + 1920;            // 1920
  float* Ptb  = s2t + 1920;            // 4608
  float* Wp0  = Ptb + 4608;            // 480000
  float* Wgp  = Wp0 + 480000;          // 30720
  float* Wtp  = Wgp + 30720;           // 1280000
  float* Wtl  = Wtp + 1280000;         // 10240 (20480 bf16 packed tail weights)
  ushortt* Xbt = (ushortt*)U;
  ushortt* Agb = (ushortt*)(U + 6291456);
  ushortt* Wtail = (ushortt*)Wtl;
  float* g = U;
  if (ws_size < (size_t)38876416 * 4) return;

  // weight packing
  pack_w<<<1875, 256, 0, stream>>>(a0W1, a0W2, Wp0, 24000);
  pack_w<<<120, 256, 0, stream>>>(gW1, gW2, Wgp, 1536);
  pack_w<<<5000, 256, 0, stream>>>(tW1, tW2, Wtp, 64000);
  pack_tailw<<<80, 256, 0, stream>>>(c1w, c2w, rw, Wtail);
  // stage 1: channel attention (split-K accumulate -> zero first)
  zerok<<<40, 256, 0, stream>>>(s1_0, 10240);
  att0_s12<<<dim3(128, 4), 256, 0, stream>>>(x, Wp0, s1_0, s2_0);
  att0_softmax<<<8, 64, 0, stream>>>(s1_0, s2_0, P0);
  att0_apply<<<dim3(250, 8), 256, 0, stream>>>(x, P0, R1);
  // stage 2: gated GCN
  gatt_s12<<<2000, 256, 0, stream>>>(R1, Wgp, s1g, s2gT);
  transpose_x1<<<dim3(24, 16, 8), 256, 0, stream>>>(R1, Xbt);
  gatt_scores<<<8000, 256, 0, stream>>>(s1g, s2gT, Aadj, Agb);
  gemm_mfma<<<dim3(12, 8, 8), 256, 0, stream>>>(Agb, Xbt, D);
  gcn_out<<<dim3(250, 8), 256, 0, stream>>>(D, gcnW, g);
  // stage 3: temporal attention (split-K accumulate -> zero first)
  zerok<<<15, 256, 0, stream>>>(s1t, 3840);
  tatt_s12<<<dim3(50, 6, 8), 256, 0, stream>>>(g, Wtp, s1t, s2t);
  tatt_softmax<<<8, 32, 0, stream>>>(s1t, s2t, Ptb);
  tatt_apply<<<dim3(250, 8), 256, 0, stream>>>(g, Ptb, (ushortt*)R1);
  // stage 4: MFMA tail + residual + LN
  tail_k<<<dim3(250, 8), 256, 0, stream>>>((const ushortt*)R1, x, Wtail,
                                           c1b, c2b, rb, lng, lnb, out);
}

// Round 6
// 536.671 us; speedup vs baseline: 1.0313x; 1.0289x over previous
//
#include <hip/hip_runtime.h>
#include <hip/hip_bf16.h>

typedef unsigned int u32;
typedef unsigned short ushortt;

#define B_  8
#define C_  64
#define N_  1000
#define T_  24
#define R_  10
#define NT_ 24000   // N*T
#define CT_ 1536    // C*T
#define NC_ 64000   // N*Co

typedef __attribute__((ext_vector_type(8))) short bf8v;
typedef __attribute__((ext_vector_type(4))) float f4v;

__device__ __forceinline__ ushortt f2b_bits(float f) {
  u32 x = __float_as_uint(f);
  u32 r = (x + 0x7fffu + ((x >> 16) & 1u)) >> 16;   // round-to-nearest-even
  return (ushortt)r;
}

__device__ __forceinline__ u32 f2b_pair(float a, float b) {
  return (u32)f2b_bits(a) | ((u32)f2b_bits(b) << 16);
}

__device__ __forceinline__ float blockSum256(float v, float* red) {
  red[threadIdx.x] = v; __syncthreads();
  #pragma unroll
  for (int s = 128; s > 0; s >>= 1) {
    if (threadIdx.x < s) red[threadIdx.x] += red[threadIdx.x + s];
    __syncthreads();
  }
  float r = red[0]; __syncthreads();
  return r;
}
__device__ __forceinline__ float blockMax256(float v, float* red) {
  red[threadIdx.x] = v; __syncthreads();
  #pragma unroll
  for (int s = 128; s > 0; s >>= 1) {
    if (threadIdx.x < s) red[threadIdx.x] = fmaxf(red[threadIdx.x], red[threadIdx.x + s]);
    __syncthreads();
  }
  float r = red[0]; __syncthreads();
  return r;
}

__device__ __forceinline__ void ld24f32(const float* p, float* v) {
  #pragma unroll
  for (int t = 0; t < 24; t += 4) {
    float4 f = *(const float4*)&p[t];
    v[t] = f.x; v[t+1] = f.y; v[t+2] = f.z; v[t+3] = f.w;
  }
}

// ---------- utility ----------
__global__ __launch_bounds__(256) void zerok(float* p, int n) {
  int i = blockIdx.x * 256 + threadIdx.x;
  if (i < n) p[i] = 0.f;
}

// pack W1[K][10] and W2[10][K] -> Wp[K][20]
__global__ __launch_bounds__(256) void pack_w(
    const float* __restrict__ W1, const float* __restrict__ W2,
    float* __restrict__ Wp, int K) {
  int i = blockIdx.x * 256 + threadIdx.x;
  if (i >= K * 20) return;
  int k = i / 20, r = i - k * 20;
  Wp[i] = (r < 10) ? W1[(size_t)k * 10 + r] : W2[(size_t)(r - 10) * K + k];
}

// pack tail weights to bf16 A-matrices:
// [0:8192)  Wc1b[2][64][64]  tap0 = c1w[...,1] (current), tap1 = c1w[...,0] (t-1)
// [8192:16384) Wc2b[2][64][64]
// [16384:20480) Wrb[64][64]
__global__ __launch_bounds__(256) void pack_tailw(
    const float* __restrict__ c1w, const float* __restrict__ c2w,
    const float* __restrict__ rw, ushortt* __restrict__ Wt) {
  int i = blockIdx.x * 256 + threadIdx.x;
  if (i >= 20480) return;
  float v;
  if (i < 8192) {
    int tap = i >> 12, o = (i >> 6) & 63, c = i & 63;
    v = c1w[(size_t)(o * 64 + c) * 2 + (tap ? 0 : 1)];
  } else if (i < 16384) {
    int j = i - 8192;
    int tap = j >> 12, o = (j >> 6) & 63, c = j & 63;
    v = c2w[(size_t)(o * 64 + c) * 2 + (tap ? 0 : 1)];
  } else {
    int j = i - 16384;
    v = rw[j];
  }
  Wt[i] = f2b_bits(v);
}

// ---------- stage 1: channel attention scores ----------
// Split-K tall-skinny GEMM: [512 x 24000] @ Wp[24000 x 20] -> s1/s2 (atomics).
__global__ __launch_bounds__(256) void att0_s12(
    const float* __restrict__ x, const float* __restrict__ Wp,
    float* __restrict__ s1, float* __restrict__ s2) {
  __shared__ float red[40 * 257];
  const int row0 = blockIdx.x * 4;
  const int kbase = blockIdx.y * 6000;
  const int tid = threadIdx.x;
  float acc[4][20];
  #pragma unroll
  for (int r = 0; r < 4; ++r)
    #pragma unroll
    for (int j = 0; j < 20; ++j) acc[r][j] = 0.f;
  const float* xb = x + (size_t)row0 * NT_ + kbase;
  const float4* wb4 = (const float4*)Wp + (size_t)kbase * 5;  // Wp[kbase*20]
  #pragma unroll 1
  for (int it = 0; it < 6; ++it) {
    int slot = tid + 256 * it;                 // float4-slot in chunk, < 1500
    if (slot < 1500) {
      int k = slot * 4;
      float4 xv0 = *(const float4*)&xb[k];
      float4 xv1 = *(const float4*)&xb[NT_ + k];
      float4 xv2 = *(const float4*)&xb[2 * NT_ + k];
      float4 xv3 = *(const float4*)&xb[3 * NT_ + k];
      const float4* w4 = wb4 + (size_t)slot * 20;   // 4 k's x 5 float4
      #pragma unroll
      for (int kk = 0; kk < 4; ++kk) {
        float4 wa = w4[kk * 5 + 0], wbv = w4[kk * 5 + 1], wc = w4[kk * 5 + 2],
               wd = w4[kk * 5 + 3], we = w4[kk * 5 + 4];
        float w[20] = {wa.x,wa.y,wa.z,wa.w, wbv.x,wbv.y,wbv.z,wbv.w,
                       wc.x,wc.y,wc.z,wc.w, wd.x,wd.y,wd.z,wd.w,
                       we.x,we.y,we.z,we.w};
        float xs0 = ((const float*)&xv0)[kk];
        float xs1 = ((const float*)&xv1)[kk];
        float xs2 = ((const float*)&xv2)[kk];
        float xs3 = ((const float*)&xv3)[kk];
        #pragma unroll
        for (int j = 0; j < 20; ++j) {
          acc[0][j] += xs0 * w[j];
          acc[1][j] += xs1 * w[j];
          acc[2][j] += xs2 * w[j];
          acc[3][j] += xs3 * w[j];
        }
      }
    }
  }
  // block reduce: 80 values x 256 threads, in 2 halves of 40
  #pragma unroll
  for (int half = 0; half < 2; ++half) {
    __syncthreads();
    #pragma unroll
    for (int mm = 0; mm < 40; ++mm) {
      int m = half * 40 + mm;
      red[mm * 257 + tid] = acc[m / 20][m % 20];
    }
    __syncthreads();
    #pragma unroll
    for (int s = 128; s >= 8; s >>= 1) {
      for (int i = tid; i < 40 * s; i += 256) {
        int rr = i / s, col = i - rr * s;
        red[rr * 257 + col] += red[rr * 257 + col + s];
      }
      __syncthreads();
    }
    if (tid < 40) {
      float v = 0.f;
      #pragma unroll
      for (int c = 0; c < 8; ++c) v += red[tid * 257 + c];
      int m = half * 40 + tid;
      int row = row0 + m / 20, j = m % 20;
      if (j < 10) atomicAdd(&s1[row * 10 + j], v);
      else        atomicAdd(&s2[row * 10 + (j - 10)], v);
    }
  }
}

__global__ __launch_bounds__(64) void att0_softmax(
    const float* __restrict__ s1, const float* __restrict__ s2, float* __restrict__ P) {
  int b = blockIdx.x, i = threadIdx.x;
  float r1[R_];
  #pragma unroll
  for (int r = 0; r < R_; ++r) r1[r] = s1[(b * 64 + i) * R_ + r];
  const float scale = rsqrtf(24000.f);
  float row[64]; float m = -1e30f;
  for (int j = 0; j < 64; ++j) {
    const float* s2r = s2 + (size_t)(b * 64 + j) * R_;
    float d = 0.f;
    #pragma unroll
    for (int r = 0; r < R_; ++r) d += r1[r] * s2r[r];
    d *= scale; row[j] = d; m = fmaxf(m, d);
  }
  float s = 0.f;
  for (int j = 0; j < 64; ++j) { float e = __expf(row[j] - m); row[j] = e; s += e; }
  float inv = 1.f / s;
  for (int j = 0; j < 64; ++j) P[((size_t)b * 64 + i) * 64 + j] = row[j] * inv;
}

__global__ __launch_bounds__(256) void att0_apply(
    const float* __restrict__ x, const float* __restrict__ P, float* __restrict__ x1tr) {
  __shared__ float Pss[4160];
  __shared__ float xt[6144];
  int b = blockIdx.y, n0 = blockIdx.x * 4;
  int tid = threadIdx.x;
  for (int i = tid; i < 4096; i += 256)
    Pss[(i >> 6) * 65 + (i & 63)] = P[(size_t)b * 4096 + i];
  {
    const float4* src4 = (const float4*)x;
    float4* dst4 = (float4*)xt;
    for (int i = tid; i < 1536; i += 256) {
      int j = i / 24, q = i - j * 24;
      dst4[i] = src4[(size_t)(b * 64 + j) * 6000 + n0 * 6 + q];
    }
  }
  __syncthreads();
  int ig = tid >> 4, ln = (tid >> 2) & 3, ts = tid & 3;
  float acc[4][6];
  #pragma unroll
  for (int ii = 0; ii < 4; ++ii)
    #pragma unroll
    for (int m = 0; m < 6; ++m) acc[ii][m] = 0.f;
  const float* base = &xt[ln * 24 + ts * 6];
  #pragma unroll 4
  for (int j = 0; j < 64; ++j) {
    float vj[6];
    #pragma unroll
    for (int m = 0; m < 6; ++m) vj[m] = base[j * 96 + m];
    #pragma unroll
    for (int ii = 0; ii < 4; ++ii) {
      float p = Pss[(ig * 4 + ii) * 65 + j];
      #pragma unroll
      for (int m = 0; m < 6; ++m) acc[ii][m] += p * vj[m];
    }
  }
  float* drow = x1tr + ((size_t)b * N_ + n0 + ln) * CT_ + ts * 6;
  #pragma unroll
  for (int ii = 0; ii < 4; ++ii) {
    float* d = drow + (ig * 4 + ii) * 24;
    *(float2*)&d[0] = make_float2(acc[ii][0], acc[ii][1]);
    *(float2*)&d[2] = make_float2(acc[ii][2], acc[ii][3]);
    *(float2*)&d[4] = make_float2(acc[ii][4], acc[ii][5]);
  }
}

// ---------- transpose x1tr -> Xbt bf16 ----------
__global__ __launch_bounds__(256) void transpose_x1(
    const float* __restrict__ x1tr, ushortt* __restrict__ Xbt) {
  __shared__ float s[64][65];
  int b = blockIdx.z, n0 = blockIdx.y * 64, c0 = blockIdx.x * 64;
  int tid = threadIdx.x;
  int r = tid >> 2, cc = (tid & 3) * 16;
  if (n0 + r < N_) {
    const float* src = x1tr + ((size_t)b * N_ + n0 + r) * CT_ + c0 + cc;
    #pragma unroll
    for (int i = 0; i < 16; i += 4) {
      float4 v = *(const float4*)&src[i];
      s[r][cc + i] = v.x; s[r][cc + i + 1] = v.y;
      s[r][cc + i + 2] = v.z; s[r][cc + i + 3] = v.w;
    }
  } else {
    #pragma unroll
    for (int i = 0; i < 16; ++i) s[r][cc + i] = 0.f;
  }
  __syncthreads();
  ushortt* dst = Xbt + ((size_t)b * CT_ + c0 + r) * 1024 + n0 + cc;
  #pragma unroll
  for (int i = 0; i < 16; ++i) dst[i] = f2b_bits(s[cc + i][r]);
}

// ---------- stage 2: gate scores ----------
__global__ __launch_bounds__(256) void gatt_s12(
    const float* __restrict__ xg, const float* __restrict__ Wp,
    float* __restrict__ s1, float* __restrict__ s2T) {
  __shared__ float xs[6144];
  __shared__ float red[5120];
  int bn0 = blockIdx.x * 4;
  int tid = threadIdx.x;
  {
    const float4* src4 = (const float4*)(xg + (size_t)bn0 * CT_);
    float4* dst4 = (float4*)xs;
    for (int i = tid; i < 1536; i += 256) dst4[i] = src4[i];
  }
  __syncthreads();
  int rid = tid >> 6, ks = tid & 63;
  float a[20];
  #pragma unroll
  for (int r = 0; r < 20; ++r) a[r] = 0.f;
  for (int k = ks; k < CT_; k += 64) {
    float xv = xs[rid * CT_ + k];
    const float4* wp4 = (const float4*)&Wp[(size_t)k * 20];
    float4 wa = wp4[0], wb = wp4[1], wc = wp4[2], wd = wp4[3], we = wp4[4];
    float wv[20] = {wa.x,wa.y,wa.z,wa.w, wb.x,wb.y,wb.z,wb.w, wc.x,wc.y,wc.z,wc.w,
                    wd.x,wd.y,wd.z,wd.w, we.x,we.y,we.z,we.w};
    #pragma unroll
    for (int r = 0; r < 20; ++r) a[r] += xv * wv[r];
  }
  #pragma unroll
  for (int r = 0; r < 20; ++r) red[tid * 20 + r] = a[r];
  __syncthreads();
  if (tid < 80) {
    int rid2 = tid / 20, r = tid % 20;
    float s = 0.f;
    for (int l = 0; l < 64; ++l) s += red[(rid2 * 64 + l) * 20 + r];
    int row = bn0 + rid2;
    int b = row / N_, n = row - b * N_;
    if (r < 10) s1[row * 10 + r] = s;
    else        s2T[((size_t)b * 10 + (r - 10)) * N_ + n] = s;
  }
}

__global__ __launch_bounds__(256) void gatt_scores(
    const float* __restrict__ s1, const float* __restrict__ s2T,
    const float* __restrict__ Aadj, ushortt* __restrict__ Agb) {
  __shared__ float p[N_];
  __shared__ float r1[R_];
  __shared__ float red[256];
  int b = blockIdx.x / N_, n = blockIdx.x % N_;
  if (threadIdx.x < R_) r1[threadIdx.x] = s1[((size_t)b * N_ + n) * R_ + threadIdx.x];
  __syncthreads();
  const float scale = rsqrtf(1536.f);
  const float* s2b = s2T + (size_t)b * 10 * N_;
  float lmax = -1e30f;
  for (int m = threadIdx.x; m < N_; m += 256) {
    float d = 0.f;
    #pragma unroll
    for (int r = 0; r < R_; ++r) d += r1[r] * s2b[r * N_ + m];
    d *= scale; p[m] = d; lmax = fmaxf(lmax, d);
  }
  float gmax = blockMax256(lmax, red);
  float lsum = 0.f;
  for (int m = threadIdx.x; m < N_; m += 256) {
    float e = __expf(p[m] - gmax); p[m] = e; lsum += e;
  }
  float gsum = blockSum256(lsum, red);
  float inv = 1.f / gsum;
  ushortt* agr = Agb + ((size_t)b * 1024 + n) * 1024;
  const float* ar = Aadj + (size_t)n * N_;
  for (int m = threadIdx.x; m < 1024; m += 256) {
    float v = (m < N_) ? p[m] * inv * ar[m] : 0.f;
    agr[m] = f2b_bits(v);
  }
}

// ---------- batched MFMA GEMM (double-buffered prefetch, T3 2-phase) ----------
// Per K-step: STAGE(next tile) -> ds_read(cur) -> 16 MFMA -> syncthreads -> flip.
// The prefetch's HBM latency hides under the current tile's LDS reads + MFMA;
// one vmcnt(0)+barrier per K-step (was: drain BEFORE compute, zero overlap).
__global__ __launch_bounds__(256) void gemm_mfma(
    const ushortt* __restrict__ Agb, const ushortt* __restrict__ Xbt,
    float* __restrict__ g1) {
  __shared__ ushortt As[2][4096];
  __shared__ ushortt Bs[2][4096];
  const int b = blockIdx.z;
  const int n0 = blockIdx.x * 128;
  const int m0 = blockIdx.y * 128;
  const ushortt* Ab = Agb + (size_t)b * 1024 * 1024;
  const ushortt* Bb = Xbt + (size_t)b * 1536 * 1024;
  const int tid = threadIdx.x;
  const int wave = tid >> 6, lane = tid & 63;
  const int wr = (wave >> 1) * 64, wc = (wave & 1) * 64;
  const int lrow = lane >> 2;
  const int lcol = (lane & 3) * 8;
  const int q = lane >> 4, l15 = lane & 15;

  f4v acc[4][4];
  #pragma unroll
  for (int i = 0; i < 4; ++i)
    #pragma unroll
    for (int j = 0; j < 4; ++j) acc[i][j] = (f4v){0.f, 0.f, 0.f, 0.f};

  const ushortt* gA = Ab + (size_t)(m0 + wave * 16 + lrow) * 1024 + lcol;
  const ushortt* gB = Bb + (size_t)(n0 + wave * 16 + lrow) * 1024 + lcol;

#define GM_STAGE(buf, kk)                                                     \
  do {                                                                        \
    __builtin_amdgcn_global_load_lds(                                         \
      (const __attribute__((address_space(1))) void*)(gA + (kk)),             \
      (__attribute__((address_space(3))) void*)(&As[buf][wave * 512]), 16, 0, 0); \
    __builtin_amdgcn_global_load_lds(                                         \
      (const __attribute__((address_space(1))) void*)(gA + (size_t)64 * 1024 + (kk)), \
      (__attribute__((address_space(3))) void*)(&As[buf][wave * 512 + 2048]), 16, 0, 0); \
    __builtin_amdgcn_global_load_lds(                                         \
      (const __attribute__((address_space(1))) void*)(gB + (kk)),             \
      (__attribute__((address_space(3))) void*)(&Bs[buf][wave * 512]), 16, 0, 0); \
    __builtin_amdgcn_global_load_lds(                                         \
      (const __attribute__((address_space(1))) void*)(gB + (size_t)64 * 1024 + (kk)), \
      (__attribute__((address_space(3))) void*)(&Bs[buf][wave * 512 + 2048]), 16, 0, 0); \
  } while (0)

  GM_STAGE(0, 0);
  __syncthreads();
  int cur = 0;
  for (int k0 = 0; k0 < 1024; k0 += 32) {
    int nxt = cur ^ 1;
    if (k0 + 32 < 1024) GM_STAGE(nxt, k0 + 32);
    bf8v af[4], bfr[4];
    #pragma unroll
    for (int i = 0; i < 4; ++i)
      af[i] = *(const bf8v*)&As[cur][(wr + i * 16 + l15) * 32 + q * 8];
    #pragma unroll
    for (int j = 0; j < 4; ++j)
      bfr[j] = *(const bf8v*)&Bs[cur][(wc + j * 16 + l15) * 32 + q * 8];
    #pragma unroll
    for (int i = 0; i < 4; ++i)
      #pragma unroll
      for (int j = 0; j < 4; ++j)
        acc[i][j] = __builtin_amdgcn_mfma_f32_16x16x32_bf16(af[i], bfr[j], acc[i][j], 0, 0, 0);
    __syncthreads();
    cur = nxt;
  }
#undef GM_STAGE
  #pragma unroll
  for (int i = 0; i < 4; ++i) {
    int rbase = m0 + wr + i * 16 + q * 4;
    #pragma unroll
    for (int r = 0; r < 4; ++r) {
      int gm = rbase + r;
      if (gm < N_) {
        float* dst = g1 + ((size_t)b * N_ + gm) * CT_ + n0 + wc + l15;
        #pragma unroll
        for (int j = 0; j < 4; ++j) dst[j * 16] = acc[i][j][r];
      }
    }
  }
}

// ---------- gcn_out ----------
__global__ __launch_bounds__(256) void gcn_out(
    const float* __restrict__ g1, const float* __restrict__ W, float* __restrict__ g) {
  __shared__ float gs[6160];
  __shared__ float Ws[4096];
  int b = blockIdx.y, n0 = blockIdx.x * 4;
  int tid = threadIdx.x;
  {
    const float4* src4 = (const float4*)g1;
    float4* dst4 = (float4*)gs;
    for (int i = tid; i < 1536; i += 256) {
      int ln = i / 384, q = i - ln * 384;
      dst4[ln * 385 + q] = src4[(size_t)(b * N_ + n0 + ln) * 384 + q];
    }
  }
  for (int i = tid; i < 4096; i += 256) Ws[i] = W[i];
  __syncthreads();
  int og = tid >> 4, ln = (tid >> 2) & 3, ts = tid & 3;
  float acc[4][6];
  #pragma unroll
  for (int oo = 0; oo < 4; ++oo)
    #pragma unroll
    for (int m = 0; m < 6; ++m) acc[oo][m] = 0.f;
  const float* base = &gs[ln * 1540 + ts * 6];
  #pragma unroll 4
  for (int c = 0; c < 64; ++c) {
    float v[6];
    #pragma unroll
    for (int m = 0; m < 6; ++m) v[m] = base[c * 24 + m];
    float4 w4 = *(const float4*)&Ws[c * 64 + og * 4];
    float wv[4] = {w4.x, w4.y, w4.z, w4.w};
    #pragma unroll
    for (int oo = 0; oo < 4; ++oo)
      #pragma unroll
      for (int m = 0; m < 6; ++m) acc[oo][m] += wv[oo] * v[m];
  }
  #pragma unroll
  for (int oo = 0; oo < 4; ++oo) {
    int o = og * 4 + oo;
    float* d = g + (((size_t)(b * C_ + o)) * N_ + n0 + ln) * T_ + ts * 6;
    *(float2*)&d[0] = make_float2(acc[oo][0], acc[oo][1]);
    *(float2*)&d[2] = make_float2(acc[oo][2], acc[oo][3]);
    *(float2*)&d[4] = make_float2(acc[oo][4], acc[oo][5]);
  }
}

// ---------- stage 3: temporal attention scores ----------
__global__ __launch_bounds__(256) void tatt_s12(
    const float* __restrict__ g, const float* __restrict__ Wp,
    float* __restrict__ s1, float* __restrict__ s2) {
  __shared__ float red[40 * 257];
  const int b = blockIdx.z, t0 = blockIdx.y * 4, n0 = blockIdx.x * 20;
  const int tid = threadIdx.x;
  const int o = tid & 63, nl = tid >> 6;
  float acc[4][20];
  #pragma unroll
  for (int tt = 0; tt < 4; ++tt)
    #pragma unroll
    for (int j = 0; j < 20; ++j) acc[tt][j] = 0.f;
  const float* gb = g + (size_t)(b * 64 + o) * NT_ + t0;
  #pragma unroll 1
  for (int it = 0; it < 5; ++it) {
    int n = n0 + it * 4 + nl;
    float4 gv = *(const float4*)&gb[n * 24];
    const float4* w4 = (const float4*)&Wp[(size_t)(n * 64 + o) * 20];
    float4 wa = w4[0], wbv = w4[1], wc = w4[2], wd = w4[3], we = w4[4];
    float w[20] = {wa.x,wa.y,wa.z,wa.w, wbv.x,wbv.y,wbv.z,wbv.w,
                   wc.x,wc.y,wc.z,wc.w, wd.x,wd.y,wd.z,wd.w,
                   we.x,we.y,we.z,we.w};
    float gs[4] = {gv.x, gv.y, gv.z, gv.w};
    #pragma unroll
    for (int tt = 0; tt < 4; ++tt)
      #pragma unroll
      for (int j = 0; j < 20; ++j) acc[tt][j] += gs[tt] * w[j];
  }
  // block reduce: 80 values x 256 threads, in 2 halves of 40
  #pragma unroll
  for (int half = 0; half < 2; ++half) {
    __syncthreads();
    #pragma unroll
    for (int mm = 0; mm < 40; ++mm) {
      int m = half * 40 + mm;
      red[mm * 257 + tid] = acc[m / 20][m % 20];
    }
    __syncthreads();
    #pragma unroll
    for (int s = 128; s >= 8; s >>= 1) {
      for (int i = tid; i < 40 * s; i += 256) {
        int rr = i / s, col = i - rr * s;
        red[rr * 257 + col] += red[rr * 257 + col + s];
      }
      __syncthreads();
    }
    if (tid < 40) {
      float v = 0.f;
      #pragma unroll
      for (int c = 0; c < 8; ++c) v += red[tid * 257 + c];
      int m = half * 40 + tid;
      int t = t0 + m / 20, j = m % 20;
      if (j < 10) atomicAdd(&s1[(b * T_ + t) * R_ + j], v);
      else        atomicAdd(&s2[(b * T_ + t) * R_ + (j - 10)], v);
    }
  }
}

__global__ __launch_bounds__(64) void tatt_softmax(
    const float* __restrict__ s1, const float* __restrict__ s2, float* __restrict__ Pt) {
  int b = blockIdx.x, t = threadIdx.x;
  if (t >= T_) return;
  float r1[R_];
  #pragma unroll
  for (int r = 0; r < R_; ++r) r1[r] = s1[(b * T_ + t) * R_ + r];
  const float scale = rsqrtf(64000.f);
  float row[T_]; float m = -1e30f;
  for (int j = 0; j < T_; ++j) {
    const float* s2r = s2 + (b * T_ + j) * R_;
    float d = 0.f;
    #pragma unroll
    for (int r = 0; r < R_; ++r) d += r1[r] * s2r[r];
    d *= scale; row[j] = d; m = fmaxf(m, d);
  }
  float s = 0.f;
  for (int j = 0; j < T_; ++j) { float e = __expf(row[j] - m); row[j] = e; s += e; }
  float inv = 1.f / s;
  for (int j = 0; j < T_; ++j) Pt[(b * T_ + t) * T_ + j] = row[j] * inv;
}

// writes x2 as packed bf16 (same f2b rounding tail_k used to apply on read)
__global__ __launch_bounds__(256) void tatt_apply(
    const float* __restrict__ g, const float* __restrict__ Pt, ushortt* __restrict__ x2b) {
  __shared__ float P[576];
  int b = blockIdx.y;
  for (int i = threadIdx.x; i < 576; i += 256) P[i] = Pt[b * 576 + i];
  __syncthreads();
  int row = blockIdx.x * 256 + threadIdx.x;
  const float* gp = g + ((size_t)b * 64000 + row) * T_;
  float gr[T_];
  ld24f32(gp, gr);
  float out[T_];
  #pragma unroll
  for (int t = 0; t < T_; ++t) {
    float a = 0.f;
    const float* Pr = &P[t * T_];
    #pragma unroll
    for (int j = 0; j < T_; ++j) a += Pr[j] * gr[j];
    out[t] = a;
  }
  u32 w[12];
  #pragma unroll
  for (int t = 0; t < 24; t += 2) w[t >> 1] = f2b_pair(out[t], out[t + 1]);
  ushortt* xp = x2b + ((size_t)b * 64000 + row) * 24;
  *(uint4*)&xp[0]  = make_uint4(w[0], w[1], w[2], w[3]);
  *(uint4*)&xp[8]  = make_uint4(w[4], w[5], w[6], w[7]);
  *(uint4*)&xp[16] = make_uint4(w[8], w[9], w[10], w[11]);
}

// ---------- stage 4 (MFMA tail): conv1 -> conv2 + res -> LN ----------
// grid (250, 8), 256 threads = 4 waves; wave w owns node nl=w (cols 32w..32w+31).
// Column layout per node: s=0,1 zero guards; s=2..25 <-> t=0..23; s=26..31 zero pad.
// ONE 32KB LDS union, timeline-overlaid:
//   phase 1: L0 = x2 row-staging, L1 = x row-staging
//   phase 2: L0 = X2c tile -> Y1c tile, L1 = Xrc tile
//   phase 3: preF = f32 [96][66] LN buffer (spans both halves)
// Final store is fully coalesced: one thread owns one 96B output row.
#define CSB 1024
#define RSB 104
#define PFS 66
__global__ __launch_bounds__(256, 4) void tail_k(
    const ushortt* __restrict__ x2b, const float* __restrict__ x,
    const ushortt* __restrict__ Wt,
    const float* __restrict__ c1b, const float* __restrict__ c2b,
    const float* __restrict__ rb,
    const float* __restrict__ lg, const float* __restrict__ lb,
    float* __restrict__ outp) {
  __shared__ __align__(16) ushortt LSH[16384];   // 32 KB union
  __shared__ float mu[96], rs[96];
  ushortt* L0 = LSH;
  ushortt* L1 = LSH + 8192;
  float* preF = (float*)LSH;                     // 96*66*4 = 25344 B
  int b = blockIdx.y, n0 = blockIdx.x * 4;
  int tid = threadIdx.x;
  int wave = tid >> 6, lane = tid & 63;
  int q = lane >> 4, l15 = lane & 15;

  // ---- stage A: coalesced block-strided loads into row-staging [64][RSB] ----
  #pragma unroll
  for (int rep = 0; rep < 3; ++rep) {
    int i = tid + rep * 256;                 // < 768 : x2b uint4 slots
    int c = i / 12, u = i - c * 12;
    const uint4* src = (const uint4*)(x2b + ((size_t)(b * 64 + c) * 1000 + n0) * 24);
    uint4 v = src[u];
    *(uint4*)&L0[c * RSB + u * 8] = v;
  }
  #pragma unroll
  for (int rep = 0; rep < 6; ++rep) {
    int i = tid + rep * 256;                 // < 1536 : x float4 slots
    int c = i / 24, qq = i - c * 24;
    const float4* src = (const float4*)(x + ((size_t)(b * 64 + c) * 1000 + n0) * 24);
    float4 v = src[qq];
    *(uint2*)&L1[c * RSB + qq * 4] = make_uint2(f2b_pair(v.x, v.y), f2b_pair(v.z, v.w));
  }
  __syncthreads();

  // ---- stage B: read x2 fragments (pa) from L0 row-staging ----
  u32 pa[4][4];
  int sKblk[4], sCol[4];
  #pragma unroll
  for (int rep = 0; rep < 4; ++rep) {
    int slot = tid + rep * 256;
    int kblk = slot >> 7, col = slot & 127;
    sKblk[rep] = kblk; sCol[rep] = col;
    int nl2 = col >> 5, s = col & 31;
    if (s >= 2 && s <= 25) {
      int boff = (kblk * 8) * RSB + nl2 * 24 + (s - 2);
      #pragma unroll
      for (int h = 0; h < 4; ++h) {
        u32 a0 = L0[boff + (2 * h) * RSB], a1 = L0[boff + (2 * h + 1) * RSB];
        pa[rep][h] = a0 | (a1 << 16);
      }
    } else {
      #pragma unroll
      for (int h = 0; h < 4; ++h) pa[rep][h] = 0u;
    }
  }
  __syncthreads();
  // write X2c tile into L0 (row-staging dead)
  #pragma unroll
  for (int rep = 0; rep < 4; ++rep)
    *(uint4*)&L0[sKblk[rep] * CSB + sCol[rep] * 8] =
        make_uint4(pa[rep][0], pa[rep][1], pa[rep][2], pa[rep][3]);
  __syncthreads();

  // ---- conv1 (X2c in L0) + read residual fragments (kb) from L1 ----
  f4v acc1[2][4];
  #pragma unroll
  for (int ct = 0; ct < 2; ++ct)
    #pragma unroll
    for (int mt = 0; mt < 4; ++mt) acc1[ct][mt] = (f4v){0.f, 0.f, 0.f, 0.f};
  #pragma unroll
  for (int ki = 0; ki < 2; ++ki) {
    bf8v a0[4], a1[4];
    #pragma unroll
    for (int mt = 0; mt < 4; ++mt) {
      a0[mt] = *(const bf8v*)&Wt[(mt * 16 + l15) * 64 + ki * 32 + q * 8];
      a1[mt] = *(const bf8v*)&Wt[4096 + (mt * 16 + l15) * 64 + ki * 32 + q * 8];
    }
    #pragma unroll
    for (int ct = 0; ct < 2; ++ct) {
      int col = wave * 32 + ct * 16 + l15;
      int colp = (col == 0) ? 0 : col - 1;
      bf8v bc = *(const bf8v*)&L0[(ki * 4 + q) * CSB + col * 8];
      bf8v bp = *(const bf8v*)&L0[(ki * 4 + q) * CSB + colp * 8];
      #pragma unroll
      for (int mt = 0; mt < 4; ++mt) {
        acc1[ct][mt] = __builtin_amdgcn_mfma_f32_16x16x32_bf16(a0[mt], bc, acc1[ct][mt], 0, 0, 0);
        acc1[ct][mt] = __builtin_amdgcn_mfma_f32_16x16x32_bf16(a1[mt], bp, acc1[ct][mt], 0, 0, 0);
      }
    }
  }
  u32 kb[4][4];
  #pragma unroll
  for (int rep = 0; rep < 4; ++rep) {
    int col = sCol[rep];
    int nl2 = col >> 5, s = col & 31;
    if (s >= 2 && s <= 25) {
      int boff = (sKblk[rep] * 8) * RSB + nl2 * 24 + (s - 2);
      #pragma unroll
      for (int h = 0; h < 4; ++h) {
        u32 b0 = L1[boff + (2 * h) * RSB], b1 = L1[boff + (2 * h + 1) * RSB];
        kb[rep][h] = b0 | (b1 << 16);
      }
    } else {
      #pragma unroll
      for (int h = 0; h < 4; ++h) kb[rep][h] = 0u;
    }
  }
  // epilogue 1 in regs: bias + relu (zeros in guard/pad cols)
  u32 ypack[2][4][2];
  #pragma unroll
  for (int ct = 0; ct < 2; ++ct) {
    int s = ct * 16 + l15;
    bool v = (s >= 2 && s <= 25);
    #pragma unroll
    for (int mt = 0; mt < 4; ++mt) {
      int o0 = mt * 16 + q * 4;
      float4 bb = *(const float4*)&c1b[o0];
      float y0 = v ? fmaxf(acc1[ct][mt][0] + bb.x, 0.f) : 0.f;
      float y1 = v ? fmaxf(acc1[ct][mt][1] + bb.y, 0.f) : 0.f;
      float y2 = v ? fmaxf(acc1[ct][mt][2] + bb.z, 0.f) : 0.f;
      float y3 = v ? fmaxf(acc1[ct][mt][3] + bb.w, 0.f) : 0.f;
      ypack[ct][mt][0] = f2b_pair(y0, y1);
      ypack[ct][mt][1] = f2b_pair(y2, y3);
    }
  }
  __syncthreads();   // all conv1 X2c reads + kb L1 reads done

  // ---- write Y1c -> L0 (over X2c), Xrc -> L1 (over x staging) ----
  #pragma unroll
  for (int ct = 0; ct < 2; ++ct) {
    int col = wave * 32 + ct * 16 + l15;
    #pragma unroll
    for (int mt = 0; mt < 4; ++mt) {
      int o0 = mt * 16 + q * 4;
      *(uint2*)&L0[(o0 >> 3) * CSB + col * 8 + (o0 & 7)] =
          make_uint2(ypack[ct][mt][0], ypack[ct][mt][1]);
    }
  }
  #pragma unroll
  for (int rep = 0; rep < 4; ++rep)
    *(uint4*)&L1[sKblk[rep] * CSB + sCol[rep] * 8] =
        make_uint4(kb[rep][0], kb[rep][1], kb[rep][2], kb[rep][3]);
  __syncthreads();

  // ---- conv2 (taps col, col-2 from Y1c=L0) + residual (Xrc=L1) ----
  f4v accA[2][4], accR[2][4];
  #pragma unroll
  for (int ct = 0; ct < 2; ++ct)
    #pragma unroll
    for (int mt = 0; mt < 4; ++mt) {
      accA[ct][mt] = (f4v){0.f, 0.f, 0.f, 0.f};
      accR[ct][mt] = (f4v){0.f, 0.f, 0.f, 0.f};
    }
  #pragma unroll
  for (int ki = 0; ki < 2; ++ki) {
    bf8v c0[4], c1t[4], rrf[4];
    #pragma unroll
    for (int mt = 0; mt < 4; ++mt) {
      c0[mt]  = *(const bf8v*)&Wt[8192 + (mt * 16 + l15) * 64 + ki * 32 + q * 8];
      c1t[mt] = *(const bf8v*)&Wt[12288 + (mt * 16 + l15) * 64 + ki * 32 + q * 8];
      rrf[mt] = *(const bf8v*)&Wt[16384 + (mt * 16 + l15) * 64 + ki * 32 + q * 8];
    }
    #pragma unroll
    for (int ct = 0; ct < 2; ++ct) {
      int col = wave * 32 + ct * 16 + l15;
      int colp2 = (col < 2) ? col : col - 2;
      bf8v bc = *(const bf8v*)&L0[(ki * 4 + q) * CSB + col * 8];
      bf8v bp = *(const bf8v*)&L0[(ki * 4 + q) * CSB + colp2 * 8];
      bf8v bx = *(const bf8v*)&L1[(ki * 4 + q) * CSB + col * 8];
      #pragma unroll
      for (int mt = 0; mt < 4; ++mt) {
        accA[ct][mt] = __builtin_amdgcn_mfma_f32_16x16x32_bf16(c0[mt], bc, accA[ct][mt], 0, 0, 0);
        accA[ct][mt] = __builtin_amdgcn_mfma_f32_16x16x32_bf16(c1t[mt], bp, accA[ct][mt], 0, 0, 0);
        accR[ct][mt] = __builtin_amdgcn_mfma_f32_16x16x32_bf16(rrf[mt], bx, accR[ct][mt], 0, 0, 0);
      }
    }
  }
  // epilogue 2: relu(conv2+b2) + (res+rb), relu -> pre (regs)
  float pre[2][4][4];
  #pragma unroll
  for (int ct = 0; ct < 2; ++ct) {
    #pragma unroll
    for (int mt = 0; mt < 4; ++mt) {
      int o0 = mt * 16 + q * 4;
      float4 b2 = *(const float4*)&c2b[o0];
      float4 rbv = *(const float4*)&rb[o0];
      float bb2[4] = {b2.x, b2.y, b2.z, b2.w};
      float brv[4] = {rbv.x, rbv.y, rbv.z, rbv.w};
      #pragma unroll
      for (int r = 0; r < 4; ++r) {
        float a = fmaxf(accA[ct][mt][r] + bb2[r], 0.f) + accR[ct][mt][r] + brv[r];
        pre[ct][mt][r] = fmaxf(a, 0.f);
      }
    }
  }
  __syncthreads();   // all conv2 L0/L1 reads done before preF overwrite

  // ---- preF (f32 [96][PFS]) spans the whole union ----
  #pragma unroll
  for (int ct = 0; ct < 2; ++ct) {
    int s = ct * 16 + l15;
    if (s >= 2 && s <= 25) {
      int p = wave * 24 + s - 2;
      #pragma unroll
      for (int mt = 0; mt < 4; ++mt) {
        int o0 = mt * 16 + q * 4;
        *(float2*)&preF[p * PFS + o0]     = make_float2(pre[ct][mt][0], pre[ct][mt][1]);
        *(float2*)&preF[p * PFS + o0 + 2] = make_float2(pre[ct][mt][2], pre[ct][mt][3]);
      }
    }
  }
  __syncthreads();
  // LN stats over o for each of 96 (node,t) pairs (f32)
  if (tid < 96) {
    const float* pr = &preF[tid * PFS];
    float sm = 0.f, qq = 0.f;
    #pragma unroll 16
    for (int c = 0; c < 64; ++c) {
      float v = pr[c];
      sm += v; qq += v * v;
    }
    float m = sm * (1.f / 64.f);
    mu[tid] = m;
    rs[tid] = rsqrtf(qq * (1.f / 64.f) - m * m + 1e-5f);
  }
  __syncthreads();
  // ---- coalesced store: thread owns one 96B output row (o, nl) ----
  {
    int o = tid >> 2, nl = tid & 3;
    float gam = lg[o], bet = lb[o];
    float vals[24];
    #pragma unroll
    for (int t = 0; t < 24; ++t) {
      int p = nl * 24 + t;
      vals[t] = (preF[p * PFS + o] - mu[p]) * rs[p] * gam + bet;
    }
    float* dst = outp + ((size_t)(b * 64 + o) * 1000 + n0 + nl) * 24;
    #pragma unroll
    for (int t = 0; t < 24; t += 4)
      *(float4*)&dst[t] = make_float4(vals[t], vals[t+1], vals[t+2], vals[t+3]);
  }
}

extern "C" void kernel_launch(void* const* d_in, const int* in_sizes, int n_in,
                              void* d_out, int out_size, void* d_ws, size_t ws_size,
                              hipStream_t stream) {
  const float* x     = (const float*)d_in[0];
  const float* Aadj  = (const float*)d_in[1];
  const float* a0W1  = (const float*)d_in[2];
  const float* a0W2  = (const float*)d_in[3];
  const float* gW1   = (const float*)d_in[4];
  const float* gW2   = (const float*)d_in[5];
  const float* gcnW  = (const float*)d_in[6];
  const float* tW1   = (const float*)d_in[7];
  const float* tW2   = (const float*)d_in[8];
  const float* c1w   = (const float*)d_in[9];
  const float* c1b   = (const float*)d_in[10];
  const float* c2w   = (const float*)d_in[11];
  const float* c2b   = (const float*)d_in[12];
  const float* rw    = (const float*)d_in[13];
  const float* rb    = (const float*)d_in[14];
  const float* lng   = (const float*)d_in[15];
  const float* lnb   = (const float*)d_in[16];
  float* out = (float*)d_out;

  float* ws = (float*)d_ws;
  float* R1   = ws;                    // 12,288,000: x1tr -> x2 (bf16 after tatt)
  float* U    = R1 + 12288000;         // 12,288,000: Xbt+Agb (bf16), later g (f32)
  float* D    = U + 12288000;          // 12,288,000: g1
  float* s1_0 = D + 12288000;          // 5120
  float* s2_0 = s1_0 + 5120;           // 5120
  float* P0   = s2_0 + 5120;           // 32768
  float* s1g  = P0 + 32768;            // 80000
  float* s2gT = s1g + 80000;           // 80000
  float* s1t  = s2gT + 80000;          // 1920
  float* s2t  = s1t + 1920;            // 1920
  float* Ptb  = s2t + 1920;            // 4608
  float* Wp0  = Ptb + 4608;            // 480000
  float* Wgp  = Wp0 + 480000;          // 30720
  float* Wtp  = Wgp + 30720;           // 1280000
  float* Wtl  = Wtp + 1280000;         // 10240 (20480 bf16 packed tail weights)
  ushortt* Xbt = (ushortt*)U;
  ushortt* Agb = (ushortt*)(U + 6291456);
  ushortt* Wtail = (ushortt*)Wtl;
  float* g = U;
  if (ws_size < (size_t)38876416 * 4) return;

  // weight packing
  pack_w<<<1875, 256, 0, stream>>>(a0W1, a0W2, Wp0, 24000);
  pack_w<<<120, 256, 0, stream>>>(gW1, gW2, Wgp, 1536);
  pack_w<<<5000, 256, 0, stream>>>(tW1, tW2, Wtp, 64000);
  pack_tailw<<<80, 256, 0, stream>>>(c1w, c2w, rw, Wtail);
  // stage 1: channel attention (split-K accumulate -> zero first)
  zerok<<<40, 256, 0, stream>>>(s1_0, 10240);
  att0_s12<<<dim3(128, 4), 256, 0, stream>>>(x, Wp0, s1_0, s2_0);
  att0_softmax<<<8, 64, 0, stream>>>(s1_0, s2_0, P0);
  att0_apply<<<dim3(250, 8), 256, 0, stream>>>(x, P0, R1);
  // stage 2: gated GCN
  gatt_s12<<<2000, 256, 0, stream>>>(R1, Wgp, s1g, s2gT);
  transpose_x1<<<dim3(24, 16, 8), 256, 0, stream>>>(R1, Xbt);
  gatt_scores<<<8000, 256, 0, stream>>>(s1g, s2gT, Aadj, Agb);
  gemm_mfma<<<dim3(12, 8, 8), 256, 0, stream>>>(Agb, Xbt, D);
  gcn_out<<<dim3(250, 8), 256, 0, stream>>>(D, gcnW, g);
  // stage 3: temporal attention (split-K accumulate -> zero first)
  zerok<<<15, 256, 0, stream>>>(s1t, 3840);
  tatt_s12<<<dim3(50, 6, 8), 256, 0, stream>>>(g, Wtp, s1t, s2t);
  tatt_softmax<<<8, 32, 0, stream>>>(s1t, s2t, Ptb);
  tatt_apply<<<dim3(250, 8), 256, 0, stream>>>(g, Ptb, (ushortt*)R1);
  // stage 4: MFMA tail + residual + LN
  tail_k<<<dim3(250, 8), 256, 0, stream>>>((const ushortt*)R1, x, Wtail,
                                           c1b, c2b, rb, lng, lnb, out);
}

// Round 7
// 520.990 us; speedup vs baseline: 1.0624x; 1.0301x over previous
//
#include <hip/hip_runtime.h>
#include <hip/hip_bf16.h>

typedef unsigned int u32;
typedef unsigned short ushortt;

#define B_  8
#define C_  64
#define N_  1000
#define T_  24
#define R_  10
#define NT_ 24000   // N*T
#define CT_ 1536    // C*T
#define NC_ 64000   // N*Co

typedef __attribute__((ext_vector_type(8))) short bf8v;
typedef __attribute__((ext_vector_type(4))) float f4v;

__device__ __forceinline__ ushortt f2b_bits(float f) {
  u32 x = __float_as_uint(f);
  u32 r = (x + 0x7fffu + ((x >> 16) & 1u)) >> 16;   // round-to-nearest-even
  return (ushortt)r;
}

__device__ __forceinline__ u32 f2b_pair(float a, float b) {
  return (u32)f2b_bits(a) | ((u32)f2b_bits(b) << 16);
}

__device__ __forceinline__ float blockSum256(float v, float* red) {
  red[threadIdx.x] = v; __syncthreads();
  #pragma unroll
  for (int s = 128; s > 0; s >>= 1) {
    if (threadIdx.x < s) red[threadIdx.x] += red[threadIdx.x + s];
    __syncthreads();
  }
  float r = red[0]; __syncthreads();
  return r;
}
__device__ __forceinline__ float blockMax256(float v, float* red) {
  red[threadIdx.x] = v; __syncthreads();
  #pragma unroll
  for (int s = 128; s > 0; s >>= 1) {
    if (threadIdx.x < s) red[threadIdx.x] = fmaxf(red[threadIdx.x], red[threadIdx.x + s]);
    __syncthreads();
  }
  float r = red[0]; __syncthreads();
  return r;
}

// ---------- utility ----------
__global__ __launch_bounds__(256) void zerok(float* p, int n) {
  int i = blockIdx.x * 256 + threadIdx.x;
  if (i < n) p[i] = 0.f;
}

// pack W1[K][10] and W2[10][K] -> Wp[K][20]
__global__ __launch_bounds__(256) void pack_w(
    const float* __restrict__ W1, const float* __restrict__ W2,
    float* __restrict__ Wp, int K) {
  int i = blockIdx.x * 256 + threadIdx.x;
  if (i >= K * 20) return;
  int k = i / 20, r = i - k * 20;
  Wp[i] = (r < 10) ? W1[(size_t)k * 10 + r] : W2[(size_t)(r - 10) * K + k];
}

// pack tail weights to bf16 A-matrices:
// [0:8192)  Wc1b[2][64][64]  tap0 = c1w[...,1] (current), tap1 = c1w[...,0] (t-1)
// [8192:16384) Wc2b[2][64][64]
// [16384:20480) Wrb[64][64]
__global__ __launch_bounds__(256) void pack_tailw(
    const float* __restrict__ c1w, const float* __restrict__ c2w,
    const float* __restrict__ rw, ushortt* __restrict__ Wt) {
  int i = blockIdx.x * 256 + threadIdx.x;
  if (i >= 20480) return;
  float v;
  if (i < 8192) {
    int tap = i >> 12, o = (i >> 6) & 63, c = i & 63;
    v = c1w[(size_t)(o * 64 + c) * 2 + (tap ? 0 : 1)];
  } else if (i < 16384) {
    int j = i - 8192;
    int tap = j >> 12, o = (j >> 6) & 63, c = j & 63;
    v = c2w[(size_t)(o * 64 + c) * 2 + (tap ? 0 : 1)];
  } else {
    int j = i - 16384;
    v = rw[j];
  }
  Wt[i] = f2b_bits(v);
}

// ---------- stage 1: channel attention scores ----------
// Split-K tall-skinny GEMM: [512 x 24000] @ Wp[24000 x 20] -> s1/s2 (atomics).
__global__ __launch_bounds__(256) void att0_s12(
    const float* __restrict__ x, const float* __restrict__ Wp,
    float* __restrict__ s1, float* __restrict__ s2) {
  __shared__ float red[40 * 257];
  const int row0 = blockIdx.x * 4;
  const int kbase = blockIdx.y * 6000;
  const int tid = threadIdx.x;
  float acc[4][20];
  #pragma unroll
  for (int r = 0; r < 4; ++r)
    #pragma unroll
    for (int j = 0; j < 20; ++j) acc[r][j] = 0.f;
  const float* xb = x + (size_t)row0 * NT_ + kbase;
  const float4* wb4 = (const float4*)Wp + (size_t)kbase * 5;  // Wp[kbase*20]
  #pragma unroll 1
  for (int it = 0; it < 6; ++it) {
    int slot = tid + 256 * it;                 // float4-slot in chunk, < 1500
    if (slot < 1500) {
      int k = slot * 4;
      float4 xv0 = *(const float4*)&xb[k];
      float4 xv1 = *(const float4*)&xb[NT_ + k];
      float4 xv2 = *(const float4*)&xb[2 * NT_ + k];
      float4 xv3 = *(const float4*)&xb[3 * NT_ + k];
      const float4* w4 = wb4 + (size_t)slot * 20;   // 4 k's x 5 float4
      #pragma unroll
      for (int kk = 0; kk < 4; ++kk) {
        float4 wa = w4[kk * 5 + 0], wbv = w4[kk * 5 + 1], wc = w4[kk * 5 + 2],
               wd = w4[kk * 5 + 3], we = w4[kk * 5 + 4];
        float w[20] = {wa.x,wa.y,wa.z,wa.w, wbv.x,wbv.y,wbv.z,wbv.w,
                       wc.x,wc.y,wc.z,wc.w, wd.x,wd.y,wd.z,wd.w,
                       we.x,we.y,we.z,we.w};
        float xs0 = ((const float*)&xv0)[kk];
        float xs1 = ((const float*)&xv1)[kk];
        float xs2 = ((const float*)&xv2)[kk];
        float xs3 = ((const float*)&xv3)[kk];
        #pragma unroll
        for (int j = 0; j < 20; ++j) {
          acc[0][j] += xs0 * w[j];
          acc[1][j] += xs1 * w[j];
          acc[2][j] += xs2 * w[j];
          acc[3][j] += xs3 * w[j];
        }
      }
    }
  }
  // block reduce: 80 values x 256 threads, in 2 halves of 40
  #pragma unroll
  for (int half = 0; half < 2; ++half) {
    __syncthreads();
    #pragma unroll
    for (int mm = 0; mm < 40; ++mm) {
      int m = half * 40 + mm;
      red[mm * 257 + tid] = acc[m / 20][m % 20];
    }
    __syncthreads();
    #pragma unroll
    for (int s = 128; s >= 8; s >>= 1) {
      for (int i = tid; i < 40 * s; i += 256) {
        int rr = i / s, col = i - rr * s;
        red[rr * 257 + col] += red[rr * 257 + col + s];
      }
      __syncthreads();
    }
    if (tid < 40) {
      float v = 0.f;
      #pragma unroll
      for (int c = 0; c < 8; ++c) v += red[tid * 257 + c];
      int m = half * 40 + tid;
      int row = row0 + m / 20, j = m % 20;
      if (j < 10) atomicAdd(&s1[row * 10 + j], v);
      else        atomicAdd(&s2[row * 10 + (j - 10)], v);
    }
  }
}

__global__ __launch_bounds__(64) void att0_softmax(
    const float* __restrict__ s1, const float* __restrict__ s2, float* __restrict__ P) {
  int b = blockIdx.x, i = threadIdx.x;
  float r1[R_];
  #pragma unroll
  for (int r = 0; r < R_; ++r) r1[r] = s1[(b * 64 + i) * R_ + r];
  const float scale = rsqrtf(24000.f);
  float row[64]; float m = -1e30f;
  for (int j = 0; j < 64; ++j) {
    const float* s2r = s2 + (size_t)(b * 64 + j) * R_;
    float d = 0.f;
    #pragma unroll
    for (int r = 0; r < R_; ++r) d += r1[r] * s2r[r];
    d *= scale; row[j] = d; m = fmaxf(m, d);
  }
  float s = 0.f;
  for (int j = 0; j < 64; ++j) { float e = __expf(row[j] - m); row[j] = e; s += e; }
  float inv = 1.f / s;
  for (int j = 0; j < 64; ++j) P[((size_t)b * 64 + i) * 64 + j] = row[j] * inv;
}

__global__ __launch_bounds__(256) void att0_apply(
    const float* __restrict__ x, const float* __restrict__ P, float* __restrict__ x1tr) {
  __shared__ float Pss[4160];
  __shared__ float xt[6144];
  int b = blockIdx.y, n0 = blockIdx.x * 4;
  int tid = threadIdx.x;
  for (int i = tid; i < 4096; i += 256)
    Pss[(i >> 6) * 65 + (i & 63)] = P[(size_t)b * 4096 + i];
  {
    const float4* src4 = (const float4*)x;
    float4* dst4 = (float4*)xt;
    for (int i = tid; i < 1536; i += 256) {
      int j = i / 24, q = i - j * 24;
      dst4[i] = src4[(size_t)(b * 64 + j) * 6000 + n0 * 6 + q];
    }
  }
  __syncthreads();
  int ig = tid >> 4, ln = (tid >> 2) & 3, ts = tid & 3;
  float acc[4][6];
  #pragma unroll
  for (int ii = 0; ii < 4; ++ii)
    #pragma unroll
    for (int m = 0; m < 6; ++m) acc[ii][m] = 0.f;
  const float* base = &xt[ln * 24 + ts * 6];
  #pragma unroll 4
  for (int j = 0; j < 64; ++j) {
    float vj[6];
    #pragma unroll
    for (int m = 0; m < 6; ++m) vj[m] = base[j * 96 + m];
    #pragma unroll
    for (int ii = 0; ii < 4; ++ii) {
      float p = Pss[(ig * 4 + ii) * 65 + j];
      #pragma unroll
      for (int m = 0; m < 6; ++m) acc[ii][m] += p * vj[m];
    }
  }
  float* drow = x1tr + ((size_t)b * N_ + n0 + ln) * CT_ + ts * 6;
  #pragma unroll
  for (int ii = 0; ii < 4; ++ii) {
    float* d = drow + (ig * 4 + ii) * 24;
    *(float2*)&d[0] = make_float2(acc[ii][0], acc[ii][1]);
    *(float2*)&d[2] = make_float2(acc[ii][2], acc[ii][3]);
    *(float2*)&d[4] = make_float2(acc[ii][4], acc[ii][5]);
  }
}

// ---------- transpose x1tr -> Xbt bf16 ----------
__global__ __launch_bounds__(256) void transpose_x1(
    const float* __restrict__ x1tr, ushortt* __restrict__ Xbt) {
  __shared__ float s[64][65];
  int b = blockIdx.z, n0 = blockIdx.y * 64, c0 = blockIdx.x * 64;
  int tid = threadIdx.x;
  int r = tid >> 2, cc = (tid & 3) * 16;
  if (n0 + r < N_) {
    const float* src = x1tr + ((size_t)b * N_ + n0 + r) * CT_ + c0 + cc;
    #pragma unroll
    for (int i = 0; i < 16; i += 4) {
      float4 v = *(const float4*)&src[i];
      s[r][cc + i] = v.x; s[r][cc + i + 1] = v.y;
      s[r][cc + i + 2] = v.z; s[r][cc + i + 3] = v.w;
    }
  } else {
    #pragma unroll
    for (int i = 0; i < 16; ++i) s[r][cc + i] = 0.f;
  }
  __syncthreads();
  ushortt* dst = Xbt + ((size_t)b * CT_ + c0 + r) * 1024 + n0 + cc;
  #pragma unroll
  for (int i = 0; i < 16; ++i) dst[i] = f2b_bits(s[cc + i][r]);
}

// ---------- stage 2: gate scores ----------
__global__ __launch_bounds__(256) void gatt_s12(
    const float* __restrict__ xg, const float* __restrict__ Wp,
    float* __restrict__ s1, float* __restrict__ s2T) {
  __shared__ float xs[6144];
  __shared__ float red[5120];
  int bn0 = blockIdx.x * 4;
  int tid = threadIdx.x;
  {
    const float4* src4 = (const float4*)(xg + (size_t)bn0 * CT_);
    float4* dst4 = (float4*)xs;
    for (int i = tid; i < 1536; i += 256) dst4[i] = src4[i];
  }
  __syncthreads();
  int rid = tid >> 6, ks = tid & 63;
  float a[20];
  #pragma unroll
  for (int r = 0; r < 20; ++r) a[r] = 0.f;
  for (int k = ks; k < CT_; k += 64) {
    float xv = xs[rid * CT_ + k];
    const float4* wp4 = (const float4*)&Wp[(size_t)k * 20];
    float4 wa = wp4[0], wb = wp4[1], wc = wp4[2], wd = wp4[3], we = wp4[4];
    float wv[20] = {wa.x,wa.y,wa.z,wa.w, wb.x,wb.y,wb.z,wb.w, wc.x,wc.y,wc.z,wc.w,
                    wd.x,wd.y,wd.z,wd.w, we.x,we.y,we.z,we.w};
    #pragma unroll
    for (int r = 0; r < 20; ++r) a[r] += xv * wv[r];
  }
  #pragma unroll
  for (int r = 0; r < 20; ++r) red[tid * 20 + r] = a[r];
  __syncthreads();
  if (tid < 80) {
    int rid2 = tid / 20, r = tid % 20;
    float s = 0.f;
    for (int l = 0; l < 64; ++l) s += red[(rid2 * 64 + l) * 20 + r];
    int row = bn0 + rid2;
    int b = row / N_, n = row - b * N_;
    if (r < 10) s1[row * 10 + r] = s;
    else        s2T[((size_t)b * 10 + (r - 10)) * N_ + n] = s;
  }
}

__global__ __launch_bounds__(256) void gatt_scores(
    const float* __restrict__ s1, const float* __restrict__ s2T,
    const float* __restrict__ Aadj, ushortt* __restrict__ Agb) {
  __shared__ float p[N_];
  __shared__ float r1[R_];
  __shared__ float red[256];
  int b = blockIdx.x / N_, n = blockIdx.x % N_;
  if (threadIdx.x < R_) r1[threadIdx.x] = s1[((size_t)b * N_ + n) * R_ + threadIdx.x];
  __syncthreads();
  const float scale = rsqrtf(1536.f);
  const float* s2b = s2T + (size_t)b * 10 * N_;
  float lmax = -1e30f;
  for (int m = threadIdx.x; m < N_; m += 256) {
    float d = 0.f;
    #pragma unroll
    for (int r = 0; r < R_; ++r) d += r1[r] * s2b[r * N_ + m];
    d *= scale; p[m] = d; lmax = fmaxf(lmax, d);
  }
  float gmax = blockMax256(lmax, red);
  float lsum = 0.f;
  for (int m = threadIdx.x; m < N_; m += 256) {
    float e = __expf(p[m] - gmax); p[m] = e; lsum += e;
  }
  float gsum = blockSum256(lsum, red);
  float inv = 1.f / gsum;
  ushortt* agr = Agb + ((size_t)b * 1024 + n) * 1024;
  const float* ar = Aadj + (size_t)n * N_;
  for (int m = threadIdx.x; m < 1024; m += 256) {
    float v = (m < N_) ? p[m] * inv * ar[m] : 0.f;
    agr[m] = f2b_bits(v);
  }
}

// ---------- batched MFMA GEMM (double-buffered prefetch, T3 2-phase) ----------
__global__ __launch_bounds__(256) void gemm_mfma(
    const ushortt* __restrict__ Agb, const ushortt* __restrict__ Xbt,
    float* __restrict__ g1) {
  __shared__ ushortt As[2][4096];
  __shared__ ushortt Bs[2][4096];
  const int b = blockIdx.z;
  const int n0 = blockIdx.x * 128;
  const int m0 = blockIdx.y * 128;
  const ushortt* Ab = Agb + (size_t)b * 1024 * 1024;
  const ushortt* Bb = Xbt + (size_t)b * 1536 * 1024;
  const int tid = threadIdx.x;
  const int wave = tid >> 6, lane = tid & 63;
  const int wr = (wave >> 1) * 64, wc = (wave & 1) * 64;
  const int lrow = lane >> 2;
  const int lcol = (lane & 3) * 8;
  const int q = lane >> 4, l15 = lane & 15;

  f4v acc[4][4];
  #pragma unroll
  for (int i = 0; i < 4; ++i)
    #pragma unroll
    for (int j = 0; j < 4; ++j) acc[i][j] = (f4v){0.f, 0.f, 0.f, 0.f};

  const ushortt* gA = Ab + (size_t)(m0 + wave * 16 + lrow) * 1024 + lcol;
  const ushortt* gB = Bb + (size_t)(n0 + wave * 16 + lrow) * 1024 + lcol;

#define GM_STAGE(buf, kk)                                                     \
  do {                                                                        \
    __builtin_amdgcn_global_load_lds(                                         \
      (const __attribute__((address_space(1))) void*)(gA + (kk)),             \
      (__attribute__((address_space(3))) void*)(&As[buf][wave * 512]), 16, 0, 0); \
    __builtin_amdgcn_global_load_lds(                                         \
      (const __attribute__((address_space(1))) void*)(gA + (size_t)64 * 1024 + (kk)), \
      (__attribute__((address_space(3))) void*)(&As[buf][wave * 512 + 2048]), 16, 0, 0); \
    __builtin_amdgcn_global_load_lds(                                         \
      (const __attribute__((address_space(1))) void*)(gB + (kk)),             \
      (__attribute__((address_space(3))) void*)(&Bs[buf][wave * 512]), 16, 0, 0); \
    __builtin_amdgcn_global_load_lds(                                         \
      (const __attribute__((address_space(1))) void*)(gB + (size_t)64 * 1024 + (kk)), \
      (__attribute__((address_space(3))) void*)(&Bs[buf][wave * 512 + 2048]), 16, 0, 0); \
  } while (0)

  GM_STAGE(0, 0);
  __syncthreads();
  int cur = 0;
  for (int k0 = 0; k0 < 1024; k0 += 32) {
    int nxt = cur ^ 1;
    if (k0 + 32 < 1024) GM_STAGE(nxt, k0 + 32);
    bf8v af[4], bfr[4];
    #pragma unroll
    for (int i = 0; i < 4; ++i)
      af[i] = *(const bf8v*)&As[cur][(wr + i * 16 + l15) * 32 + q * 8];
    #pragma unroll
    for (int j = 0; j < 4; ++j)
      bfr[j] = *(const bf8v*)&Bs[cur][(wc + j * 16 + l15) * 32 + q * 8];
    #pragma unroll
    for (int i = 0; i < 4; ++i)
      #pragma unroll
      for (int j = 0; j < 4; ++j)
        acc[i][j] = __builtin_amdgcn_mfma_f32_16x16x32_bf16(af[i], bfr[j], acc[i][j], 0, 0, 0);
    __syncthreads();
    cur = nxt;
  }
#undef GM_STAGE
  #pragma unroll
  for (int i = 0; i < 4; ++i) {
    int rbase = m0 + wr + i * 16 + q * 4;
    #pragma unroll
    for (int r = 0; r < 4; ++r) {
      int gm = rbase + r;
      if (gm < N_) {
        float* dst = g1 + ((size_t)b * N_ + gm) * CT_ + n0 + wc + l15;
        #pragma unroll
        for (int j = 0; j < 4; ++j) dst[j * 16] = acc[i][j][r];
      }
    }
  }
}

// ---------- gcn_out ----------
__global__ __launch_bounds__(256) void gcn_out(
    const float* __restrict__ g1, const float* __restrict__ W, float* __restrict__ g) {
  __shared__ float gs[6160];
  __shared__ float Ws[4096];
  int b = blockIdx.y, n0 = blockIdx.x * 4;
  int tid = threadIdx.x;
  {
    const float4* src4 = (const float4*)g1;
    float4* dst4 = (float4*)gs;
    for (int i = tid; i < 1536; i += 256) {
      int ln = i / 384, q = i - ln * 384;
      dst4[ln * 385 + q] = src4[(size_t)(b * N_ + n0 + ln) * 384 + q];
    }
  }
  for (int i = tid; i < 4096; i += 256) Ws[i] = W[i];
  __syncthreads();
  int og = tid >> 4, ln = (tid >> 2) & 3, ts = tid & 3;
  float acc[4][6];
  #pragma unroll
  for (int oo = 0; oo < 4; ++oo)
    #pragma unroll
    for (int m = 0; m < 6; ++m) acc[oo][m] = 0.f;
  const float* base = &gs[ln * 1540 + ts * 6];
  #pragma unroll 4
  for (int c = 0; c < 64; ++c) {
    float v[6];
    #pragma unroll
    for (int m = 0; m < 6; ++m) v[m] = base[c * 24 + m];
    float4 w4 = *(const float4*)&Ws[c * 64 + og * 4];
    float wv[4] = {w4.x, w4.y, w4.z, w4.w};
    #pragma unroll
    for (int oo = 0; oo < 4; ++oo)
      #pragma unroll
      for (int m = 0; m < 6; ++m) acc[oo][m] += wv[oo] * v[m];
  }
  #pragma unroll
  for (int oo = 0; oo < 4; ++oo) {
    int o = og * 4 + oo;
    float* d = g + (((size_t)(b * C_ + o)) * N_ + n0 + ln) * T_ + ts * 6;
    *(float2*)&d[0] = make_float2(acc[oo][0], acc[oo][1]);
    *(float2*)&d[2] = make_float2(acc[oo][2], acc[oo][3]);
    *(float2*)&d[4] = make_float2(acc[oo][4], acc[oo][5]);
  }
}

// ---------- stage 3: temporal attention scores ----------
__global__ __launch_bounds__(256) void tatt_s12(
    const float* __restrict__ g, const float* __restrict__ Wp,
    float* __restrict__ s1, float* __restrict__ s2) {
  __shared__ float red[40 * 257];
  const int b = blockIdx.z, t0 = blockIdx.y * 4, n0 = blockIdx.x * 20;
  const int tid = threadIdx.x;
  const int o = tid & 63, nl = tid >> 6;
  float acc[4][20];
  #pragma unroll
  for (int tt = 0; tt < 4; ++tt)
    #pragma unroll
    for (int j = 0; j < 20; ++j) acc[tt][j] = 0.f;
  const float* gb = g + (size_t)(b * 64 + o) * NT_ + t0;
  #pragma unroll 1
  for (int it = 0; it < 5; ++it) {
    int n = n0 + it * 4 + nl;
    float4 gv = *(const float4*)&gb[n * 24];
    const float4* w4 = (const float4*)&Wp[(size_t)(n * 64 + o) * 20];
    float4 wa = w4[0], wbv = w4[1], wc = w4[2], wd = w4[3], we = w4[4];
    float w[20] = {wa.x,wa.y,wa.z,wa.w, wbv.x,wbv.y,wbv.z,wbv.w,
                   wc.x,wc.y,wc.z,wc.w, wd.x,wd.y,wd.z,wd.w,
                   we.x,we.y,we.z,we.w};
    float gs[4] = {gv.x, gv.y, gv.z, gv.w};
    #pragma unroll
    for (int tt = 0; tt < 4; ++tt)
      #pragma unroll
      for (int j = 0; j < 20; ++j) acc[tt][j] += gs[tt] * w[j];
  }
  // block reduce: 80 values x 256 threads, in 2 halves of 40
  #pragma unroll
  for (int half = 0; half < 2; ++half) {
    __syncthreads();
    #pragma unroll
    for (int mm = 0; mm < 40; ++mm) {
      int m = half * 40 + mm;
      red[mm * 257 + tid] = acc[m / 20][m % 20];
    }
    __syncthreads();
    #pragma unroll
    for (int s = 128; s >= 8; s >>= 1) {
      for (int i = tid; i < 40 * s; i += 256) {
        int rr = i / s, col = i - rr * s;
        red[rr * 257 + col] += red[rr * 257 + col + s];
      }
      __syncthreads();
    }
    if (tid < 40) {
      float v = 0.f;
      #pragma unroll
      for (int c = 0; c < 8; ++c) v += red[tid * 257 + c];
      int m = half * 40 + tid;
      int t = t0 + m / 20, j = m % 20;
      if (j < 10) atomicAdd(&s1[(b * T_ + t) * R_ + j], v);
      else        atomicAdd(&s2[(b * T_ + t) * R_ + (j - 10)], v);
    }
  }
}

__global__ __launch_bounds__(64) void tatt_softmax(
    const float* __restrict__ s1, const float* __restrict__ s2, float* __restrict__ Pt) {
  int b = blockIdx.x, t = threadIdx.x;
  if (t >= T_) return;
  float r1[R_];
  #pragma unroll
  for (int r = 0; r < R_; ++r) r1[r] = s1[(b * T_ + t) * R_ + r];
  const float scale = rsqrtf(64000.f);
  float row[T_]; float m = -1e30f;
  for (int j = 0; j < T_; ++j) {
    const float* s2r = s2 + (b * T_ + j) * R_;
    float d = 0.f;
    #pragma unroll
    for (int r = 0; r < R_; ++r) d += r1[r] * s2r[r];
    d *= scale; row[j] = d; m = fmaxf(m, d);
  }
  float s = 0.f;
  for (int j = 0; j < T_; ++j) { float e = __expf(row[j] - m); row[j] = e; s += e; }
  float inv = 1.f / s;
  for (int j = 0; j < T_; ++j) Pt[(b * T_ + t) * T_ + j] = row[j] * inv;
}

// ---------- stage 4 (MFMA tail, tatt_apply FUSED): Pt@g -> conv1 -> conv2+res -> LN ----------
// grid (250, 8), 256 threads = 4 waves; wave w owns node nl=w (cols 32w..32w+31).
// Column layout per node: s=0,1 zero guards; s=2..25 <-> t=0..23; s=26..31 zero pad.
// tatt_apply fusion: thread (c=tid>>2, nl=tid&3) loads its 24-t g row into regs,
// computes x2 row = Pt[b] @ g row (f32, identical math+rounding to old tatt_apply),
// writes bf16 into the x2 row-staging slots stage B expects. Kills the separate
// tatt_apply launch + the x2b global round-trip.
// ONE 32KB LDS union, timeline-overlaid (as before) + PtS 2.3KB.
#define CSB 1024
#define RSB 104
#define PFS 66
__global__ __launch_bounds__(256, 4) void tail_k(
    const float* __restrict__ g, const float* __restrict__ Pt,
    const float* __restrict__ x,
    const ushortt* __restrict__ Wt,
    const float* __restrict__ c1b, const float* __restrict__ c2b,
    const float* __restrict__ rb,
    const float* __restrict__ lg, const float* __restrict__ lb,
    float* __restrict__ outp) {
  __shared__ __align__(16) ushortt LSH[16384];   // 32 KB union
  __shared__ __align__(16) float PtS[576];
  __shared__ float mu[96], rs[96];
  ushortt* L0 = LSH;
  ushortt* L1 = LSH + 8192;
  float* preF = (float*)LSH;                     // 96*66*4 = 25344 B
  int b = blockIdx.y, n0 = blockIdx.x * 4;
  int tid = threadIdx.x;
  int wave = tid >> 6, lane = tid & 63;
  int q = lane >> 4, l15 = lane & 15;

  // ---- stage A: Pt -> LDS; g row -> regs; x -> L1 row-staging ----
  if (tid < 144)
    ((float4*)PtS)[tid] = ((const float4*)(Pt + (size_t)b * 576))[tid];
  const int sc = tid >> 2, snl = tid & 3;
  float gr[24];
  {
    const float4* gp = (const float4*)(g + ((size_t)(b * 64 + sc) * 1000 + n0 + snl) * 24);
    #pragma unroll
    for (int q2 = 0; q2 < 6; ++q2) {
      float4 v = gp[q2];
      gr[q2 * 4] = v.x; gr[q2 * 4 + 1] = v.y; gr[q2 * 4 + 2] = v.z; gr[q2 * 4 + 3] = v.w;
    }
  }
  #pragma unroll
  for (int rep = 0; rep < 6; ++rep) {
    int i = tid + rep * 256;                 // < 1536 : x float4 slots
    int c = i / 24, qq = i - c * 24;
    const float4* src = (const float4*)(x + ((size_t)(b * 64 + c) * 1000 + n0) * 24);
    float4 v = src[qq];
    *(uint2*)&L1[c * RSB + qq * 4] = make_uint2(f2b_pair(v.x, v.y), f2b_pair(v.z, v.w));
  }
  __syncthreads();

  // ---- fused tatt_apply: x2 row = Pt @ g row, -> L0 row-staging (bf16) ----
  {
    u32 w12[12];
    #pragma unroll
    for (int t = 0; t < 24; t += 2) {
      float a0 = 0.f, a1 = 0.f;
      const float4* p0 = (const float4*)&PtS[t * 24];
      const float4* p1 = (const float4*)&PtS[t * 24 + 24];
      #pragma unroll
      for (int q2 = 0; q2 < 6; ++q2) {
        float4 v0 = p0[q2], v1 = p1[q2];
        a0 += v0.x * gr[q2 * 4] + v0.y * gr[q2 * 4 + 1]
            + v0.z * gr[q2 * 4 + 2] + v0.w * gr[q2 * 4 + 3];
        a1 += v1.x * gr[q2 * 4] + v1.y * gr[q2 * 4 + 1]
            + v1.z * gr[q2 * 4 + 2] + v1.w * gr[q2 * 4 + 3];
      }
      w12[t >> 1] = f2b_pair(a0, a1);
    }
    uint4* da = (uint4*)&L0[sc * RSB + snl * 24];
    da[0] = make_uint4(w12[0], w12[1], w12[2], w12[3]);
    da[1] = make_uint4(w12[4], w12[5], w12[6], w12[7]);
    da[2] = make_uint4(w12[8], w12[9], w12[10], w12[11]);
  }
  __syncthreads();

  // ---- stage B: read x2 fragments (pa) from L0 row-staging ----
  u32 pa[4][4];
  int sKblk[4], sCol[4];
  #pragma unroll
  for (int rep = 0; rep < 4; ++rep) {
    int slot = tid + rep * 256;
    int kblk = slot >> 7, col = slot & 127;
    sKblk[rep] = kblk; sCol[rep] = col;
    int nl2 = col >> 5, s = col & 31;
    if (s >= 2 && s <= 25) {
      int boff = (kblk * 8) * RSB + nl2 * 24 + (s - 2);
      #pragma unroll
      for (int h = 0; h < 4; ++h) {
        u32 a0 = L0[boff + (2 * h) * RSB], a1 = L0[boff + (2 * h + 1) * RSB];
        pa[rep][h] = a0 | (a1 << 16);
      }
    } else {
      #pragma unroll
      for (int h = 0; h < 4; ++h) pa[rep][h] = 0u;
    }
  }
  __syncthreads();
  // write X2c tile into L0 (row-staging dead)
  #pragma unroll
  for (int rep = 0; rep < 4; ++rep)
    *(uint4*)&L0[sKblk[rep] * CSB + sCol[rep] * 8] =
        make_uint4(pa[rep][0], pa[rep][1], pa[rep][2], pa[rep][3]);
  __syncthreads();

  // ---- conv1 (X2c in L0) + read residual fragments (kb) from L1 ----
  f4v acc1[2][4];
  #pragma unroll
  for (int ct = 0; ct < 2; ++ct)
    #pragma unroll
    for (int mt = 0; mt < 4; ++mt) acc1[ct][mt] = (f4v){0.f, 0.f, 0.f, 0.f};
  #pragma unroll
  for (int ki = 0; ki < 2; ++ki) {
    bf8v a0[4], a1[4];
    #pragma unroll
    for (int mt = 0; mt < 4; ++mt) {
      a0[mt] = *(const bf8v*)&Wt[(mt * 16 + l15) * 64 + ki * 32 + q * 8];
      a1[mt] = *(const bf8v*)&Wt[4096 + (mt * 16 + l15) * 64 + ki * 32 + q * 8];
    }
    #pragma unroll
    for (int ct = 0; ct < 2; ++ct) {
      int col = wave * 32 + ct * 16 + l15;
      int colp = (col == 0) ? 0 : col - 1;
      bf8v bc = *(const bf8v*)&L0[(ki * 4 + q) * CSB + col * 8];
      bf8v bp = *(const bf8v*)&L0[(ki * 4 + q) * CSB + colp * 8];
      #pragma unroll
      for (int mt = 0; mt < 4; ++mt) {
        acc1[ct][mt] = __builtin_amdgcn_mfma_f32_16x16x32_bf16(a0[mt], bc, acc1[ct][mt], 0, 0, 0);
        acc1[ct][mt] = __builtin_amdgcn_mfma_f32_16x16x32_bf16(a1[mt], bp, acc1[ct][mt], 0, 0, 0);
      }
    }
  }
  u32 kb[4][4];
  #pragma unroll
  for (int rep = 0; rep < 4; ++rep) {
    int col = sCol[rep];
    int nl2 = col >> 5, s = col & 31;
    if (s >= 2 && s <= 25) {
      int boff = (sKblk[rep] * 8) * RSB + nl2 * 24 + (s - 2);
      #pragma unroll
      for (int h = 0; h < 4; ++h) {
        u32 b0 = L1[boff + (2 * h) * RSB], b1 = L1[boff + (2 * h + 1) * RSB];
        kb[rep][h] = b0 | (b1 << 16);
      }
    } else {
      #pragma unroll
      for (int h = 0; h < 4; ++h) kb[rep][h] = 0u;
    }
  }
  // epilogue 1 in regs: bias + relu (zeros in guard/pad cols)
  u32 ypack[2][4][2];
  #pragma unroll
  for (int ct = 0; ct < 2; ++ct) {
    int s = ct * 16 + l15;
    bool v = (s >= 2 && s <= 25);
    #pragma unroll
    for (int mt = 0; mt < 4; ++mt) {
      int o0 = mt * 16 + q * 4;
      float4 bb = *(const float4*)&c1b[o0];
      float y0 = v ? fmaxf(acc1[ct][mt][0] + bb.x, 0.f) : 0.f;
      float y1 = v ? fmaxf(acc1[ct][mt][1] + bb.y, 0.f) : 0.f;
      float y2 = v ? fmaxf(acc1[ct][mt][2] + bb.z, 0.f) : 0.f;
      float y3 = v ? fmaxf(acc1[ct][mt][3] + bb.w, 0.f) : 0.f;
      ypack[ct][mt][0] = f2b_pair(y0, y1);
      ypack[ct][mt][1] = f2b_pair(y2, y3);
    }
  }
  __syncthreads();   // all conv1 X2c reads + kb L1 reads done

  // ---- write Y1c -> L0 (over X2c), Xrc -> L1 (over x staging) ----
  #pragma unroll
  for (int ct = 0; ct < 2; ++ct) {
    int col = wave * 32 + ct * 16 + l15;
    #pragma unroll
    for (int mt = 0; mt < 4; ++mt) {
      int o0 = mt * 16 + q * 4;
      *(uint2*)&L0[(o0 >> 3) * CSB + col * 8 + (o0 & 7)] =
          make_uint2(ypack[ct][mt][0], ypack[ct][mt][1]);
    }
  }
  #pragma unroll
  for (int rep = 0; rep < 4; ++rep)
    *(uint4*)&L1[sKblk[rep] * CSB + sCol[rep] * 8] =
        make_uint4(kb[rep][0], kb[rep][1], kb[rep][2], kb[rep][3]);
  __syncthreads();

  // ---- conv2 (taps col, col-2 from Y1c=L0) + residual (Xrc=L1) ----
  f4v accA[2][4], accR[2][4];
  #pragma unroll
  for (int ct = 0; ct < 2; ++ct)
    #pragma unroll
    for (int mt = 0; mt < 4; ++mt) {
      accA[ct][mt] = (f4v){0.f, 0.f, 0.f, 0.f};
      accR[ct][mt] = (f4v){0.f, 0.f, 0.f, 0.f};
    }
  #pragma unroll
  for (int ki = 0; ki < 2; ++ki) {
    bf8v c0[4], c1t[4], rrf[4];
    #pragma unroll
    for (int mt = 0; mt < 4; ++mt) {
      c0[mt]  = *(const bf8v*)&Wt[8192 + (mt * 16 + l15) * 64 + ki * 32 + q * 8];
      c1t[mt] = *(const bf8v*)&Wt[12288 + (mt * 16 + l15) * 64 + ki * 32 + q * 8];
      rrf[mt] = *(const bf8v*)&Wt[16384 + (mt * 16 + l15) * 64 + ki * 32 + q * 8];
    }
    #pragma unroll
    for (int ct = 0; ct < 2; ++ct) {
      int col = wave * 32 + ct * 16 + l15;
      int colp2 = (col < 2) ? col : col - 2;
      bf8v bc = *(const bf8v*)&L0[(ki * 4 + q) * CSB + col * 8];
      bf8v bp = *(const bf8v*)&L0[(ki * 4 + q) * CSB + colp2 * 8];
      bf8v bx = *(const bf8v*)&L1[(ki * 4 + q) * CSB + col * 8];
      #pragma unroll
      for (int mt = 0; mt < 4; ++mt) {
        accA[ct][mt] = __builtin_amdgcn_mfma_f32_16x16x32_bf16(c0[mt], bc, accA[ct][mt], 0, 0, 0);
        accA[ct][mt] = __builtin_amdgcn_mfma_f32_16x16x32_bf16(c1t[mt], bp, accA[ct][mt], 0, 0, 0);
        accR[ct][mt] = __builtin_amdgcn_mfma_f32_16x16x32_bf16(rrf[mt], bx, accR[ct][mt], 0, 0, 0);
      }
    }
  }
  // epilogue 2: relu(conv2+b2) + (res+rb), relu -> pre (regs)
  float pre[2][4][4];
  #pragma unroll
  for (int ct = 0; ct < 2; ++ct) {
    #pragma unroll
    for (int mt = 0; mt < 4; ++mt) {
      int o0 = mt * 16 + q * 4;
      float4 b2 = *(const float4*)&c2b[o0];
      float4 rbv = *(const float4*)&rb[o0];
      float bb2[4] = {b2.x, b2.y, b2.z, b2.w};
      float brv[4] = {rbv.x, rbv.y, rbv.z, rbv.w};
      #pragma unroll
      for (int r = 0; r < 4; ++r) {
        float a = fmaxf(accA[ct][mt][r] + bb2[r], 0.f) + accR[ct][mt][r] + brv[r];
        pre[ct][mt][r] = fmaxf(a, 0.f);
      }
    }
  }
  __syncthreads();   // all conv2 L0/L1 reads done before preF overwrite

  // ---- preF (f32 [96][PFS]) spans the whole union ----
  #pragma unroll
  for (int ct = 0; ct < 2; ++ct) {
    int s = ct * 16 + l15;
    if (s >= 2 && s <= 25) {
      int p = wave * 24 + s - 2;
      #pragma unroll
      for (int mt = 0; mt < 4; ++mt) {
        int o0 = mt * 16 + q * 4;
        *(float2*)&preF[p * PFS + o0]     = make_float2(pre[ct][mt][0], pre[ct][mt][1]);
        *(float2*)&preF[p * PFS + o0 + 2] = make_float2(pre[ct][mt][2], pre[ct][mt][3]);
      }
    }
  }
  __syncthreads();
  // LN stats over o for each of 96 (node,t) pairs (f32)
  if (tid < 96) {
    const float* pr = &preF[tid * PFS];
    float sm = 0.f, qq = 0.f;
    #pragma unroll 16
    for (int c = 0; c < 64; ++c) {
      float v = pr[c];
      sm += v; qq += v * v;
    }
    float m = sm * (1.f / 64.f);
    mu[tid] = m;
    rs[tid] = rsqrtf(qq * (1.f / 64.f) - m * m + 1e-5f);
  }
  __syncthreads();
  // ---- coalesced store: thread owns one 96B output row (o, nl) ----
  {
    int o = tid >> 2, nl = tid & 3;
    float gam = lg[o], bet = lb[o];
    float vals[24];
    #pragma unroll
    for (int t = 0; t < 24; ++t) {
      int p = nl * 24 + t;
      vals[t] = (preF[p * PFS + o] - mu[p]) * rs[p] * gam + bet;
    }
    float* dst = outp + ((size_t)(b * 64 + o) * 1000 + n0 + nl) * 24;
    #pragma unroll
    for (int t = 0; t < 24; t += 4)
      *(float4*)&dst[t] = make_float4(vals[t], vals[t+1], vals[t+2], vals[t+3]);
  }
}

extern "C" void kernel_launch(void* const* d_in, const int* in_sizes, int n_in,
                              void* d_out, int out_size, void* d_ws, size_t ws_size,
                              hipStream_t stream) {
  const float* x     = (const float*)d_in[0];
  const float* Aadj  = (const float*)d_in[1];
  const float* a0W1  = (const float*)d_in[2];
  const float* a0W2  = (const float*)d_in[3];
  const float* gW1   = (const float*)d_in[4];
  const float* gW2   = (const float*)d_in[5];
  const float* gcnW  = (const float*)d_in[6];
  const float* tW1   = (const float*)d_in[7];
  const float* tW2   = (const float*)d_in[8];
  const float* c1w   = (const float*)d_in[9];
  const float* c1b   = (const float*)d_in[10];
  const float* c2w   = (const float*)d_in[11];
  const float* c2b   = (const float*)d_in[12];
  const float* rw    = (const float*)d_in[13];
  const float* rb    = (const float*)d_in[14];
  const float* lng   = (const float*)d_in[15];
  const float* lnb   = (const float*)d_in[16];
  float* out = (float*)d_out;

  float* ws = (float*)d_ws;
  float* R1   = ws;                    // 12,288,000: x1tr
  float* U    = R1 + 12288000;         // 12,288,000: Xbt+Agb (bf16), later g (f32)
  float* D    = U + 12288000;          // 12,288,000: g1
  float* s1_0 = D + 12288000;          // 5120
  float* s2_0 = s1_0 + 5120;           // 5120
  float* P0   = s2_0 + 5120;           // 32768
  float* s1g  = P0 + 32768;            // 80000
  float* s2gT = s1g + 80000;           // 80000
  float* s1t  = s2gT + 80000;          // 1920
  float* s2t  = s1t + 1920;            // 1920
  float* Ptb  = s2t + 1920;            // 4608
  float* Wp0  = Ptb + 4608;            // 480000
  float* Wgp  = Wp0 + 480000;          // 30720
  float* Wtp  = Wgp + 30720;           // 1280000
  float* Wtl  = Wtp + 1280000;         // 10240 (20480 bf16 packed tail weights)
  ushortt* Xbt = (ushortt*)U;
  ushortt* Agb = (ushortt*)(U + 6291456);
  ushortt* Wtail = (ushortt*)Wtl;
  float* g = U;
  if (ws_size < (size_t)38876416 * 4) return;

  // weight packing
  pack_w<<<1875, 256, 0, stream>>>(a0W1, a0W2, Wp0, 24000);
  pack_w<<<120, 256, 0, stream>>>(gW1, gW2, Wgp, 1536);
  pack_w<<<5000, 256, 0, stream>>>(tW1, tW2, Wtp, 64000);
  pack_tailw<<<80, 256, 0, stream>>>(c1w, c2w, rw, Wtail);
  // stage 1: channel attention (split-K accumulate -> zero first)
  zerok<<<40, 256, 0, stream>>>(s1_0, 10240);
  att0_s12<<<dim3(128, 4), 256, 0, stream>>>(x, Wp0, s1_0, s2_0);
  att0_softmax<<<8, 64, 0, stream>>>(s1_0, s2_0, P0);
  att0_apply<<<dim3(250, 8), 256, 0, stream>>>(x, P0, R1);
  // stage 2: gated GCN
  gatt_s12<<<2000, 256, 0, stream>>>(R1, Wgp, s1g, s2gT);
  transpose_x1<<<dim3(24, 16, 8), 256, 0, stream>>>(R1, Xbt);
  gatt_scores<<<8000, 256, 0, stream>>>(s1g, s2gT, Aadj, Agb);
  gemm_mfma<<<dim3(12, 8, 8), 256, 0, stream>>>(Agb, Xbt, D);
  gcn_out<<<dim3(250, 8), 256, 0, stream>>>(D, gcnW, g);
  // stage 3: temporal attention (split-K accumulate -> zero first)
  zerok<<<15, 256, 0, stream>>>(s1t, 3840);
  tatt_s12<<<dim3(50, 6, 8), 256, 0, stream>>>(g, Wtp, s1t, s2t);
  tatt_softmax<<<8, 32, 0, stream>>>(s1t, s2t, Ptb);
  // stage 4: fused tatt_apply + MFMA tail + residual + LN
  tail_k<<<dim3(250, 8), 256, 0, stream>>>(g, Ptb, x, Wtail,
                                           c1b, c2b, rb, lng, lnb, out);
}

// Round 8
// 495.984 us; speedup vs baseline: 1.1159x; 1.0504x over previous
//
#include <hip/hip_runtime.h>
#include <hip/hip_bf16.h>

typedef unsigned int u32;
typedef unsigned short ushortt;

#define B_  8
#define C_  64
#define N_  1000
#define T_  24
#define R_  10
#define NT_ 24000   // N*T
#define CT_ 1536    // C*T
#define NC_ 64000   // N*Co

typedef __attribute__((ext_vector_type(8))) short bf8v;
typedef __attribute__((ext_vector_type(4))) float f4v;

__device__ __forceinline__ ushortt f2b_bits(float f) {
  u32 x = __float_as_uint(f);
  u32 r = (x + 0x7fffu + ((x >> 16) & 1u)) >> 16;   // round-to-nearest-even
  return (ushortt)r;
}

__device__ __forceinline__ u32 f2b_pair(float a, float b) {
  return (u32)f2b_bits(a) | ((u32)f2b_bits(b) << 16);
}

__device__ __forceinline__ float blockSum256(float v, float* red) {
  red[threadIdx.x] = v; __syncthreads();
  #pragma unroll
  for (int s = 128; s > 0; s >>= 1) {
    if (threadIdx.x < s) red[threadIdx.x] += red[threadIdx.x + s];
    __syncthreads();
  }
  float r = red[0]; __syncthreads();
  return r;
}
__device__ __forceinline__ float blockMax256(float v, float* red) {
  red[threadIdx.x] = v; __syncthreads();
  #pragma unroll
  for (int s = 128; s > 0; s >>= 1) {
    if (threadIdx.x < s) red[threadIdx.x] = fmaxf(red[threadIdx.x], red[threadIdx.x + s]);
    __syncthreads();
  }
  float r = red[0]; __syncthreads();
  return r;
}

// ---------- utility ----------
__global__ __launch_bounds__(256) void zerok(float* p, int n) {
  int i = blockIdx.x * 256 + threadIdx.x;
  if (i < n) p[i] = 0.f;
}

// pack W1[K][10] and W2[10][K] -> Wp[K][20]
__global__ __launch_bounds__(256) void pack_w(
    const float* __restrict__ W1, const float* __restrict__ W2,
    float* __restrict__ Wp, int K) {
  int i = blockIdx.x * 256 + threadIdx.x;
  if (i >= K * 20) return;
  int k = i / 20, r = i - k * 20;
  Wp[i] = (r < 10) ? W1[(size_t)k * 10 + r] : W2[(size_t)(r - 10) * K + k];
}

// pack tail weights to bf16 A-matrices:
// [0:8192)  Wc1b[2][64][64]  tap0 = c1w[...,1] (current), tap1 = c1w[...,0] (t-1)
// [8192:16384) Wc2b[2][64][64]
// [16384:20480) Wrb[64][64]
__global__ __launch_bounds__(256) void pack_tailw(
    const float* __restrict__ c1w, const float* __restrict__ c2w,
    const float* __restrict__ rw, ushortt* __restrict__ Wt) {
  int i = blockIdx.x * 256 + threadIdx.x;
  if (i >= 20480) return;
  float v;
  if (i < 8192) {
    int tap = i >> 12, o = (i >> 6) & 63, c = i & 63;
    v = c1w[(size_t)(o * 64 + c) * 2 + (tap ? 0 : 1)];
  } else if (i < 16384) {
    int j = i - 8192;
    int tap = j >> 12, o = (j >> 6) & 63, c = j & 63;
    v = c2w[(size_t)(o * 64 + c) * 2 + (tap ? 0 : 1)];
  } else {
    int j = i - 16384;
    v = rw[j];
  }
  Wt[i] = f2b_bits(v);
}

// ---------- stage 1: channel attention scores ----------
// Split-K tall-skinny GEMM: [512 x 24000] @ Wp[24000 x 20] -> s1/s2 (atomics).
__global__ __launch_bounds__(256) void att0_s12(
    const float* __restrict__ x, const float* __restrict__ Wp,
    float* __restrict__ s1, float* __restrict__ s2) {
  __shared__ float red[40 * 257];
  const int row0 = blockIdx.x * 4;
  const int kbase = blockIdx.y * 6000;
  const int tid = threadIdx.x;
  float acc[4][20];
  #pragma unroll
  for (int r = 0; r < 4; ++r)
    #pragma unroll
    for (int j = 0; j < 20; ++j) acc[r][j] = 0.f;
  const float* xb = x + (size_t)row0 * NT_ + kbase;
  const float4* wb4 = (const float4*)Wp + (size_t)kbase * 5;  // Wp[kbase*20]
  #pragma unroll 1
  for (int it = 0; it < 6; ++it) {
    int slot = tid + 256 * it;                 // float4-slot in chunk, < 1500
    if (slot < 1500) {
      int k = slot * 4;
      float4 xv0 = *(const float4*)&xb[k];
      float4 xv1 = *(const float4*)&xb[NT_ + k];
      float4 xv2 = *(const float4*)&xb[2 * NT_ + k];
      float4 xv3 = *(const float4*)&xb[3 * NT_ + k];
      const float4* w4 = wb4 + (size_t)slot * 20;   // 4 k's x 5 float4
      #pragma unroll
      for (int kk = 0; kk < 4; ++kk) {
        float4 wa = w4[kk * 5 + 0], wbv = w4[kk * 5 + 1], wc = w4[kk * 5 + 2],
               wd = w4[kk * 5 + 3], we = w4[kk * 5 + 4];
        float w[20] = {wa.x,wa.y,wa.z,wa.w, wbv.x,wbv.y,wbv.z,wbv.w,
                       wc.x,wc.y,wc.z,wc.w, wd.x,wd.y,wd.z,wd.w,
                       we.x,we.y,we.z,we.w};
        float xs0 = ((const float*)&xv0)[kk];
        float xs1 = ((const float*)&xv1)[kk];
        float xs2 = ((const float*)&xv2)[kk];
        float xs3 = ((const float*)&xv3)[kk];
        #pragma unroll
        for (int j = 0; j < 20; ++j) {
          acc[0][j] += xs0 * w[j];
          acc[1][j] += xs1 * w[j];
          acc[2][j] += xs2 * w[j];
          acc[3][j] += xs3 * w[j];
        }
      }
    }
  }
  // block reduce: 80 values x 256 threads, in 2 halves of 40
  #pragma unroll
  for (int half = 0; half < 2; ++half) {
    __syncthreads();
    #pragma unroll
    for (int mm = 0; mm < 40; ++mm) {
      int m = half * 40 + mm;
      red[mm * 257 + tid] = acc[m / 20][m % 20];
    }
    __syncthreads();
    #pragma unroll
    for (int s = 128; s >= 8; s >>= 1) {
      for (int i = tid; i < 40 * s; i += 256) {
        int rr = i / s, col = i - rr * s;
        red[rr * 257 + col] += red[rr * 257 + col + s];
      }
      __syncthreads();
    }
    if (tid < 40) {
      float v = 0.f;
      #pragma unroll
      for (int c = 0; c < 8; ++c) v += red[tid * 257 + c];
      int m = half * 40 + tid;
      int row = row0 + m / 20, j = m % 20;
      if (j < 10) atomicAdd(&s1[row * 10 + j], v);
      else        atomicAdd(&s2[row * 10 + (j - 10)], v);
    }
  }
}

__global__ __launch_bounds__(64) void att0_softmax(
    const float* __restrict__ s1, const float* __restrict__ s2, float* __restrict__ P) {
  int b = blockIdx.x, i = threadIdx.x;
  float r1[R_];
  #pragma unroll
  for (int r = 0; r < R_; ++r) r1[r] = s1[(b * 64 + i) * R_ + r];
  const float scale = rsqrtf(24000.f);
  float row[64]; float m = -1e30f;
  for (int j = 0; j < 64; ++j) {
    const float* s2r = s2 + (size_t)(b * 64 + j) * R_;
    float d = 0.f;
    #pragma unroll
    for (int r = 0; r < R_; ++r) d += r1[r] * s2r[r];
    d *= scale; row[j] = d; m = fmaxf(m, d);
  }
  float s = 0.f;
  for (int j = 0; j < 64; ++j) { float e = __expf(row[j] - m); row[j] = e; s += e; }
  float inv = 1.f / s;
  for (int j = 0; j < 64; ++j) P[((size_t)b * 64 + i) * 64 + j] = row[j] * inv;
}

// ---------- fused: att0_apply + gatt_s12 ----------
// grid (250, 8). Phase 1 (att0_apply): Pss+xt -> acc[4][6] per thread.
// Phase 2: write x1 tile to LDS xs (f32, over xt) + to global x1b (bf16, same
// f2b rounding transpose_x1 used to apply -> Xbt bits unchanged).
// Phase 3 (gatt_s12 body): gate scores from f32 xs (identical loop order ->
// s1g/s2gT bitwise identical to the old separate kernel).
// LDS union 44KB: [Pss 4160 | gap | xt/xs 6144 @5120] ; red 5120 @0 (phase 3).
__global__ __launch_bounds__(256) void att0_apply_gatt(
    const float* __restrict__ x, const float* __restrict__ P,
    const float* __restrict__ Wgp,
    ushortt* __restrict__ x1b, float* __restrict__ s1g, float* __restrict__ s2gT) {
  __shared__ float SH[11264];
  float* Pss = SH;            // phase 1 (4160)
  float* xt  = SH + 5120;     // phase 1 (6144)
  float* red = SH;            // phase 3 (5120, over Pss)
  float* xs  = SH + 5120;     // phase 2/3 (6144, over xt)
  int b = blockIdx.y, n0 = blockIdx.x * 4;
  int tid = threadIdx.x;
  for (int i = tid; i < 4096; i += 256)
    Pss[(i >> 6) * 65 + (i & 63)] = P[(size_t)b * 4096 + i];
  {
    const float4* src4 = (const float4*)x;
    float4* dst4 = (float4*)xt;
    for (int i = tid; i < 1536; i += 256) {
      int j = i / 24, q = i - j * 24;
      dst4[i] = src4[(size_t)(b * 64 + j) * 6000 + n0 * 6 + q];
    }
  }
  __syncthreads();
  int ig = tid >> 4, ln = (tid >> 2) & 3, ts = tid & 3;
  float acc[4][6];
  #pragma unroll
  for (int ii = 0; ii < 4; ++ii)
    #pragma unroll
    for (int m = 0; m < 6; ++m) acc[ii][m] = 0.f;
  const float* base = &xt[ln * 24 + ts * 6];
  #pragma unroll 4
  for (int j = 0; j < 64; ++j) {
    float vj[6];
    #pragma unroll
    for (int m = 0; m < 6; ++m) vj[m] = base[j * 96 + m];
    #pragma unroll
    for (int ii = 0; ii < 4; ++ii) {
      float p = Pss[(ig * 4 + ii) * 65 + j];
      #pragma unroll
      for (int m = 0; m < 6; ++m) acc[ii][m] += p * vj[m];
    }
  }
  __syncthreads();   // all Pss/xt reads done
  // phase 2: x1 tile -> xs (f32) and -> x1b (bf16)
  {
    ushortt* drow = x1b + ((size_t)b * N_ + n0 + ln) * CT_ + ts * 6;
    float* xrow = &xs[ln * CT_ + ts * 6];
    #pragma unroll
    for (int ii = 0; ii < 4; ++ii) {
      int ctb = (ig * 4 + ii) * 24;
      #pragma unroll
      for (int m = 0; m < 6; ++m) xrow[ctb + m] = acc[ii][m];
      *(u32*)&drow[ctb]     = f2b_pair(acc[ii][0], acc[ii][1]);
      *(u32*)&drow[ctb + 2] = f2b_pair(acc[ii][2], acc[ii][3]);
      *(u32*)&drow[ctb + 4] = f2b_pair(acc[ii][4], acc[ii][5]);
    }
  }
  __syncthreads();
  // phase 3: gate scores (gatt_s12 body, xs in place of staged x1tr)
  int rid = tid >> 6, ks = tid & 63;
  float a[20];
  #pragma unroll
  for (int r = 0; r < 20; ++r) a[r] = 0.f;
  for (int k = ks; k < CT_; k += 64) {
    float xv = xs[rid * CT_ + k];
    const float4* wp4 = (const float4*)&Wgp[(size_t)k * 20];
    float4 wa = wp4[0], wb = wp4[1], wc = wp4[2], wd = wp4[3], we = wp4[4];
    float wv[20] = {wa.x,wa.y,wa.z,wa.w, wb.x,wb.y,wb.z,wb.w, wc.x,wc.y,wc.z,wc.w,
                    wd.x,wd.y,wd.z,wd.w, we.x,we.y,we.z,we.w};
    #pragma unroll
    for (int r = 0; r < 20; ++r) a[r] += xv * wv[r];
  }
  #pragma unroll
  for (int r = 0; r < 20; ++r) red[tid * 20 + r] = a[r];
  __syncthreads();
  if (tid < 80) {
    int rid2 = tid / 20, r = tid % 20;
    float s = 0.f;
    for (int l = 0; l < 64; ++l) s += red[(rid2 * 64 + l) * 20 + r];
    int n = n0 + rid2;
    int row = b * N_ + n;
    if (r < 10) s1g[row * 10 + r] = s;
    else        s2gT[((size_t)b * 10 + (r - 10)) * N_ + n] = s;
  }
}

// ---------- transpose x1b (bf16) -> Xbt bf16 ----------
__global__ __launch_bounds__(256) void transpose_x1(
    const ushortt* __restrict__ x1b, ushortt* __restrict__ Xbt) {
  __shared__ ushortt st[64][66];
  int b = blockIdx.z, n0 = blockIdx.y * 64, c0 = blockIdx.x * 64;
  int tid = threadIdx.x;
  int r = tid >> 2, cc = (tid & 3) * 16;
  if (n0 + r < N_) {
    const ushortt* src = x1b + ((size_t)b * N_ + n0 + r) * CT_ + c0 + cc;
    ushortt tmp[16];
    *(uint4*)&tmp[0] = *(const uint4*)&src[0];
    *(uint4*)&tmp[8] = *(const uint4*)&src[8];
    #pragma unroll
    for (int i = 0; i < 16; ++i) st[r][cc + i] = tmp[i];
  } else {
    #pragma unroll
    for (int i = 0; i < 16; ++i) st[r][cc + i] = 0;
  }
  __syncthreads();
  ushortt out[16];
  #pragma unroll
  for (int i = 0; i < 16; ++i) out[i] = st[cc + i][r];
  ushortt* dst = Xbt + ((size_t)b * CT_ + c0 + r) * 1024 + n0 + cc;
  *(uint4*)&dst[0] = *(const uint4*)&out[0];
  *(uint4*)&dst[8] = *(const uint4*)&out[8];
}

__global__ __launch_bounds__(256) void gatt_scores(
    const float* __restrict__ s1, const float* __restrict__ s2T,
    const float* __restrict__ Aadj, ushortt* __restrict__ Agb) {
  __shared__ float p[N_];
  __shared__ float r1[R_];
  __shared__ float red[256];
  int b = blockIdx.x / N_, n = blockIdx.x % N_;
  if (threadIdx.x < R_) r1[threadIdx.x] = s1[((size_t)b * N_ + n) * R_ + threadIdx.x];
  __syncthreads();
  const float scale = rsqrtf(1536.f);
  const float* s2b = s2T + (size_t)b * 10 * N_;
  float lmax = -1e30f;
  for (int m = threadIdx.x; m < N_; m += 256) {
    float d = 0.f;
    #pragma unroll
    for (int r = 0; r < R_; ++r) d += r1[r] * s2b[r * N_ + m];
    d *= scale; p[m] = d; lmax = fmaxf(lmax, d);
  }
  float gmax = blockMax256(lmax, red);
  float lsum = 0.f;
  for (int m = threadIdx.x; m < N_; m += 256) {
    float e = __expf(p[m] - gmax); p[m] = e; lsum += e;
  }
  float gsum = blockSum256(lsum, red);
  float inv = 1.f / gsum;
  ushortt* agr = Agb + ((size_t)b * 1024 + n) * 1024;
  const float* ar = Aadj + (size_t)n * N_;
  for (int m = threadIdx.x; m < 1024; m += 256) {
    float v = (m < N_) ? p[m] * inv * ar[m] : 0.f;
    agr[m] = f2b_bits(v);
  }
}

// ---------- batched MFMA GEMM (double-buffered prefetch, T3 2-phase) ----------
__global__ __launch_bounds__(256) void gemm_mfma(
    const ushortt* __restrict__ Agb, const ushortt* __restrict__ Xbt,
    float* __restrict__ g1) {
  __shared__ ushortt As[2][4096];
  __shared__ ushortt Bs[2][4096];
  const int b = blockIdx.z;
  const int n0 = blockIdx.x * 128;
  const int m0 = blockIdx.y * 128;
  const ushortt* Ab = Agb + (size_t)b * 1024 * 1024;
  const ushortt* Bb = Xbt + (size_t)b * 1536 * 1024;
  const int tid = threadIdx.x;
  const int wave = tid >> 6, lane = tid & 63;
  const int wr = (wave >> 1) * 64, wc = (wave & 1) * 64;
  const int lrow = lane >> 2;
  const int lcol = (lane & 3) * 8;
  const int q = lane >> 4, l15 = lane & 15;

  f4v acc[4][4];
  #pragma unroll
  for (int i = 0; i < 4; ++i)
    #pragma unroll
    for (int j = 0; j < 4; ++j) acc[i][j] = (f4v){0.f, 0.f, 0.f, 0.f};

  const ushortt* gA = Ab + (size_t)(m0 + wave * 16 + lrow) * 1024 + lcol;
  const ushortt* gB = Bb + (size_t)(n0 + wave * 16 + lrow) * 1024 + lcol;

#define GM_STAGE(buf, kk)                                                     \
  do {                                                                        \
    __builtin_amdgcn_global_load_lds(                                         \
      (const __attribute__((address_space(1))) void*)(gA + (kk)),             \
      (__attribute__((address_space(3))) void*)(&As[buf][wave * 512]), 16, 0, 0); \
    __builtin_amdgcn_global_load_lds(                                         \
      (const __attribute__((address_space(1))) void*)(gA + (size_t)64 * 1024 + (kk)), \
      (__attribute__((address_space(3))) void*)(&As[buf][wave * 512 + 2048]), 16, 0, 0); \
    __builtin_amdgcn_global_load_lds(                                         \
      (const __attribute__((address_space(1))) void*)(gB + (kk)),             \
      (__attribute__((address_space(3))) void*)(&Bs[buf][wave * 512]), 16, 0, 0); \
    __builtin_amdgcn_global_load_lds(                                         \
      (const __attribute__((address_space(1))) void*)(gB + (size_t)64 * 1024 + (kk)), \
      (__attribute__((address_space(3))) void*)(&Bs[buf][wave * 512 + 2048]), 16, 0, 0); \
  } while (0)

  GM_STAGE(0, 0);
  __syncthreads();
  int cur = 0;
  for (int k0 = 0; k0 < 1024; k0 += 32) {
    int nxt = cur ^ 1;
    if (k0 + 32 < 1024) GM_STAGE(nxt, k0 + 32);
    bf8v af[4], bfr[4];
    #pragma unroll
    for (int i = 0; i < 4; ++i)
      af[i] = *(const bf8v*)&As[cur][(wr + i * 16 + l15) * 32 + q * 8];
    #pragma unroll
    for (int j = 0; j < 4; ++j)
      bfr[j] = *(const bf8v*)&Bs[cur][(wc + j * 16 + l15) * 32 + q * 8];
    #pragma unroll
    for (int i = 0; i < 4; ++i)
      #pragma unroll
      for (int j = 0; j < 4; ++j)
        acc[i][j] = __builtin_amdgcn_mfma_f32_16x16x32_bf16(af[i], bfr[j], acc[i][j], 0, 0, 0);
    __syncthreads();
    cur = nxt;
  }
#undef GM_STAGE
  #pragma unroll
  for (int i = 0; i < 4; ++i) {
    int rbase = m0 + wr + i * 16 + q * 4;
    #pragma unroll
    for (int r = 0; r < 4; ++r) {
      int gm = rbase + r;
      if (gm < N_) {
        float* dst = g1 + ((size_t)b * N_ + gm) * CT_ + n0 + wc + l15;
        #pragma unroll
        for (int j = 0; j < 4; ++j) dst[j * 16] = acc[i][j][r];
      }
    }
  }
}

// ---------- gcn_out ----------
__global__ __launch_bounds__(256) void gcn_out(
    const float* __restrict__ g1, const float* __restrict__ W, float* __restrict__ g) {
  __shared__ float gs[6160];
  __shared__ float Ws[4096];
  int b = blockIdx.y, n0 = blockIdx.x * 4;
  int tid = threadIdx.x;
  {
    const float4* src4 = (const float4*)g1;
    float4* dst4 = (float4*)gs;
    for (int i = tid; i < 1536; i += 256) {
      int ln = i / 384, q = i - ln * 384;
      dst4[ln * 385 + q] = src4[(size_t)(b * N_ + n0 + ln) * 384 + q];
    }
  }
  for (int i = tid; i < 4096; i += 256) Ws[i] = W[i];
  __syncthreads();
  int og = tid >> 4, ln = (tid >> 2) & 3, ts = tid & 3;
  float acc[4][6];
  #pragma unroll
  for (int oo = 0; oo < 4; ++oo)
    #pragma unroll
    for (int m = 0; m < 6; ++m) acc[oo][m] = 0.f;
  const float* base = &gs[ln * 1540 + ts * 6];
  #pragma unroll 4
  for (int c = 0; c < 64; ++c) {
    float v[6];
    #pragma unroll
    for (int m = 0; m < 6; ++m) v[m] = base[c * 24 + m];
    float4 w4 = *(const float4*)&Ws[c * 64 + og * 4];
    float wv[4] = {w4.x, w4.y, w4.z, w4.w};
    #pragma unroll
    for (int oo = 0; oo < 4; ++oo)
      #pragma unroll
      for (int m = 0; m < 6; ++m) acc[oo][m] += wv[oo] * v[m];
  }
  #pragma unroll
  for (int oo = 0; oo < 4; ++oo) {
    int o = og * 4 + oo;
    float* d = g + (((size_t)(b * C_ + o)) * N_ + n0 + ln) * T_ + ts * 6;
    *(float2*)&d[0] = make_float2(acc[oo][0], acc[oo][1]);
    *(float2*)&d[2] = make_float2(acc[oo][2], acc[oo][3]);
    *(float2*)&d[4] = make_float2(acc[oo][4], acc[oo][5]);
  }
}

// ---------- stage 3: temporal attention scores ----------
__global__ __launch_bounds__(256) void tatt_s12(
    const float* __restrict__ g, const float* __restrict__ Wp,
    float* __restrict__ s1, float* __restrict__ s2) {
  __shared__ float red[40 * 257];
  const int b = blockIdx.z, t0 = blockIdx.y * 4, n0 = blockIdx.x * 20;
  const int tid = threadIdx.x;
  const int o = tid & 63, nl = tid >> 6;
  float acc[4][20];
  #pragma unroll
  for (int tt = 0; tt < 4; ++tt)
    #pragma unroll
    for (int j = 0; j < 20; ++j) acc[tt][j] = 0.f;
  const float* gb = g + (size_t)(b * 64 + o) * NT_ + t0;
  #pragma unroll 1
  for (int it = 0; it < 5; ++it) {
    int n = n0 + it * 4 + nl;
    float4 gv = *(const float4*)&gb[n * 24];
    const float4* w4 = (const float4*)&Wp[(size_t)(n * 64 + o) * 20];
    float4 wa = w4[0], wbv = w4[1], wc = w4[2], wd = w4[3], we = w4[4];
    float w[20] = {wa.x,wa.y,wa.z,wa.w, wbv.x,wbv.y,wbv.z,wbv.w,
                   wc.x,wc.y,wc.z,wc.w, wd.x,wd.y,wd.z,wd.w,
                   we.x,we.y,we.z,we.w};
    float gs[4] = {gv.x, gv.y, gv.z, gv.w};
    #pragma unroll
    for (int tt = 0; tt < 4; ++tt)
      #pragma unroll
      for (int j = 0; j < 20; ++j) acc[tt][j] += gs[tt] * w[j];
  }
  // block reduce: 80 values x 256 threads, in 2 halves of 40
  #pragma unroll
  for (int half = 0; half < 2; ++half) {
    __syncthreads();
    #pragma unroll
    for (int mm = 0; mm < 40; ++mm) {
      int m = half * 40 + mm;
      red[mm * 257 + tid] = acc[m / 20][m % 20];
    }
    __syncthreads();
    #pragma unroll
    for (int s = 128; s >= 8; s >>= 1) {
      for (int i = tid; i < 40 * s; i += 256) {
        int rr = i / s, col = i - rr * s;
        red[rr * 257 + col] += red[rr * 257 + col + s];
      }
      __syncthreads();
    }
    if (tid < 40) {
      float v = 0.f;
      #pragma unroll
      for (int c = 0; c < 8; ++c) v += red[tid * 257 + c];
      int m = half * 40 + tid;
      int t = t0 + m / 20, j = m % 20;
      if (j < 10) atomicAdd(&s1[(b * T_ + t) * R_ + j], v);
      else        atomicAdd(&s2[(b * T_ + t) * R_ + (j - 10)], v);
    }
  }
}

__global__ __launch_bounds__(64) void tatt_softmax(
    const float* __restrict__ s1, const float* __restrict__ s2, float* __restrict__ Pt) {
  int b = blockIdx.x, t = threadIdx.x;
  if (t >= T_) return;
  float r1[R_];
  #pragma unroll
  for (int r = 0; r < R_; ++r) r1[r] = s1[(b * T_ + t) * R_ + r];
  const float scale = rsqrtf(64000.f);
  float row[T_]; float m = -1e30f;
  for (int j = 0; j < T_; ++j) {
    const float* s2r = s2 + (b * T_ + j) * R_;
    float d = 0.f;
    #pragma unroll
    for (int r = 0; r < R_; ++r) d += r1[r] * s2r[r];
    d *= scale; row[j] = d; m = fmaxf(m, d);
  }
  float s = 0.f;
  for (int j = 0; j < T_; ++j) { float e = __expf(row[j] - m); row[j] = e; s += e; }
  float inv = 1.f / s;
  for (int j = 0; j < T_; ++j) Pt[(b * T_ + t) * T_ + j] = row[j] * inv;
}

// ---------- stage 4 (MFMA tail, tatt_apply FUSED): Pt@g -> conv1 -> conv2+res -> LN ----------
#define CSB 1024
#define RSB 104
#define PFS 66
__global__ __launch_bounds__(256, 4) void tail_k(
    const float* __restrict__ g, const float* __restrict__ Pt,
    const float* __restrict__ x,
    const ushortt* __restrict__ Wt,
    const float* __restrict__ c1b, const float* __restrict__ c2b,
    const float* __restrict__ rb,
    const float* __restrict__ lg, const float* __restrict__ lb,
    float* __restrict__ outp) {
  __shared__ __align__(16) ushortt LSH[16384];   // 32 KB union
  __shared__ __align__(16) float PtS[576];
  __shared__ float mu[96], rs[96];
  ushortt* L0 = LSH;
  ushortt* L1 = LSH + 8192;
  float* preF = (float*)LSH;                     // 96*66*4 = 25344 B
  int b = blockIdx.y, n0 = blockIdx.x * 4;
  int tid = threadIdx.x;
  int wave = tid >> 6, lane = tid & 63;
  int q = lane >> 4, l15 = lane & 15;

  // ---- stage A: Pt -> LDS; g row -> regs; x -> L1 row-staging ----
  if (tid < 144)
    ((float4*)PtS)[tid] = ((const float4*)(Pt + (size_t)b * 576))[tid];
  const int sc = tid >> 2, snl = tid & 3;
  float gr[24];
  {
    const float4* gp = (const float4*)(g + ((size_t)(b * 64 + sc) * 1000 + n0 + snl) * 24);
    #pragma unroll
    for (int q2 = 0; q2 < 6; ++q2) {
      float4 v = gp[q2];
      gr[q2 * 4] = v.x; gr[q2 * 4 + 1] = v.y; gr[q2 * 4 + 2] = v.z; gr[q2 * 4 + 3] = v.w;
    }
  }
  #pragma unroll
  for (int rep = 0; rep < 6; ++rep) {
    int i = tid + rep * 256;                 // < 1536 : x float4 slots
    int c = i / 24, qq = i - c * 24;
    const float4* src = (const float4*)(x + ((size_t)(b * 64 + c) * 1000 + n0) * 24);
    float4 v = src[qq];
    *(uint2*)&L1[c * RSB + qq * 4] = make_uint2(f2b_pair(v.x, v.y), f2b_pair(v.z, v.w));
  }
  __syncthreads();

  // ---- fused tatt_apply: x2 row = Pt @ g row, -> L0 row-staging (bf16) ----
  {
    u32 w12[12];
    #pragma unroll
    for (int t = 0; t < 24; t += 2) {
      float a0 = 0.f, a1 = 0.f;
      const float4* p0 = (const float4*)&PtS[t * 24];
      const float4* p1 = (const float4*)&PtS[t * 24 + 24];
      #pragma unroll
      for (int q2 = 0; q2 < 6; ++q2) {
        float4 v0 = p0[q2], v1 = p1[q2];
        a0 += v0.x * gr[q2 * 4] + v0.y * gr[q2 * 4 + 1]
            + v0.z * gr[q2 * 4 + 2] + v0.w * gr[q2 * 4 + 3];
        a1 += v1.x * gr[q2 * 4] + v1.y * gr[q2 * 4 + 1]
            + v1.z * gr[q2 * 4 + 2] + v1.w * gr[q2 * 4 + 3];
      }
      w12[t >> 1] = f2b_pair(a0, a1);
    }
    uint4* da = (uint4*)&L0[sc * RSB + snl * 24];
    da[0] = make_uint4(w12[0], w12[1], w12[2], w12[3]);
    da[1] = make_uint4(w12[4], w12[5], w12[6], w12[7]);
    da[2] = make_uint4(w12[8], w12[9], w12[10], w12[11]);
  }
  __syncthreads();

  // ---- stage B: read x2 fragments (pa) from L0 row-staging ----
  u32 pa[4][4];
  int sKblk[4], sCol[4];
  #pragma unroll
  for (int rep = 0; rep < 4; ++rep) {
    int slot = tid + rep * 256;
    int kblk = slot >> 7, col = slot & 127;
    sKblk[rep] = kblk; sCol[rep] = col;
    int nl2 = col >> 5, s = col & 31;
    if (s >= 2 && s <= 25) {
      int boff = (kblk * 8) * RSB + nl2 * 24 + (s - 2);
      #pragma unroll
      for (int h = 0; h < 4; ++h) {
        u32 a0 = L0[boff + (2 * h) * RSB], a1 = L0[boff + (2 * h + 1) * RSB];
        pa[rep][h] = a0 | (a1 << 16);
      }
    } else {
      #pragma unroll
      for (int h = 0; h < 4; ++h) pa[rep][h] = 0u;
    }
  }
  __syncthreads();
  // write X2c tile into L0 (row-staging dead)
  #pragma unroll
  for (int rep = 0; rep < 4; ++rep)
    *(uint4*)&L0[sKblk[rep] * CSB + sCol[rep] * 8] =
        make_uint4(pa[rep][0], pa[rep][1], pa[rep][2], pa[rep][3]);
  __syncthreads();

  // ---- conv1 (X2c in L0) + read residual fragments (kb) from L1 ----
  f4v acc1[2][4];
  #pragma unroll
  for (int ct = 0; ct < 2; ++ct)
    #pragma unroll
    for (int mt = 0; mt < 4; ++mt) acc1[ct][mt] = (f4v){0.f, 0.f, 0.f, 0.f};
  #pragma unroll
  for (int ki = 0; ki < 2; ++ki) {
    bf8v a0[4], a1[4];
    #pragma unroll
    for (int mt = 0; mt < 4; ++mt) {
      a0[mt] = *(const bf8v*)&Wt[(mt * 16 + l15) * 64 + ki * 32 + q * 8];
      a1[mt] = *(const bf8v*)&Wt[4096 + (mt * 16 + l15) * 64 + ki * 32 + q * 8];
    }
    #pragma unroll
    for (int ct = 0; ct < 2; ++ct) {
      int col = wave * 32 + ct * 16 + l15;
      int colp = (col == 0) ? 0 : col - 1;
      bf8v bc = *(const bf8v*)&L0[(ki * 4 + q) * CSB + col * 8];
      bf8v bp = *(const bf8v*)&L0[(ki * 4 + q) * CSB + colp * 8];
      #pragma unroll
      for (int mt = 0; mt < 4; ++mt) {
        acc1[ct][mt] = __builtin_amdgcn_mfma_f32_16x16x32_bf16(a0[mt], bc, acc1[ct][mt], 0, 0, 0);
        acc1[ct][mt] = __builtin_amdgcn_mfma_f32_16x16x32_bf16(a1[mt], bp, acc1[ct][mt], 0, 0, 0);
      }
    }
  }
  u32 kb[4][4];
  #pragma unroll
  for (int rep = 0; rep < 4; ++rep) {
    int col = sCol[rep];
    int nl2 = col >> 5, s = col & 31;
    if (s >= 2 && s <= 25) {
      int boff = (sKblk[rep] * 8) * RSB + nl2 * 24 + (s - 2);
      #pragma unroll
      for (int h = 0; h < 4; ++h) {
        u32 b0 = L1[boff + (2 * h) * RSB], b1 = L1[boff + (2 * h + 1) * RSB];
        kb[rep][h] = b0 | (b1 << 16);
      }
    } else {
      #pragma unroll
      for (int h = 0; h < 4; ++h) kb[rep][h] = 0u;
    }
  }
  // epilogue 1 in regs: bias + relu (zeros in guard/pad cols)
  u32 ypack[2][4][2];
  #pragma unroll
  for (int ct = 0; ct < 2; ++ct) {
    int s = ct * 16 + l15;
    bool v = (s >= 2 && s <= 25);
    #pragma unroll
    for (int mt = 0; mt < 4; ++mt) {
      int o0 = mt * 16 + q * 4;
      float4 bb = *(const float4*)&c1b[o0];
      float y0 = v ? fmaxf(acc1[ct][mt][0] + bb.x, 0.f) : 0.f;
      float y1 = v ? fmaxf(acc1[ct][mt][1] + bb.y, 0.f) : 0.f;
      float y2 = v ? fmaxf(acc1[ct][mt][2] + bb.z, 0.f) : 0.f;
      float y3 = v ? fmaxf(acc1[ct][mt][3] + bb.w, 0.f) : 0.f;
      ypack[ct][mt][0] = f2b_pair(y0, y1);
      ypack[ct][mt][1] = f2b_pair(y2, y3);
    }
  }
  __syncthreads();   // all conv1 X2c reads + kb L1 reads done

  // ---- write Y1c -> L0 (over X2c), Xrc -> L1 (over x staging) ----
  #pragma unroll
  for (int ct = 0; ct < 2; ++ct) {
    int col = wave * 32 + ct * 16 + l15;
    #pragma unroll
    for (int mt = 0; mt < 4; ++mt) {
      int o0 = mt * 16 + q * 4;
      *(uint2*)&L0[(o0 >> 3) * CSB + col * 8 + (o0 & 7)] =
          make_uint2(ypack[ct][mt][0], ypack[ct][mt][1]);
    }
  }
  #pragma unroll
  for (int rep = 0; rep < 4; ++rep)
    *(uint4*)&L1[sKblk[rep] * CSB + sCol[rep] * 8] =
        make_uint4(kb[rep][0], kb[rep][1], kb[rep][2], kb[rep][3]);
  __syncthreads();

  // ---- conv2 (taps col, col-2 from Y1c=L0) + residual (Xrc=L1) ----
  f4v accA[2][4], accR[2][4];
  #pragma unroll
  for (int ct = 0; ct < 2; ++ct)
    #pragma unroll
    for (int mt = 0; mt < 4; ++mt) {
      accA[ct][mt] = (f4v){0.f, 0.f, 0.f, 0.f};
      accR[ct][mt] = (f4v){0.f, 0.f, 0.f, 0.f};
    }
  #pragma unroll
  for (int ki = 0; ki < 2; ++ki) {
    bf8v c0[4], c1t[4], rrf[4];
    #pragma unroll
    for (int mt = 0; mt < 4; ++mt) {
      c0[mt]  = *(const bf8v*)&Wt[8192 + (mt * 16 + l15) * 64 + ki * 32 + q * 8];
      c1t[mt] = *(const bf8v*)&Wt[12288 + (mt * 16 + l15) * 64 + ki * 32 + q * 8];
      rrf[mt] = *(const bf8v*)&Wt[16384 + (mt * 16 + l15) * 64 + ki * 32 + q * 8];
    }
    #pragma unroll
    for (int ct = 0; ct < 2; ++ct) {
      int col = wave * 32 + ct * 16 + l15;
      int colp2 = (col < 2) ? col : col - 2;
      bf8v bc = *(const bf8v*)&L0[(ki * 4 + q) * CSB + col * 8];
      bf8v bp = *(const bf8v*)&L0[(ki * 4 + q) * CSB + colp2 * 8];
      bf8v bx = *(const bf8v*)&L1[(ki * 4 + q) * CSB + col * 8];
      #pragma unroll
      for (int mt = 0; mt < 4; ++mt) {
        accA[ct][mt] = __builtin_amdgcn_mfma_f32_16x16x32_bf16(c0[mt], bc, accA[ct][mt], 0, 0, 0);
        accA[ct][mt] = __builtin_amdgcn_mfma_f32_16x16x32_bf16(c1t[mt], bp, accA[ct][mt], 0, 0, 0);
        accR[ct][mt] = __builtin_amdgcn_mfma_f32_16x16x32_bf16(rrf[mt], bx, accR[ct][mt], 0, 0, 0);
      }
    }
  }
  // epilogue 2: relu(conv2+b2) + (res+rb), relu -> pre (regs)
  float pre[2][4][4];
  #pragma unroll
  for (int ct = 0; ct < 2; ++ct) {
    #pragma unroll
    for (int mt = 0; mt < 4; ++mt) {
      int o0 = mt * 16 + q * 4;
      float4 b2 = *(const float4*)&c2b[o0];
      float4 rbv = *(const float4*)&rb[o0];
      float bb2[4] = {b2.x, b2.y, b2.z, b2.w};
      float brv[4] = {rbv.x, rbv.y, rbv.z, rbv.w};
      #pragma unroll
      for (int r = 0; r < 4; ++r) {
        float a = fmaxf(accA[ct][mt][r] + bb2[r], 0.f) + accR[ct][mt][r] + brv[r];
        pre[ct][mt][r] = fmaxf(a, 0.f);
      }
    }
  }
  __syncthreads();   // all conv2 L0/L1 reads done before preF overwrite

  // ---- preF (f32 [96][PFS]) spans the whole union ----
  #pragma unroll
  for (int ct = 0; ct < 2; ++ct) {
    int s = ct * 16 + l15;
    if (s >= 2 && s <= 25) {
      int p = wave * 24 + s - 2;
      #pragma unroll
      for (int mt = 0; mt < 4; ++mt) {
        int o0 = mt * 16 + q * 4;
        *(float2*)&preF[p * PFS + o0]     = make_float2(pre[ct][mt][0], pre[ct][mt][1]);
        *(float2*)&preF[p * PFS + o0 + 2] = make_float2(pre[ct][mt][2], pre[ct][mt][3]);
      }
    }
  }
  __syncthreads();
  // LN stats over o for each of 96 (node,t) pairs (f32)
  if (tid < 96) {
    const float* pr = &preF[tid * PFS];
    float sm = 0.f, qq = 0.f;
    #pragma unroll 16
    for (int c = 0; c < 64; ++c) {
      float v = pr[c];
      sm += v; qq += v * v;
    }
    float m = sm * (1.f / 64.f);
    mu[tid] = m;
    rs[tid] = rsqrtf(qq * (1.f / 64.f) - m * m + 1e-5f);
  }
  __syncthreads();
  // ---- coalesced store: thread owns one 96B output row (o, nl) ----
  {
    int o = tid >> 2, nl = tid & 3;
    float gam = lg[o], bet = lb[o];
    float vals[24];
    #pragma unroll
    for (int t = 0; t < 24; ++t) {
      int p = nl * 24 + t;
      vals[t] = (preF[p * PFS + o] - mu[p]) * rs[p] * gam + bet;
    }
    float* dst = outp + ((size_t)(b * 64 + o) * 1000 + n0 + nl) * 24;
    #pragma unroll
    for (int t = 0; t < 24; t += 4)
      *(float4*)&dst[t] = make_float4(vals[t], vals[t+1], vals[t+2], vals[t+3]);
  }
}

extern "C" void kernel_launch(void* const* d_in, const int* in_sizes, int n_in,
                              void* d_out, int out_size, void* d_ws, size_t ws_size,
                              hipStream_t stream) {
  const float* x     = (const float*)d_in[0];
  const float* Aadj  = (const float*)d_in[1];
  const float* a0W1  = (const float*)d_in[2];
  const float* a0W2  = (const float*)d_in[3];
  const float* gW1   = (const float*)d_in[4];
  const float* gW2   = (const float*)d_in[5];
  const float* gcnW  = (const float*)d_in[6];
  const float* tW1   = (const float*)d_in[7];
  const float* tW2   = (const float*)d_in[8];
  const float* c1w   = (const float*)d_in[9];
  const float* c1b   = (const float*)d_in[10];
  const float* c2w   = (const float*)d_in[11];
  const float* c2b   = (const float*)d_in[12];
  const float* rw    = (const float*)d_in[13];
  const float* rb    = (const float*)d_in[14];
  const float* lng   = (const float*)d_in[15];
  const float* lnb   = (const float*)d_in[16];
  float* out = (float*)d_out;

  float* ws = (float*)d_ws;
  float* R1   = ws;                    // x1b (bf16, 24.5 MB)
  float* U    = R1 + 12288000;         // 12,288,000: Xbt+Agb (bf16), later g (f32)
  float* D    = U + 12288000;          // 12,288,000: g1
  float* s1_0 = D + 12288000;          // 5120
  float* s2_0 = s1_0 + 5120;           // 5120
  float* P0   = s2_0 + 5120;           // 32768
  float* s1g  = P0 + 32768;            // 80000
  float* s2gT = s1g + 80000;           // 80000
  float* s1t  = s2gT + 80000;          // 1920
  float* s2t  = s1t + 1920;            // 1920
  float* Ptb  = s2t + 1920;            // 4608
  float* Wp0  = Ptb + 4608;            // 480000
  float* Wgp  = Wp0 + 480000;          // 30720
  float* Wtp  = Wgp + 30720;           // 1280000
  float* Wtl  = Wtp + 1280000;         // 10240 (20480 bf16 packed tail weights)
  ushortt* x1b = (ushortt*)R1;
  ushortt* Xbt = (ushortt*)U;
  ushortt* Agb = (ushortt*)(U + 6291456);
  ushortt* Wtail = (ushortt*)Wtl;
  float* g = U;
  if (ws_size < (size_t)38876416 * 4) return;

  // weight packing
  pack_w<<<1875, 256, 0, stream>>>(a0W1, a0W2, Wp0, 24000);
  pack_w<<<120, 256, 0, stream>>>(gW1, gW2, Wgp, 1536);
  pack_w<<<5000, 256, 0, stream>>>(tW1, tW2, Wtp, 64000);
  pack_tailw<<<80, 256, 0, stream>>>(c1w, c2w, rw, Wtail);
  // stage 1: channel attention (split-K accumulate -> zero first)
  zerok<<<40, 256, 0, stream>>>(s1_0, 10240);
  att0_s12<<<dim3(128, 4), 256, 0, stream>>>(x, Wp0, s1_0, s2_0);
  att0_softmax<<<8, 64, 0, stream>>>(s1_0, s2_0, P0);
  // stage 1b+2a fused: attention-apply + gate scores (x1 stored bf16)
  att0_apply_gatt<<<dim3(250, 8), 256, 0, stream>>>(x, P0, Wgp, x1b, s1g, s2gT);
  // stage 2: gated GCN
  transpose_x1<<<dim3(24, 16, 8), 256, 0, stream>>>(x1b, Xbt);
  gatt_scores<<<8000, 256, 0, stream>>>(s1g, s2gT, Aadj, Agb);
  gemm_mfma<<<dim3(12, 8, 8), 256, 0, stream>>>(Agb, Xbt, D);
  gcn_out<<<dim3(250, 8), 256, 0, stream>>>(D, gcnW, g);
  // stage 3: temporal attention (split-K accumulate -> zero first)
  zerok<<<15, 256, 0, stream>>>(s1t, 3840);
  tatt_s12<<<dim3(50, 6, 8), 256, 0, stream>>>(g, Wtp, s1t, s2t);
  tatt_softmax<<<8, 32, 0, stream>>>(s1t, s2t, Ptb);
  // stage 4: fused tatt_apply + MFMA tail + residual + LN
  tail_k<<<dim3(250, 8), 256, 0, stream>>>(g, Ptb, x, Wtail,
                                           c1b, c2b, rb, lng, lnb, out);
}